// Round 2
// baseline (481.755 us; speedup 1.0000x reference)
//
#include <hip/hip_runtime.h>

// KEPCE_GAT r12: r11 + degree-balanced node permutation for the agg kernels.
// k_agg2f was 89us at VALUBusy 48%, HBM 35%, 0 bank conflicts: neither ALU
// nor BW bound. Cost = degree variance (Poisson(32) rows): a wave carries 8
// random nodes -> runtime ~ max of 8 half-rows (~20 trips vs mean 16), and
// the pre-epilogue __syncthreads extends to max over 32 nodes (~22). Fix:
// counting-sort nodes by degree (256 bins, 3 cheap kernels), agg kernels
// process perm[g] so each wave gets equal-degree nodes (lane eff ~95%).
// CSR build: LDS counting sort, zero global atomics, 1024-thr blocks.

__device__ __forceinline__ float lrelu(float v){ return v > 0.f ? v : 0.2f*v; }

#define BSH   7        // bucket = dst >> 7  (128 dsts/bucket)
#define BKN   (1<<BSH)
#define TTILE 4096     // edges per partition tile (1024 thr x 4)

// Fold edge MLP: Wc[66,2] = w_e1[66,32] @ w_e2[32,2]; bc[2] = b_e1@w_e2 + b_e2.
// Also zeroes the 256-bin degree histogram (runs first on the stream).
__global__ void k_wcomb(const float* __restrict__ we1, const float* __restrict__ be1,
                        const float* __restrict__ we2, const float* __restrict__ be2,
                        float* __restrict__ wc, float* __restrict__ bc,
                        int* __restrict__ dhist){
  int t = threadIdx.x;
  if (t < 256) dhist[t] = 0;
  if (t < 132){
    int i = t >> 1, k = t & 1;
    float acc = 0.f;
    for (int j = 0; j < 32; ++j) acc += we1[i*32+j]*we2[j*2+k];
    wc[t] = acc;
  } else if (t < 134){
    int k = t - 132;
    float acc = be2[k];
    for (int j = 0; j < 32; ++j) acc += be1[j]*we2[j*2+k];
    bc[k] = acc;
  }
}

// Scan stage 1: per-256-block sums.
__global__ void k_scan1(const int* __restrict__ src, int* __restrict__ bsum, int n){
  __shared__ int lds[256];
  int t = threadIdx.x, k = blockIdx.x*256 + t;
  lds[t] = (k < n) ? src[k] : 0;
  __syncthreads();
  #pragma unroll
  for (int off = 1; off < 256; off <<= 1){
    int u = (t >= off) ? lds[t-off] : 0;
    __syncthreads();
    lds[t] += u;
    __syncthreads();
  }
  if (t == 255) bsum[blockIdx.x] = lds[255];
}

// Scan stage 2: exclusive scan (nb <= 1024). One block.
__global__ void k_scan2(const int* __restrict__ bsum, int* __restrict__ boffs, int nb){
  __shared__ int lds[1024];
  int t = threadIdx.x;
  int v = (t < nb) ? bsum[t] : 0;
  lds[t] = v;
  __syncthreads();
  #pragma unroll
  for (int off = 1; off < 1024; off <<= 1){
    int u = (t >= off) ? lds[t-off] : 0;
    __syncthreads();
    lds[t] += u;
    __syncthreads();
  }
  if (t < nb) boffs[t] = lds[t] - v;
}

// Scan stage 3: exclusive scan into out, adding per-block offsets.
__global__ void k_scan3g(const int* __restrict__ src, const int* __restrict__ boffs,
                         int* __restrict__ out, int n){
  __shared__ int lds[256];
  int t = threadIdx.x, k = blockIdx.x*256 + t;
  int v = (k < n) ? src[k] : 0;
  lds[t] = v;
  __syncthreads();
  #pragma unroll
  for (int off = 1; off < 256; off <<= 1){
    int u = (t >= off) ? lds[t-off] : 0;
    __syncthreads();
    lds[t] += u;
    __syncthreads();
  }
  if (k < n) out[k] = boffs[blockIdx.x] + lds[t] - v;
}

// Per-tile bucket histogram (LDS) -> hmat[bucket][tile] (bucket-major).
__global__ void k_histT(const int* __restrict__ dst, int* __restrict__ hmat,
                        int E, int ntiles, int nbk){
  __shared__ int cnt[1024];
  int tile = blockIdx.x, lt = threadIdx.x;
  for (int b = lt; b < nbk; b += 1024) cnt[b] = 0;
  __syncthreads();
  int tb = tile*TTILE;
  #pragma unroll
  for (int r = 0; r < TTILE/1024; ++r){
    int e = tb + r*1024 + lt;
    if (e < E) atomicAdd(&cnt[dst[e] >> BSH], 1);
  }
  __syncthreads();
  for (int b = lt; b < nbk; b += 1024) hmat[(size_t)b*ntiles + tile] = cnt[b];
}

// Partition pass: streaming re-read of edge arrays; LDS ranks; write int4
// records {src,w,c,dst} to exact (bucket,tile) offsets -> bucket-grouped tmp.
__global__ void k_partition(const int* __restrict__ ei, const float* __restrict__ ew,
                            const float* __restrict__ ce, const int* __restrict__ gofs,
                            int4* __restrict__ tmp, int E, int ntiles, int nbk){
  __shared__ int cnt[1024];
  __shared__ int base[1024];
  int tile = blockIdx.x, lt = threadIdx.x;
  for (int b = lt; b < nbk; b += 1024){
    cnt[b] = 0;
    base[b] = gofs[(size_t)b*ntiles + tile];
  }
  __syncthreads();
  int tb = tile*TTILE;
  #pragma unroll
  for (int r = 0; r < TTILE/1024; ++r){
    int e = tb + r*1024 + lt;
    if (e < E){
      int d = ei[E+e];
      int bk = d >> BSH;
      int rk = atomicAdd(&cnt[bk], 1);
      tmp[base[bk] + rk] = make_int4(ei[e], __float_as_int(ew[e]),
                                     __float_as_int(ce[e]), d);
    }
  }
}

// Per-bucket finalize: LDS dst-histogram -> scan -> rowstart + exact placement.
__global__ void k_bucket(const int4* __restrict__ tmp, const int* __restrict__ gofs,
                         int* __restrict__ rowstart, int4* __restrict__ csr,
                         int n, int E, int ntiles, int nbk){
  __shared__ int cnt[BKN];
  __shared__ int sc[BKN];
  __shared__ int cur[BKN];
  int b = blockIdx.x, lt = threadIdx.x;
  int d0 = b << BSH;
  int segs = gofs[(size_t)b*ntiles];
  int sege = (b+1 < nbk) ? gofs[(size_t)(b+1)*ntiles] : E;
  if (lt < BKN) cnt[lt] = 0;
  __syncthreads();
  for (int j = segs + lt; j < sege; j += 1024)
    atomicAdd(&cnt[tmp[j].w & (BKN-1)], 1);
  __syncthreads();
  if (lt < BKN) sc[lt] = cnt[lt];
  __syncthreads();
  #pragma unroll
  for (int off = 1; off < BKN; off <<= 1){
    int u = (lt >= off && lt < BKN) ? sc[lt-off] : 0;
    __syncthreads();
    if (lt < BKN) sc[lt] += u;
    __syncthreads();
  }
  if (lt < BKN){
    int excl = segs + sc[lt] - cnt[lt];
    cur[lt] = excl;
    int d = d0 + lt;
    if (d < n) rowstart[d] = excl;
  }
  if (b == 0 && lt == 0) rowstart[n] = E;
  __syncthreads();
  for (int j = segs + lt; j < sege; j += 1024){
    int4 rec = tmp[j];
    int pos = atomicAdd(&cur[rec.w & (BKN-1)], 1);
    csr[pos] = rec;
  }
}

// ---- degree-balanced permutation: 256-bin counting sort over degrees ----
__global__ void k_deghist(const int* __restrict__ rowstart, int* __restrict__ dhist, int n){
  __shared__ int h[256];
  int lt = threadIdx.x;
  if (lt < 256) h[lt] = 0;
  __syncthreads();
  int i = blockIdx.x*1024 + lt;
  if (i < n){
    int deg = rowstart[i+1] - rowstart[i];
    atomicAdd(&h[min(deg, 255)], 1);
  }
  __syncthreads();
  if (lt < 256 && h[lt]) atomicAdd(&dhist[lt], h[lt]);
}

// Exclusive scan of the 256-bin histogram -> gcur (atomically bumped in pass 2).
__global__ void k_dscan(const int* __restrict__ dhist, int* __restrict__ gcur){
  __shared__ int lds[256];
  int t = threadIdx.x;
  int v = dhist[t];
  lds[t] = v;
  __syncthreads();
  #pragma unroll
  for (int off = 1; off < 256; off <<= 1){
    int u = (t >= off) ? lds[t-off] : 0;
    __syncthreads();
    lds[t] += u;
    __syncthreads();
  }
  gcur[t] = lds[t] - v;
}

__global__ void k_permscatter(const int* __restrict__ rowstart, int* __restrict__ gcur,
                              int* __restrict__ perm, int n){
  __shared__ int h[256];
  __shared__ int base[256];
  __shared__ int cur[256];
  int lt = threadIdx.x;
  if (lt < 256){ h[lt] = 0; cur[lt] = 0; }
  __syncthreads();
  int i = blockIdx.x*1024 + lt;
  int bin = 0;
  if (i < n){
    bin = min(rowstart[i+1] - rowstart[i], 255);
    atomicAdd(&h[bin], 1);
  }
  __syncthreads();
  if (lt < 256) base[lt] = h[lt] ? atomicAdd(&gcur[lt], h[lt]) : 0;
  __syncthreads();
  if (i < n){
    int rk = atomicAdd(&cur[bin], 1);
    perm[base[bin] + rk] = i;
  }
}

// Fused init+pre layer1: h0 = relu(x@wi+bi) in regs; xl1/xr1 = h0@Wl/Wr + b.
__global__ void k_pre1(const float* __restrict__ x, const float* __restrict__ wi,
                       const float* __restrict__ bi, const float* __restrict__ wl,
                       const float* __restrict__ bl, const float* __restrict__ wr,
                       const float* __restrict__ br, float* __restrict__ xl,
                       float* __restrict__ xr, int n){
  int i = blockIdx.x*blockDim.x + threadIdx.x;
  if (i >= n) return;
  float xi[5];
  #pragma unroll
  for (int j = 0; j < 5; ++j) xi[j] = x[i*5+j];
  float h[8];
  #pragma unroll
  for (int o = 0; o < 8; ++o){
    float acc = bi[o];
    #pragma unroll
    for (int j = 0; j < 5; ++j) acc += xi[j]*wi[j*8+o];
    h[o] = fmaxf(acc, 0.f);
  }
  #pragma unroll
  for (int o = 0; o < 16; ++o){
    float a = bl[o], r = br[o];
    #pragma unroll
    for (int j = 0; j < 8; ++j){ a += h[j]*wl[j*16+o]; r += h[j]*wr[j*16+o]; }
    xl[(size_t)i*16+o] = a;
    xr[(size_t)i*16+o] = r;
  }
}

// xl = hin@Wl+bl, xr = hin@Wr+br (layer2: 16 -> 32).
__global__ void k_pre2(const float* __restrict__ hin,
                       const float* __restrict__ wl, const float* __restrict__ bl,
                       const float* __restrict__ wr, const float* __restrict__ br,
                       float* __restrict__ xl, float* __restrict__ xr, int n){
  int i = blockIdx.x*blockDim.x + threadIdx.x;
  if (i >= n) return;
  float h[16];
  #pragma unroll
  for (int j = 0; j < 16; ++j) h[j] = hin[(size_t)i*16+j];
  #pragma unroll
  for (int o = 0; o < 32; ++o){
    float a = bl[o], r = br[o];
    #pragma unroll
    for (int j = 0; j < 16; ++j){ a += h[j]*wl[j*32+o]; r += h[j]*wr[j*32+o]; }
    xl[(size_t)i*32+o] = a;
    xr[(size_t)i*32+o] = r;
  }
}

// Layer-1 aggregation, split-K: 8 threads/node = (head, edge-half).
// Nodes taken in degree-sorted order via perm for wave balance.
__global__ void k_agg1(const int* __restrict__ rowstart, const int4* __restrict__ csr,
                       const float* __restrict__ xl, const float* __restrict__ xr,
                       const float* __restrict__ we, const float* __restrict__ att,
                       const float* __restrict__ bias, const int* __restrict__ perm,
                       float* __restrict__ hout, int n){
  constexpr int C = 4, HC = 16;
  int t = blockIdx.x*blockDim.x + threadIdx.x;
  int g = t >> 3, l = t & 7, head = l & 3, half = l >> 2;
  if (g >= n) return;
  int i = perm[g];
  float weA[C], weB[C], AT[C], BS[C];
  #pragma unroll
  for (int c = 0; c < C; ++c){
    int o = head*C + c;
    weA[c] = we[o]; weB[c] = we[HC+o]; AT[c] = att[o]; BS[c] = bias[o];
  }
  float XR[C];
  {
    float4 b = *(const float4*)(xr + (size_t)i*HC + head*C);
    XR[0]=b.x; XR[1]=b.y; XR[2]=b.z; XR[3]=b.w;
  }
  float m = -3.0e38f, den = 0.f, sw = 0.f, sc = 0.f;
  float num[C] = {0.f,0.f,0.f,0.f};
  int rs = rowstart[i], re = rowstart[i+1];
  int mid = rs + ((re - rs) >> 1);
  int jb = half ? mid : rs, je = half ? re : mid;
  int j = jb;
  for (; j + 2 <= je; j += 2){
    int4 pa = csr[j], pb = csr[j+1];
    float4 qa = *(const float4*)(xl + (size_t)pa.x*HC + head*C);
    float4 qb = *(const float4*)(xl + (size_t)pb.x*HC + head*C);
    float f0a = __int_as_float(pa.y), f1a = __int_as_float(pa.z);
    float f0b = __int_as_float(pb.y), f1b = __int_as_float(pb.z);
    sw += f0a + f0b; sc += f1a + f1b;
    float XA[C] = {qa.x,qa.y,qa.z,qa.w};
    float XB[C] = {qb.x,qb.y,qb.z,qb.w};
    float aa = 0.f, ab = 0.f;
    #pragma unroll
    for (int c = 0; c < C; ++c) aa += AT[c]*lrelu(XA[c] + XR[c] + f0a*weA[c] + f1a*weB[c]);
    #pragma unroll
    for (int c = 0; c < C; ++c) ab += AT[c]*lrelu(XB[c] + XR[c] + f0b*weA[c] + f1b*weB[c]);
    float nm = fmaxf(m, aa);
    float r = __expf(m - nm), ex = __expf(aa - nm);
    den = den*r + ex;
    #pragma unroll
    for (int c = 0; c < C; ++c) num[c] = num[c]*r + ex*XA[c];
    m = nm;
    nm = fmaxf(m, ab); r = __expf(m - nm); ex = __expf(ab - nm);
    den = den*r + ex;
    #pragma unroll
    for (int c = 0; c < C; ++c) num[c] = num[c]*r + ex*XB[c];
    m = nm;
  }
  if (j < je){
    int4 pa = csr[j];
    float4 qa = *(const float4*)(xl + (size_t)pa.x*HC + head*C);
    float f0a = __int_as_float(pa.y), f1a = __int_as_float(pa.z);
    sw += f0a; sc += f1a;
    float XA[C] = {qa.x,qa.y,qa.z,qa.w};
    float aa = 0.f;
    #pragma unroll
    for (int c = 0; c < C; ++c) aa += AT[c]*lrelu(XA[c] + XR[c] + f0a*weA[c] + f1a*weB[c]);
    float nm = fmaxf(m, aa);
    float r = __expf(m - nm), ex = __expf(aa - nm);
    den = den*r + ex;
    #pragma unroll
    for (int c = 0; c < C; ++c) num[c] = num[c]*r + ex*XA[c];
    m = nm;
  }
  {
    float mo  = __shfl_xor(m, 4);
    float dno = __shfl_xor(den, 4);
    float swo = __shfl_xor(sw, 4), sco = __shfl_xor(sc, 4);
    float nm = fmaxf(m, mo);
    float r0 = __expf(m - nm), r1 = __expf(mo - nm);
    den = den*r0 + dno*r1;
    #pragma unroll
    for (int c = 0; c < C; ++c){
      float no = __shfl_xor(num[c], 4);
      num[c] = num[c]*r0 + no*r1;
    }
    m = nm; sw += swo; sc += sco;
  }
  float cf = fmaxf((float)(re - rs), 1.f);
  float la0 = sw/cf, la1 = sc/cf;
  float4 qs = *(const float4*)(xl + (size_t)i*HC + head*C);
  float XS[C] = {qs.x,qs.y,qs.z,qs.w};
  float as = 0.f;
  #pragma unroll
  for (int c = 0; c < C; ++c) as += AT[c]*lrelu(XS[c] + XR[c] + la0*weA[c] + la1*weB[c]);
  float nm = fmaxf(m, as);
  float r = __expf(m - nm), ex = __expf(as - nm);
  den = den*r + ex;
  #pragma unroll
  for (int c = 0; c < C; ++c) num[c] = num[c]*r + ex*XS[c];
  if (half == 0){
    float inv = 1.f/den;
    #pragma unroll
    for (int c = 0; c < C; ++c)
      hout[(size_t)i*HC + head*C + c] = fmaxf(num[c]*inv + BS[c], 0.f);
  }
}

// Layer-2 aggregation, split-K (8 thr/node) + fused fc/edge-MLP epilogue.
// Degree-sorted node order via perm.
__global__ void k_agg2f(const int* __restrict__ rowstart, const int4* __restrict__ csr,
                        const float* __restrict__ xl, const float* __restrict__ xr,
                        const float* __restrict__ we, const float* __restrict__ att,
                        const float* __restrict__ bias, const float* __restrict__ wfc,
                        const float* __restrict__ bfc, const float* __restrict__ wc,
                        const int* __restrict__ perm,
                        float* __restrict__ asrc, float* __restrict__ bdst, int n){
  constexpr int C = 8, HC = 32;
  __shared__ float s_h[32*33];
  __shared__ float s_w[1024];
  __shared__ float s_wc[134];
  int lt = threadIdx.x;
  for (int k = lt; k < 1024; k += 256) s_w[k] = wfc[k];
  if (lt < 134) s_wc[lt] = wc[lt];
  int t = blockIdx.x*blockDim.x + lt;
  int g = t >> 3, l = lt & 7, head = l & 3, half = l >> 2;
  bool valid = g < n;
  int i = valid ? perm[g] : 0;
  float weA[C], weB[C], AT[C], BS[C];
  #pragma unroll
  for (int c = 0; c < C; ++c){
    int o = head*C + c;
    weA[c] = we[o]; weB[c] = we[HC+o]; AT[c] = att[o]; BS[c] = bias[o];
  }
  float XR[C];
  {
    const float4* pr = (const float4*)(xr + (size_t)i*HC + head*C);
    float4 b0 = pr[0], b1 = pr[1];
    XR[0]=b0.x; XR[1]=b0.y; XR[2]=b0.z; XR[3]=b0.w;
    XR[4]=b1.x; XR[5]=b1.y; XR[6]=b1.z; XR[7]=b1.w;
  }
  float m = -3.0e38f, den = 0.f, sw = 0.f, sc = 0.f;
  float num[C] = {0.f,0.f,0.f,0.f,0.f,0.f,0.f,0.f};
  int rs = 0, re = 0;
  if (valid){ rs = rowstart[i]; re = rowstart[i+1]; }
  int mid = rs + ((re - rs) >> 1);
  int jb = half ? mid : rs, je = half ? re : mid;
  int j = jb;
  for (; j + 2 <= je; j += 2){
    int4 pa = csr[j], pb = csr[j+1];
    const float4* qa = (const float4*)(xl + (size_t)pa.x*HC + head*C);
    const float4* qb = (const float4*)(xl + (size_t)pb.x*HC + head*C);
    float4 a0 = qa[0], a1 = qa[1], b0 = qb[0], b1 = qb[1];
    float f0a = __int_as_float(pa.y), f1a = __int_as_float(pa.z);
    float f0b = __int_as_float(pb.y), f1b = __int_as_float(pb.z);
    sw += f0a + f0b; sc += f1a + f1b;
    float XA[C] = {a0.x,a0.y,a0.z,a0.w,a1.x,a1.y,a1.z,a1.w};
    float XB[C] = {b0.x,b0.y,b0.z,b0.w,b1.x,b1.y,b1.z,b1.w};
    float aa = 0.f, ab = 0.f;
    #pragma unroll
    for (int c = 0; c < C; ++c) aa += AT[c]*lrelu(XA[c] + XR[c] + f0a*weA[c] + f1a*weB[c]);
    #pragma unroll
    for (int c = 0; c < C; ++c) ab += AT[c]*lrelu(XB[c] + XR[c] + f0b*weA[c] + f1b*weB[c]);
    float nm = fmaxf(m, aa);
    float r = __expf(m - nm), ex = __expf(aa - nm);
    den = den*r + ex;
    #pragma unroll
    for (int c = 0; c < C; ++c) num[c] = num[c]*r + ex*XA[c];
    m = nm;
    nm = fmaxf(m, ab); r = __expf(m - nm); ex = __expf(ab - nm);
    den = den*r + ex;
    #pragma unroll
    for (int c = 0; c < C; ++c) num[c] = num[c]*r + ex*XB[c];
    m = nm;
  }
  if (j < je){
    int4 pa = csr[j];
    const float4* qa = (const float4*)(xl + (size_t)pa.x*HC + head*C);
    float4 a0 = qa[0], a1 = qa[1];
    float f0a = __int_as_float(pa.y), f1a = __int_as_float(pa.z);
    sw += f0a; sc += f1a;
    float XA[C] = {a0.x,a0.y,a0.z,a0.w,a1.x,a1.y,a1.z,a1.w};
    float aa = 0.f;
    #pragma unroll
    for (int c = 0; c < C; ++c) aa += AT[c]*lrelu(XA[c] + XR[c] + f0a*weA[c] + f1a*weB[c]);
    float nm = fmaxf(m, aa);
    float r = __expf(m - nm), ex = __expf(aa - nm);
    den = den*r + ex;
    #pragma unroll
    for (int c = 0; c < C; ++c) num[c] = num[c]*r + ex*XA[c];
    m = nm;
  }
  {
    float mo  = __shfl_xor(m, 4);
    float dno = __shfl_xor(den, 4);
    float swo = __shfl_xor(sw, 4), sco = __shfl_xor(sc, 4);
    float nm = fmaxf(m, mo);
    float r0 = __expf(m - nm), r1 = __expf(mo - nm);
    den = den*r0 + dno*r1;
    #pragma unroll
    for (int c = 0; c < C; ++c){
      float no = __shfl_xor(num[c], 4);
      num[c] = num[c]*r0 + no*r1;
    }
    m = nm; sw += swo; sc += sco;
  }
  if (valid){
    float cf = fmaxf((float)(re - rs), 1.f);
    float la0 = sw/cf, la1 = sc/cf;
    const float4* pl = (const float4*)(xl + (size_t)i*HC + head*C);
    float4 s0 = pl[0], s1 = pl[1];
    float XS[C] = {s0.x,s0.y,s0.z,s0.w,s1.x,s1.y,s1.z,s1.w};
    float as = 0.f;
    #pragma unroll
    for (int c = 0; c < C; ++c) as += AT[c]*lrelu(XS[c] + XR[c] + la0*weA[c] + la1*weB[c]);
    float nm = fmaxf(m, as);
    float r = __expf(m - nm), ex = __expf(as - nm);
    den = den*r + ex;
    #pragma unroll
    for (int c = 0; c < C; ++c) num[c] = num[c]*r + ex*XS[c];
  }
  int ln = lt >> 3;
  if (half == 0){
    float inv = valid ? 1.f/den : 0.f;
    #pragma unroll
    for (int c = 0; c < C; ++c)
      s_h[ln*33 + head*C + c] = valid ? fmaxf(num[c]*inv + BS[c], 0.f) : 0.f;
  }
  __syncthreads();
  float hl[32];
  #pragma unroll
  for (int j2 = 0; j2 < 32; ++j2) hl[j2] = s_h[ln*33 + j2];
  float pa0=0.f, pa1=0.f, pb0=0.f, pb1=0.f;
  #pragma unroll
  for (int k = 0; k < 4; ++k){
    int o = l*4 + k;
    float acc = bfc[o];
    #pragma unroll
    for (int j2 = 0; j2 < 32; ++j2) acc += hl[j2]*s_w[j2*32+o];
    float f = fmaxf(acc, 0.f);
    pa0 += f*s_wc[(2+o)*2];  pa1 += f*s_wc[(2+o)*2+1];
    pb0 += f*s_wc[(34+o)*2]; pb1 += f*s_wc[(34+o)*2+1];
  }
  pa0 += __shfl_xor(pa0,1); pa0 += __shfl_xor(pa0,2); pa0 += __shfl_xor(pa0,4);
  pa1 += __shfl_xor(pa1,1); pa1 += __shfl_xor(pa1,2); pa1 += __shfl_xor(pa1,4);
  pb0 += __shfl_xor(pb0,1); pb0 += __shfl_xor(pb0,2); pb0 += __shfl_xor(pb0,4);
  pb1 += __shfl_xor(pb1,1); pb1 += __shfl_xor(pb1,2); pb1 += __shfl_xor(pb1,4);
  if (valid){
    if (l == 0)      ((float2*)asrc)[i] = make_float2(pa0, pa1);
    else if (l == 1) ((float2*)bdst)[i] = make_float2(pb0, pb1);
  }
}

// out[e] = ef[e]@Wc[0:2] + asrc[src] + bdst[dst] + bc  (float2 store)
__global__ void k_edge_final(const int* __restrict__ ei, const float* __restrict__ ew,
                             const float* __restrict__ ce, const float* __restrict__ asrc,
                             const float* __restrict__ bdst, const float* __restrict__ wc,
                             const float* __restrict__ bc, float2* __restrict__ out, int E){
  int e = blockIdx.x*blockDim.x + threadIdx.x;
  if (e >= E) return;
  int s = ei[e], d = ei[E+e];
  float f0 = ew[e], f1 = ce[e];
  float2 a = ((const float2*)asrc)[s];
  float2 b = ((const float2*)bdst)[d];
  out[e] = make_float2(f0*wc[0] + f1*wc[2] + a.x + b.x + bc[0],
                       f0*wc[1] + f1*wc[3] + a.y + b.y + bc[1]);
}

extern "C" void kernel_launch(void* const* d_in, const int* in_sizes, int n_in,
                              void* d_out, int out_size, void* d_ws, size_t ws_size,
                              hipStream_t stream){
  const float* x     = (const float*)d_in[0];
  const int*   ei    = (const int*)  d_in[1];
  const float* ew    = (const float*)d_in[2];
  const float* ce    = (const float*)d_in[3];
  const float* w_init= (const float*)d_in[4];
  const float* b_init= (const float*)d_in[5];
  const float* w1l   = (const float*)d_in[6];
  const float* b1l   = (const float*)d_in[7];
  const float* w1r   = (const float*)d_in[8];
  const float* b1r   = (const float*)d_in[9];
  const float* w1e   = (const float*)d_in[10];
  const float* att1  = (const float*)d_in[11];
  const float* bias1 = (const float*)d_in[12];
  const float* w2l   = (const float*)d_in[13];
  const float* b2l   = (const float*)d_in[14];
  const float* w2r   = (const float*)d_in[15];
  const float* b2r   = (const float*)d_in[16];
  const float* w2e   = (const float*)d_in[17];
  const float* att2  = (const float*)d_in[18];
  const float* bias2 = (const float*)d_in[19];
  const float* w_fc  = (const float*)d_in[20];
  const float* b_fc  = (const float*)d_in[21];
  const float* w_e1  = (const float*)d_in[22];
  const float* b_e1  = (const float*)d_in[23];
  const float* w_e2  = (const float*)d_in[24];
  const float* b_e2  = (const float*)d_in[25];

  const int n = in_sizes[0]/5;     // 100000
  const int E = in_sizes[2];       // 3200000
  const int ntiles = (E + TTILE - 1) / TTILE;     // ~782
  const int nbk    = (n + BKN - 1) >> BSH;        // ~782 buckets
  const int M      = nbk * ntiles;                // ~611K
  const int nbA    = (M + 255) >> 8;              // ~2389 (>1024 -> 3-level)
  const int nbB    = (nbA + 255) >> 8;            // ~10

  // ---- workspace layout: 128B-aligned (32 x 4B units) ----
  int*   W32 = (int*)d_ws;
  float* Wf  = (float*)d_ws;
  size_t off = 0;
  auto nxt = [&off](size_t cnt){ size_t p = off; off += (cnt + 31) & ~(size_t)31; return p; };
  int*   rowstart = W32 + nxt((size_t)n + 1);
  int*   bsum     = W32 + nxt(nbA);
  int*   boffs    = W32 + nxt(nbA);
  int*   bsum2    = W32 + nxt(nbB);
  int*   boffs2   = W32 + nxt(nbB);
  int*   hmat     = W32 + nxt(M);
  int*   gofs     = W32 + nxt(M);
  float* wc       = Wf  + nxt(160);
  float* bc       = wc + 132;
  int*   dhist    = W32 + nxt(256);
  int*   gcur     = W32 + nxt(256);
  int*   perm     = W32 + nxt((size_t)n);
  int4*  csr      = (int4*)(W32 + nxt((size_t)4*E));
  size_t na = ((size_t)n + 31) & ~(size_t)31;
  size_t bigsz = (size_t)4*E > 80*na ? (size_t)4*E : 80*na;
  float* S    = Wf + nxt(bigsz);
  int4*  tmp  = (int4*)S;
  float* xl1  = S;              // 16n, dead after agg1
  float* xr1  = S + 16*na;      // 16n, dead after agg1
  float* h1   = S + 32*na;      // 16n, dead after pre2
  float* xl2  = S;              // 32n (over xl1/xr1)
  float* xr2  = S + 48*na;      // 32n
  float* asrc = S + 32*na;      // 2n  (over h1, dead)
  float* bdst = S + 34*na;      // 2n

  dim3 blk(256);
  dim3 ge((E + 255)/256), gn((n + 255)/256), gn8(((size_t)8*n + 255)/256);
  dim3 gp((n + 1023)/1024);

  k_wcomb<<<1,256,0,stream>>>(w_e1,b_e1,w_e2,b_e2,wc,bc,dhist);

  // ---- CSR build: LDS counting sort + 3-level hierarchical scan ----
  k_histT<<<ntiles,1024,0,stream>>>(ei + E, hmat, E, ntiles, nbk);
  k_scan1<<<nbA,256,0,stream>>>(hmat,bsum,M);
  k_scan1<<<nbB,256,0,stream>>>(bsum,bsum2,nbA);
  k_scan2<<<1,1024,0,stream>>>(bsum2,boffs2,nbB);
  k_scan3g<<<nbB,256,0,stream>>>(bsum,boffs2,boffs,nbA);
  k_scan3g<<<nbA,256,0,stream>>>(hmat,boffs,gofs,M);
  k_partition<<<ntiles,1024,0,stream>>>(ei,ew,ce,gofs,tmp,E,ntiles,nbk);
  k_bucket<<<nbk,1024,0,stream>>>(tmp,gofs,rowstart,csr,n,E,ntiles,nbk);

  // ---- degree-balanced permutation ----
  k_deghist<<<gp,1024,0,stream>>>(rowstart,dhist,n);
  k_dscan<<<1,256,0,stream>>>(dhist,gcur);
  k_permscatter<<<gp,1024,0,stream>>>(rowstart,gcur,perm,n);

  // ---- GATv2 layer 1 (in 8, C=4) ----
  k_pre1<<<gn,blk,0,stream>>>(x,w_init,b_init,w1l,b1l,w1r,b1r,xl1,xr1,n);
  k_agg1<<<gn8,blk,0,stream>>>(rowstart,csr,xl1,xr1,w1e,att1,bias1,perm,h1,n);

  // ---- GATv2 layer 2 (in 16, C=8) + fused fc/edge-MLP node terms ----
  k_pre2<<<gn,blk,0,stream>>>(h1,w2l,b2l,w2r,b2r,xl2,xr2,n);
  k_agg2f<<<gn8,blk,0,stream>>>(rowstart,csr,xl2,xr2,w2e,att2,bias2,w_fc,b_fc,wc,perm,asrc,bdst,n);

  // ---- edge scores ----
  k_edge_final<<<ge,blk,0,stream>>>(ei,ew,ce,asrc,bdst,wc,bc,(float2*)d_out,E);
}

// Round 3
// 465.573 us; speedup vs baseline: 1.0348x; 1.0348x over previous
//
#include <hip/hip_runtime.h>

// KEPCE_GAT r13: r11 base (perm reverted: r12 showed -4us in agg2f but +13us
// system from lost coalescing + perm kernels). New: (1) CSR records SoA 12B
// (csr_src int + csr_wc float2; dst dropped -- agg never reads it): -12.8MB
// per agg pass, -12.8MB bucket writes. (2) k_pre2 fused into k_agg1 epilogue
// via LDS (h1 never hits HBM, one fewer kernel).
// CSR build: LDS counting sort, zero global atomics, 1024-thr blocks.

__device__ __forceinline__ float lrelu(float v){ return v > 0.f ? v : 0.2f*v; }

#define BSH   7        // bucket = dst >> 7  (128 dsts/bucket)
#define BKN   (1<<BSH)
#define TTILE 4096     // edges per partition tile (1024 thr x 4)

// Fold edge MLP: Wc[66,2] = w_e1[66,32] @ w_e2[32,2]; bc[2] = b_e1@w_e2 + b_e2.
__global__ void k_wcomb(const float* __restrict__ we1, const float* __restrict__ be1,
                        const float* __restrict__ we2, const float* __restrict__ be2,
                        float* __restrict__ wc, float* __restrict__ bc){
  int t = threadIdx.x;
  if (t < 132){
    int i = t >> 1, k = t & 1;
    float acc = 0.f;
    for (int j = 0; j < 32; ++j) acc += we1[i*32+j]*we2[j*2+k];
    wc[t] = acc;
  } else if (t < 134){
    int k = t - 132;
    float acc = be2[k];
    for (int j = 0; j < 32; ++j) acc += be1[j]*we2[j*2+k];
    bc[k] = acc;
  }
}

// Scan stage 1: per-256-block sums.
__global__ void k_scan1(const int* __restrict__ src, int* __restrict__ bsum, int n){
  __shared__ int lds[256];
  int t = threadIdx.x, k = blockIdx.x*256 + t;
  lds[t] = (k < n) ? src[k] : 0;
  __syncthreads();
  #pragma unroll
  for (int off = 1; off < 256; off <<= 1){
    int u = (t >= off) ? lds[t-off] : 0;
    __syncthreads();
    lds[t] += u;
    __syncthreads();
  }
  if (t == 255) bsum[blockIdx.x] = lds[255];
}

// Scan stage 2: exclusive scan (nb <= 1024). One block.
__global__ void k_scan2(const int* __restrict__ bsum, int* __restrict__ boffs, int nb){
  __shared__ int lds[1024];
  int t = threadIdx.x;
  int v = (t < nb) ? bsum[t] : 0;
  lds[t] = v;
  __syncthreads();
  #pragma unroll
  for (int off = 1; off < 1024; off <<= 1){
    int u = (t >= off) ? lds[t-off] : 0;
    __syncthreads();
    lds[t] += u;
    __syncthreads();
  }
  if (t < nb) boffs[t] = lds[t] - v;
}

// Scan stage 3: exclusive scan into out, adding per-block offsets.
__global__ void k_scan3g(const int* __restrict__ src, const int* __restrict__ boffs,
                         int* __restrict__ out, int n){
  __shared__ int lds[256];
  int t = threadIdx.x, k = blockIdx.x*256 + t;
  int v = (k < n) ? src[k] : 0;
  lds[t] = v;
  __syncthreads();
  #pragma unroll
  for (int off = 1; off < 256; off <<= 1){
    int u = (t >= off) ? lds[t-off] : 0;
    __syncthreads();
    lds[t] += u;
    __syncthreads();
  }
  if (k < n) out[k] = boffs[blockIdx.x] + lds[t] - v;
}

// Per-tile bucket histogram (LDS) -> hmat[bucket][tile] (bucket-major).
__global__ void k_histT(const int* __restrict__ dst, int* __restrict__ hmat,
                        int E, int ntiles, int nbk){
  __shared__ int cnt[1024];
  int tile = blockIdx.x, lt = threadIdx.x;
  for (int b = lt; b < nbk; b += 1024) cnt[b] = 0;
  __syncthreads();
  int tb = tile*TTILE;
  #pragma unroll
  for (int r = 0; r < TTILE/1024; ++r){
    int e = tb + r*1024 + lt;
    if (e < E) atomicAdd(&cnt[dst[e] >> BSH], 1);
  }
  __syncthreads();
  for (int b = lt; b < nbk; b += 1024) hmat[(size_t)b*ntiles + tile] = cnt[b];
}

// Partition pass: streaming re-read of edge arrays; LDS ranks; write int4
// records {src,w,c,dst} to exact (bucket,tile) offsets -> bucket-grouped tmp.
__global__ void k_partition(const int* __restrict__ ei, const float* __restrict__ ew,
                            const float* __restrict__ ce, const int* __restrict__ gofs,
                            int4* __restrict__ tmp, int E, int ntiles, int nbk){
  __shared__ int cnt[1024];
  __shared__ int base[1024];
  int tile = blockIdx.x, lt = threadIdx.x;
  for (int b = lt; b < nbk; b += 1024){
    cnt[b] = 0;
    base[b] = gofs[(size_t)b*ntiles + tile];
  }
  __syncthreads();
  int tb = tile*TTILE;
  #pragma unroll
  for (int r = 0; r < TTILE/1024; ++r){
    int e = tb + r*1024 + lt;
    if (e < E){
      int d = ei[E+e];
      int bk = d >> BSH;
      int rk = atomicAdd(&cnt[bk], 1);
      tmp[base[bk] + rk] = make_int4(ei[e], __float_as_int(ew[e]),
                                     __float_as_int(ce[e]), d);
    }
  }
}

// Per-bucket finalize: LDS dst-histogram -> scan -> rowstart + SoA CSR
// (csr_src int, csr_wc float2 -- dst dropped, agg kernels never read it).
__global__ void k_bucket(const int4* __restrict__ tmp, const int* __restrict__ gofs,
                         int* __restrict__ rowstart, int* __restrict__ csr_src,
                         float2* __restrict__ csr_wc,
                         int n, int E, int ntiles, int nbk){
  __shared__ int cnt[BKN];
  __shared__ int sc[BKN];
  __shared__ int cur[BKN];
  int b = blockIdx.x, lt = threadIdx.x;
  int d0 = b << BSH;
  int segs = gofs[(size_t)b*ntiles];
  int sege = (b+1 < nbk) ? gofs[(size_t)(b+1)*ntiles] : E;
  if (lt < BKN) cnt[lt] = 0;
  __syncthreads();
  for (int j = segs + lt; j < sege; j += 1024)
    atomicAdd(&cnt[tmp[j].w & (BKN-1)], 1);
  __syncthreads();
  if (lt < BKN) sc[lt] = cnt[lt];
  __syncthreads();
  #pragma unroll
  for (int off = 1; off < BKN; off <<= 1){
    int u = (lt >= off && lt < BKN) ? sc[lt-off] : 0;
    __syncthreads();
    if (lt < BKN) sc[lt] += u;
    __syncthreads();
  }
  if (lt < BKN){
    int excl = segs + sc[lt] - cnt[lt];
    cur[lt] = excl;
    int d = d0 + lt;
    if (d < n) rowstart[d] = excl;
  }
  if (b == 0 && lt == 0) rowstart[n] = E;
  __syncthreads();
  for (int j = segs + lt; j < sege; j += 1024){
    int4 rec = tmp[j];
    int pos = atomicAdd(&cur[rec.w & (BKN-1)], 1);
    csr_src[pos] = rec.x;
    csr_wc[pos] = make_float2(__int_as_float(rec.y), __int_as_float(rec.z));
  }
}

// Fused init+pre layer1: h0 = relu(x@wi+bi) in regs; xl1/xr1 = h0@Wl/Wr + b.
__global__ void k_pre1(const float* __restrict__ x, const float* __restrict__ wi,
                       const float* __restrict__ bi, const float* __restrict__ wl,
                       const float* __restrict__ bl, const float* __restrict__ wr,
                       const float* __restrict__ br, float* __restrict__ xl,
                       float* __restrict__ xr, int n){
  int i = blockIdx.x*blockDim.x + threadIdx.x;
  if (i >= n) return;
  float xi[5];
  #pragma unroll
  for (int j = 0; j < 5; ++j) xi[j] = x[i*5+j];
  float h[8];
  #pragma unroll
  for (int o = 0; o < 8; ++o){
    float acc = bi[o];
    #pragma unroll
    for (int j = 0; j < 5; ++j) acc += xi[j]*wi[j*8+o];
    h[o] = fmaxf(acc, 0.f);
  }
  #pragma unroll
  for (int o = 0; o < 16; ++o){
    float a = bl[o], r = br[o];
    #pragma unroll
    for (int j = 0; j < 8; ++j){ a += h[j]*wl[j*16+o]; r += h[j]*wr[j*16+o]; }
    xl[(size_t)i*16+o] = a;
    xr[(size_t)i*16+o] = r;
  }
}

// Layer-1 aggregation, split-K (8 thr/node) + FUSED layer-2 pre (fc 16->64)
// epilogue via LDS: h1 never touches HBM.
__global__ void k_agg1f(const int* __restrict__ rowstart, const int* __restrict__ csr_src,
                        const float2* __restrict__ csr_wc,
                        const float* __restrict__ xl, const float* __restrict__ xr,
                        const float* __restrict__ we, const float* __restrict__ att,
                        const float* __restrict__ bias,
                        const float* __restrict__ w2l, const float* __restrict__ b2l,
                        const float* __restrict__ w2r, const float* __restrict__ b2r,
                        float* __restrict__ xl2, float* __restrict__ xr2, int n){
  constexpr int C = 4, HC = 16;
  __shared__ float s_h[32*17];
  __shared__ float s_wl[512];
  __shared__ float s_wr[512];
  int lt = threadIdx.x;
  for (int k = lt; k < 512; k += 256){ s_wl[k] = w2l[k]; s_wr[k] = w2r[k]; }
  int t = blockIdx.x*blockDim.x + lt;
  int i = t >> 3, l = lt & 7, head = l & 3, half = l >> 2;
  bool valid = i < n;
  int ic = valid ? i : 0;
  float weA[C], weB[C], AT[C], BS[C];
  #pragma unroll
  for (int c = 0; c < C; ++c){
    int o = head*C + c;
    weA[c] = we[o]; weB[c] = we[HC+o]; AT[c] = att[o]; BS[c] = bias[o];
  }
  float XR[C];
  {
    float4 b = *(const float4*)(xr + (size_t)ic*HC + head*C);
    XR[0]=b.x; XR[1]=b.y; XR[2]=b.z; XR[3]=b.w;
  }
  float m = -3.0e38f, den = 0.f, sw = 0.f, sc = 0.f;
  float num[C] = {0.f,0.f,0.f,0.f};
  int rs = 0, re = 0;
  if (valid){ rs = rowstart[i]; re = rowstart[i+1]; }
  int mid = rs + ((re - rs) >> 1);
  int jb = half ? mid : rs, je = half ? re : mid;
  int j = jb;
  for (; j + 2 <= je; j += 2){
    int sa = csr_src[j], sb = csr_src[j+1];
    float2 wa = csr_wc[j], wb = csr_wc[j+1];
    float4 qa = *(const float4*)(xl + (size_t)sa*HC + head*C);
    float4 qb = *(const float4*)(xl + (size_t)sb*HC + head*C);
    float f0a = wa.x, f1a = wa.y;
    float f0b = wb.x, f1b = wb.y;
    sw += f0a + f0b; sc += f1a + f1b;
    float XA[C] = {qa.x,qa.y,qa.z,qa.w};
    float XB[C] = {qb.x,qb.y,qb.z,qb.w};
    float aa = 0.f, ab = 0.f;
    #pragma unroll
    for (int c = 0; c < C; ++c) aa += AT[c]*lrelu(XA[c] + XR[c] + f0a*weA[c] + f1a*weB[c]);
    #pragma unroll
    for (int c = 0; c < C; ++c) ab += AT[c]*lrelu(XB[c] + XR[c] + f0b*weA[c] + f1b*weB[c]);
    float nm = fmaxf(m, aa);
    float r = __expf(m - nm), ex = __expf(aa - nm);
    den = den*r + ex;
    #pragma unroll
    for (int c = 0; c < C; ++c) num[c] = num[c]*r + ex*XA[c];
    m = nm;
    nm = fmaxf(m, ab); r = __expf(m - nm); ex = __expf(ab - nm);
    den = den*r + ex;
    #pragma unroll
    for (int c = 0; c < C; ++c) num[c] = num[c]*r + ex*XB[c];
    m = nm;
  }
  if (j < je){
    int sa = csr_src[j];
    float2 wa = csr_wc[j];
    float4 qa = *(const float4*)(xl + (size_t)sa*HC + head*C);
    float f0a = wa.x, f1a = wa.y;
    sw += f0a; sc += f1a;
    float XA[C] = {qa.x,qa.y,qa.z,qa.w};
    float aa = 0.f;
    #pragma unroll
    for (int c = 0; c < C; ++c) aa += AT[c]*lrelu(XA[c] + XR[c] + f0a*weA[c] + f1a*weB[c]);
    float nm = fmaxf(m, aa);
    float r = __expf(m - nm), ex = __expf(aa - nm);
    den = den*r + ex;
    #pragma unroll
    for (int c = 0; c < C; ++c) num[c] = num[c]*r + ex*XA[c];
    m = nm;
  }
  {
    float mo  = __shfl_xor(m, 4);
    float dno = __shfl_xor(den, 4);
    float swo = __shfl_xor(sw, 4), sco = __shfl_xor(sc, 4);
    float nm = fmaxf(m, mo);
    float r0 = __expf(m - nm), r1 = __expf(mo - nm);
    den = den*r0 + dno*r1;
    #pragma unroll
    for (int c = 0; c < C; ++c){
      float no = __shfl_xor(num[c], 4);
      num[c] = num[c]*r0 + no*r1;
    }
    m = nm; sw += swo; sc += sco;
  }
  {
    float cf = fmaxf((float)(re - rs), 1.f);
    float la0 = sw/cf, la1 = sc/cf;
    float4 qs = *(const float4*)(xl + (size_t)ic*HC + head*C);
    float XS[C] = {qs.x,qs.y,qs.z,qs.w};
    float as = 0.f;
    #pragma unroll
    for (int c = 0; c < C; ++c) as += AT[c]*lrelu(XS[c] + XR[c] + la0*weA[c] + la1*weB[c]);
    float nm = fmaxf(m, as);
    float r = __expf(m - nm), ex = __expf(as - nm);
    den = den*r + ex;
    #pragma unroll
    for (int c = 0; c < C; ++c) num[c] = num[c]*r + ex*XS[c];
  }
  int ln = lt >> 3;
  if (half == 0){
    float inv = valid ? 1.f/den : 0.f;
    #pragma unroll
    for (int c = 0; c < C; ++c)
      s_h[ln*17 + head*C + c] = valid ? fmaxf(num[c]*inv + BS[c], 0.f) : 0.f;
  }
  __syncthreads();
  // fc epilogue: node ln, thread computes outputs o = l*4..l*4+3 of both
  // xl2 = h@w2l+b2l and xr2 = h@w2r+b2r (16 -> 32 each).
  float hv[16];
  #pragma unroll
  for (int j2 = 0; j2 < 16; ++j2) hv[j2] = s_h[ln*17 + j2];
  if (valid){
    float ol[4], orr[4];
    #pragma unroll
    for (int k = 0; k < 4; ++k){
      int o = l*4 + k;
      float a = b2l[o], r = b2r[o];
      #pragma unroll
      for (int j2 = 0; j2 < 16; ++j2){ a += hv[j2]*s_wl[j2*32+o]; r += hv[j2]*s_wr[j2*32+o]; }
      ol[k] = a; orr[k] = r;
    }
    *(float4*)(xl2 + (size_t)i*32 + l*4) = make_float4(ol[0],ol[1],ol[2],ol[3]);
    *(float4*)(xr2 + (size_t)i*32 + l*4) = make_float4(orr[0],orr[1],orr[2],orr[3]);
  }
}

// Layer-2 aggregation, split-K (8 thr/node) + fused fc/edge-MLP epilogue.
__global__ void k_agg2f(const int* __restrict__ rowstart, const int* __restrict__ csr_src,
                        const float2* __restrict__ csr_wc,
                        const float* __restrict__ xl, const float* __restrict__ xr,
                        const float* __restrict__ we, const float* __restrict__ att,
                        const float* __restrict__ bias, const float* __restrict__ wfc,
                        const float* __restrict__ bfc, const float* __restrict__ wc,
                        float* __restrict__ asrc, float* __restrict__ bdst, int n){
  constexpr int C = 8, HC = 32;
  __shared__ float s_h[32*33];
  __shared__ float s_w[1024];
  __shared__ float s_wc[134];
  int lt = threadIdx.x;
  for (int k = lt; k < 1024; k += 256) s_w[k] = wfc[k];
  if (lt < 134) s_wc[lt] = wc[lt];
  int t = blockIdx.x*blockDim.x + lt;
  int i = t >> 3, l = lt & 7, head = l & 3, half = l >> 2;
  bool valid = i < n;
  int ic = valid ? i : 0;
  float weA[C], weB[C], AT[C], BS[C];
  #pragma unroll
  for (int c = 0; c < C; ++c){
    int o = head*C + c;
    weA[c] = we[o]; weB[c] = we[HC+o]; AT[c] = att[o]; BS[c] = bias[o];
  }
  float XR[C];
  {
    const float4* pr = (const float4*)(xr + (size_t)ic*HC + head*C);
    float4 b0 = pr[0], b1 = pr[1];
    XR[0]=b0.x; XR[1]=b0.y; XR[2]=b0.z; XR[3]=b0.w;
    XR[4]=b1.x; XR[5]=b1.y; XR[6]=b1.z; XR[7]=b1.w;
  }
  float m = -3.0e38f, den = 0.f, sw = 0.f, sc = 0.f;
  float num[C] = {0.f,0.f,0.f,0.f,0.f,0.f,0.f,0.f};
  int rs = 0, re = 0;
  if (valid){ rs = rowstart[i]; re = rowstart[i+1]; }
  int mid = rs + ((re - rs) >> 1);
  int jb = half ? mid : rs, je = half ? re : mid;
  int j = jb;
  for (; j + 2 <= je; j += 2){
    int sa = csr_src[j], sb = csr_src[j+1];
    float2 wa = csr_wc[j], wb = csr_wc[j+1];
    const float4* qa = (const float4*)(xl + (size_t)sa*HC + head*C);
    const float4* qb = (const float4*)(xl + (size_t)sb*HC + head*C);
    float4 a0 = qa[0], a1 = qa[1], b0 = qb[0], b1 = qb[1];
    float f0a = wa.x, f1a = wa.y;
    float f0b = wb.x, f1b = wb.y;
    sw += f0a + f0b; sc += f1a + f1b;
    float XA[C] = {a0.x,a0.y,a0.z,a0.w,a1.x,a1.y,a1.z,a1.w};
    float XB[C] = {b0.x,b0.y,b0.z,b0.w,b1.x,b1.y,b1.z,b1.w};
    float aa = 0.f, ab = 0.f;
    #pragma unroll
    for (int c = 0; c < C; ++c) aa += AT[c]*lrelu(XA[c] + XR[c] + f0a*weA[c] + f1a*weB[c]);
    #pragma unroll
    for (int c = 0; c < C; ++c) ab += AT[c]*lrelu(XB[c] + XR[c] + f0b*weA[c] + f1b*weB[c]);
    float nm = fmaxf(m, aa);
    float r = __expf(m - nm), ex = __expf(aa - nm);
    den = den*r + ex;
    #pragma unroll
    for (int c = 0; c < C; ++c) num[c] = num[c]*r + ex*XA[c];
    m = nm;
    nm = fmaxf(m, ab); r = __expf(m - nm); ex = __expf(ab - nm);
    den = den*r + ex;
    #pragma unroll
    for (int c = 0; c < C; ++c) num[c] = num[c]*r + ex*XB[c];
    m = nm;
  }
  if (j < je){
    int sa = csr_src[j];
    float2 wa = csr_wc[j];
    const float4* qa = (const float4*)(xl + (size_t)sa*HC + head*C);
    float4 a0 = qa[0], a1 = qa[1];
    float f0a = wa.x, f1a = wa.y;
    sw += f0a; sc += f1a;
    float XA[C] = {a0.x,a0.y,a0.z,a0.w,a1.x,a1.y,a1.z,a1.w};
    float aa = 0.f;
    #pragma unroll
    for (int c = 0; c < C; ++c) aa += AT[c]*lrelu(XA[c] + XR[c] + f0a*weA[c] + f1a*weB[c]);
    float nm = fmaxf(m, aa);
    float r = __expf(m - nm), ex = __expf(aa - nm);
    den = den*r + ex;
    #pragma unroll
    for (int c = 0; c < C; ++c) num[c] = num[c]*r + ex*XA[c];
    m = nm;
  }
  {
    float mo  = __shfl_xor(m, 4);
    float dno = __shfl_xor(den, 4);
    float swo = __shfl_xor(sw, 4), sco = __shfl_xor(sc, 4);
    float nm = fmaxf(m, mo);
    float r0 = __expf(m - nm), r1 = __expf(mo - nm);
    den = den*r0 + dno*r1;
    #pragma unroll
    for (int c = 0; c < C; ++c){
      float no = __shfl_xor(num[c], 4);
      num[c] = num[c]*r0 + no*r1;
    }
    m = nm; sw += swo; sc += sco;
  }
  if (valid){
    float cf = fmaxf((float)(re - rs), 1.f);
    float la0 = sw/cf, la1 = sc/cf;
    const float4* pl = (const float4*)(xl + (size_t)i*HC + head*C);
    float4 s0 = pl[0], s1 = pl[1];
    float XS[C] = {s0.x,s0.y,s0.z,s0.w,s1.x,s1.y,s1.z,s1.w};
    float as = 0.f;
    #pragma unroll
    for (int c = 0; c < C; ++c) as += AT[c]*lrelu(XS[c] + XR[c] + la0*weA[c] + la1*weB[c]);
    float nm = fmaxf(m, as);
    float r = __expf(m - nm), ex = __expf(as - nm);
    den = den*r + ex;
    #pragma unroll
    for (int c = 0; c < C; ++c) num[c] = num[c]*r + ex*XS[c];
  }
  int ln = lt >> 3;
  if (half == 0){
    float inv = valid ? 1.f/den : 0.f;
    #pragma unroll
    for (int c = 0; c < C; ++c)
      s_h[ln*33 + head*C + c] = valid ? fmaxf(num[c]*inv + BS[c], 0.f) : 0.f;
  }
  __syncthreads();
  float hl[32];
  #pragma unroll
  for (int j2 = 0; j2 < 32; ++j2) hl[j2] = s_h[ln*33 + j2];
  float pa0=0.f, pa1=0.f, pb0=0.f, pb1=0.f;
  #pragma unroll
  for (int k = 0; k < 4; ++k){
    int o = l*4 + k;
    float acc = bfc[o];
    #pragma unroll
    for (int j2 = 0; j2 < 32; ++j2) acc += hl[j2]*s_w[j2*32+o];
    float f = fmaxf(acc, 0.f);
    pa0 += f*s_wc[(2+o)*2];  pa1 += f*s_wc[(2+o)*2+1];
    pb0 += f*s_wc[(34+o)*2]; pb1 += f*s_wc[(34+o)*2+1];
  }
  pa0 += __shfl_xor(pa0,1); pa0 += __shfl_xor(pa0,2); pa0 += __shfl_xor(pa0,4);
  pa1 += __shfl_xor(pa1,1); pa1 += __shfl_xor(pa1,2); pa1 += __shfl_xor(pa1,4);
  pb0 += __shfl_xor(pb0,1); pb0 += __shfl_xor(pb0,2); pb0 += __shfl_xor(pb0,4);
  pb1 += __shfl_xor(pb1,1); pb1 += __shfl_xor(pb1,2); pb1 += __shfl_xor(pb1,4);
  if (valid){
    if (l == 0)      ((float2*)asrc)[i] = make_float2(pa0, pa1);
    else if (l == 1) ((float2*)bdst)[i] = make_float2(pb0, pb1);
  }
}

// out[e] = ef[e]@Wc[0:2] + asrc[src] + bdst[dst] + bc  (float2 store)
__global__ void k_edge_final(const int* __restrict__ ei, const float* __restrict__ ew,
                             const float* __restrict__ ce, const float* __restrict__ asrc,
                             const float* __restrict__ bdst, const float* __restrict__ wc,
                             const float* __restrict__ bc, float2* __restrict__ out, int E){
  int e = blockIdx.x*blockDim.x + threadIdx.x;
  if (e >= E) return;
  int s = ei[e], d = ei[E+e];
  float f0 = ew[e], f1 = ce[e];
  float2 a = ((const float2*)asrc)[s];
  float2 b = ((const float2*)bdst)[d];
  out[e] = make_float2(f0*wc[0] + f1*wc[2] + a.x + b.x + bc[0],
                       f0*wc[1] + f1*wc[3] + a.y + b.y + bc[1]);
}

extern "C" void kernel_launch(void* const* d_in, const int* in_sizes, int n_in,
                              void* d_out, int out_size, void* d_ws, size_t ws_size,
                              hipStream_t stream){
  const float* x     = (const float*)d_in[0];
  const int*   ei    = (const int*)  d_in[1];
  const float* ew    = (const float*)d_in[2];
  const float* ce    = (const float*)d_in[3];
  const float* w_init= (const float*)d_in[4];
  const float* b_init= (const float*)d_in[5];
  const float* w1l   = (const float*)d_in[6];
  const float* b1l   = (const float*)d_in[7];
  const float* w1r   = (const float*)d_in[8];
  const float* b1r   = (const float*)d_in[9];
  const float* w1e   = (const float*)d_in[10];
  const float* att1  = (const float*)d_in[11];
  const float* bias1 = (const float*)d_in[12];
  const float* w2l   = (const float*)d_in[13];
  const float* b2l   = (const float*)d_in[14];
  const float* w2r   = (const float*)d_in[15];
  const float* b2r   = (const float*)d_in[16];
  const float* w2e   = (const float*)d_in[17];
  const float* att2  = (const float*)d_in[18];
  const float* bias2 = (const float*)d_in[19];
  const float* w_fc  = (const float*)d_in[20];
  const float* b_fc  = (const float*)d_in[21];
  const float* w_e1  = (const float*)d_in[22];
  const float* b_e1  = (const float*)d_in[23];
  const float* w_e2  = (const float*)d_in[24];
  const float* b_e2  = (const float*)d_in[25];

  const int n = in_sizes[0]/5;     // 100000
  const int E = in_sizes[2];       // 3200000
  const int ntiles = (E + TTILE - 1) / TTILE;     // ~782
  const int nbk    = (n + BKN - 1) >> BSH;        // ~782 buckets
  const int M      = nbk * ntiles;                // ~611K
  const int nbA    = (M + 255) >> 8;              // ~2389 (>1024 -> 3-level)
  const int nbB    = (nbA + 255) >> 8;            // ~10

  // ---- workspace layout: 128B-aligned (32 x 4B units) ----
  int*   W32 = (int*)d_ws;
  float* Wf  = (float*)d_ws;
  size_t off = 0;
  auto nxt = [&off](size_t cnt){ size_t p = off; off += (cnt + 31) & ~(size_t)31; return p; };
  int*   rowstart = W32 + nxt((size_t)n + 1);
  int*   bsum     = W32 + nxt(nbA);
  int*   boffs    = W32 + nxt(nbA);
  int*   bsum2    = W32 + nxt(nbB);
  int*   boffs2   = W32 + nxt(nbB);
  int*   hmat     = W32 + nxt(M);
  int*   gofs     = W32 + nxt(M);
  float* wc       = Wf  + nxt(160);
  float* bc       = wc + 132;
  int*    csr_src = W32 + nxt((size_t)E);
  float2* csr_wc  = (float2*)(Wf + nxt((size_t)2*E));
  size_t na = ((size_t)n + 31) & ~(size_t)31;
  size_t bigsz = (size_t)4*E > 96*na ? (size_t)4*E : 96*na;
  float* S    = Wf + nxt(bigsz);
  int4*  tmp  = (int4*)S;          // 4E ints, dead after k_bucket
  float* xl1  = S;                 // 16n, dead after agg1f
  float* xr1  = S + 16*na;         // 16n, dead after agg1f
  float* xl2  = S + 32*na;         // 32n
  float* xr2  = S + 64*na;         // 32n
  float* asrc = S;                 // 2n (over dead xl1)
  float* bdst = S + 2*na;          // 2n

  dim3 blk(256);
  dim3 ge((E + 255)/256), gn((n + 255)/256), gn8(((size_t)8*n + 255)/256);

  k_wcomb<<<1,192,0,stream>>>(w_e1,b_e1,w_e2,b_e2,wc,bc);

  // ---- CSR build: LDS counting sort + 3-level hierarchical scan ----
  k_histT<<<ntiles,1024,0,stream>>>(ei + E, hmat, E, ntiles, nbk);
  k_scan1<<<nbA,256,0,stream>>>(hmat,bsum,M);
  k_scan1<<<nbB,256,0,stream>>>(bsum,bsum2,nbA);
  k_scan2<<<1,1024,0,stream>>>(bsum2,boffs2,nbB);
  k_scan3g<<<nbB,256,0,stream>>>(bsum,boffs2,boffs,nbA);
  k_scan3g<<<nbA,256,0,stream>>>(hmat,boffs,gofs,M);
  k_partition<<<ntiles,1024,0,stream>>>(ei,ew,ce,gofs,tmp,E,ntiles,nbk);
  k_bucket<<<nbk,1024,0,stream>>>(tmp,gofs,rowstart,csr_src,csr_wc,n,E,ntiles,nbk);

  // ---- GATv2 layer 1 (in 8, C=4) + fused layer-2 pre (16->64) ----
  k_pre1<<<gn,blk,0,stream>>>(x,w_init,b_init,w1l,b1l,w1r,b1r,xl1,xr1,n);
  k_agg1f<<<gn8,blk,0,stream>>>(rowstart,csr_src,csr_wc,xl1,xr1,w1e,att1,bias1,
                                w2l,b2l,w2r,b2r,xl2,xr2,n);

  // ---- GATv2 layer 2 (in 16, C=8) + fused fc/edge-MLP node terms ----
  k_agg2f<<<gn8,blk,0,stream>>>(rowstart,csr_src,csr_wc,xl2,xr2,w2e,att2,bias2,
                                w_fc,b_fc,wc,asrc,bdst,n);

  // ---- edge scores ----
  k_edge_final<<<ge,blk,0,stream>>>(ei,ew,ce,asrc,bdst,wc,bc,(float2*)d_out,E);
}

// Round 4
// 432.621 us; speedup vs baseline: 1.1136x; 1.0762x over previous
//
#include <hip/hip_runtime.h>

// KEPCE_GAT r14: r13 + (1) 4-edge unroll in both agg kernels (agg2f is
// latency-bound on the random 128B xl gather: FETCH 211MB >> 64MB working
// set = L2-miss gather; VALUBusy 47%; 2 edges in flight was too shallow).
// (2) CSR build simplified: per-bucket atomic cursors replace the 611K-entry
// hmat/gofs matrix + 5 scan kernels (intra-bucket order is irrelevant --
// k_bucket re-sorts by dst). (3) edge_final 2 edges/thread vectorized.
// CSR build: LDS counting sort; only per-bucket base atomics.

__device__ __forceinline__ float lrelu(float v){ return v > 0.f ? v : 0.2f*v; }

#define BSH   7        // bucket = dst >> 7  (128 dsts/bucket)
#define BKN   (1<<BSH)
#define TTILE 4096     // edges per partition tile (1024 thr x 4)

// Fold edge MLP: Wc[66,2] = w_e1[66,32] @ w_e2[32,2]; bc[2] = b_e1@w_e2 + b_e2.
__global__ void k_wcomb(const float* __restrict__ we1, const float* __restrict__ be1,
                        const float* __restrict__ we2, const float* __restrict__ be2,
                        float* __restrict__ wc, float* __restrict__ bc){
  int t = threadIdx.x;
  if (t < 132){
    int i = t >> 1, k = t & 1;
    float acc = 0.f;
    for (int j = 0; j < 32; ++j) acc += we1[i*32+j]*we2[j*2+k];
    wc[t] = acc;
  } else if (t < 134){
    int k = t - 132;
    float acc = be2[k];
    for (int j = 0; j < 32; ++j) acc += be1[j]*we2[j*2+k];
    bc[k] = acc;
  }
}

// Per-tile LDS bucket histogram -> one global atomicAdd per bin per block.
__global__ void k_bhist(const int* __restrict__ dst, int* __restrict__ gcnt,
                        int E, int nbk){
  __shared__ int cnt[1024];
  int lt = threadIdx.x;
  for (int b = lt; b < nbk; b += 1024) cnt[b] = 0;
  __syncthreads();
  int tb = blockIdx.x*TTILE;
  #pragma unroll
  for (int r = 0; r < TTILE/1024; ++r){
    int e = tb + r*1024 + lt;
    if (e < E) atomicAdd(&cnt[dst[e] >> BSH], 1);
  }
  __syncthreads();
  for (int b = lt; b < nbk; b += 1024)
    if (cnt[b]) atomicAdd(&gcnt[b], cnt[b]);
}

// Exclusive scan of nbk (<=1024) bucket counts -> bbase[0..nbk] and cursor.
__global__ void k_bscan(const int* __restrict__ gcnt, int* __restrict__ bbase,
                        int* __restrict__ cursor, int nb){
  __shared__ int lds[1024];
  int t = threadIdx.x;
  int v = (t < nb) ? gcnt[t] : 0;
  lds[t] = v;
  __syncthreads();
  #pragma unroll
  for (int off = 1; off < 1024; off <<= 1){
    int u = (t >= off) ? lds[t-off] : 0;
    __syncthreads();
    lds[t] += u;
    __syncthreads();
  }
  if (t < nb){
    int ex = lds[t] - v;
    bbase[t] = ex;
    cursor[t] = ex;
    if (t == nb-1) bbase[nb] = lds[t];
  }
}

// Partition: single streaming pass; records in registers; LDS ranks; block's
// per-bucket base claimed via one global atomicAdd per bin.
__global__ void k_partitionB(const int* __restrict__ ei, const float* __restrict__ ew,
                             const float* __restrict__ ce, int* __restrict__ cursor,
                             int4* __restrict__ tmp, int E, int nbk){
  __shared__ int cnt[1024];
  __shared__ int base[1024];
  int lt = threadIdx.x;
  for (int b = lt; b < nbk; b += 1024) cnt[b] = 0;
  __syncthreads();
  int tb = blockIdx.x*TTILE;
  int4 rec[TTILE/1024];
  int bk[TTILE/1024], rk[TTILE/1024];
  #pragma unroll
  for (int r = 0; r < TTILE/1024; ++r){
    int e = tb + r*1024 + lt;
    bk[r] = -1;
    if (e < E){
      int d = ei[E+e];
      int b2 = d >> BSH;
      bk[r] = b2;
      rk[r] = atomicAdd(&cnt[b2], 1);
      rec[r] = make_int4(ei[e], __float_as_int(ew[e]), __float_as_int(ce[e]), d);
    }
  }
  __syncthreads();
  for (int b = lt; b < nbk; b += 1024)
    base[b] = cnt[b] ? atomicAdd(&cursor[b], cnt[b]) : 0;
  __syncthreads();
  #pragma unroll
  for (int r = 0; r < TTILE/1024; ++r)
    if (bk[r] >= 0) tmp[base[bk[r]] + rk[r]] = rec[r];
}

// Per-bucket finalize: LDS dst-histogram -> scan -> rowstart + SoA CSR.
__global__ void k_bucket(const int4* __restrict__ tmp, const int* __restrict__ bbase,
                         int* __restrict__ rowstart, int* __restrict__ csr_src,
                         float2* __restrict__ csr_wc,
                         int n, int E, int nbk){
  __shared__ int cnt[BKN];
  __shared__ int sc[BKN];
  __shared__ int cur[BKN];
  int b = blockIdx.x, lt = threadIdx.x;
  int d0 = b << BSH;
  int segs = bbase[b];
  int sege = bbase[b+1];
  if (lt < BKN) cnt[lt] = 0;
  __syncthreads();
  for (int j = segs + lt; j < sege; j += 1024)
    atomicAdd(&cnt[tmp[j].w & (BKN-1)], 1);
  __syncthreads();
  if (lt < BKN) sc[lt] = cnt[lt];
  __syncthreads();
  #pragma unroll
  for (int off = 1; off < BKN; off <<= 1){
    int u = (lt >= off && lt < BKN) ? sc[lt-off] : 0;
    __syncthreads();
    if (lt < BKN) sc[lt] += u;
    __syncthreads();
  }
  if (lt < BKN){
    int excl = segs + sc[lt] - cnt[lt];
    cur[lt] = excl;
    int d = d0 + lt;
    if (d < n) rowstart[d] = excl;
  }
  if (b == 0 && lt == 0) rowstart[n] = E;
  __syncthreads();
  for (int j = segs + lt; j < sege; j += 1024){
    int4 rec = tmp[j];
    int pos = atomicAdd(&cur[rec.w & (BKN-1)], 1);
    csr_src[pos] = rec.x;
    csr_wc[pos] = make_float2(__int_as_float(rec.y), __int_as_float(rec.z));
  }
}

// Fused init+pre layer1: h0 = relu(x@wi+bi) in regs; xl1/xr1 = h0@Wl/Wr + b.
__global__ void k_pre1(const float* __restrict__ x, const float* __restrict__ wi,
                       const float* __restrict__ bi, const float* __restrict__ wl,
                       const float* __restrict__ bl, const float* __restrict__ wr,
                       const float* __restrict__ br, float* __restrict__ xl,
                       float* __restrict__ xr, int n){
  int i = blockIdx.x*blockDim.x + threadIdx.x;
  if (i >= n) return;
  float xi[5];
  #pragma unroll
  for (int j = 0; j < 5; ++j) xi[j] = x[i*5+j];
  float h[8];
  #pragma unroll
  for (int o = 0; o < 8; ++o){
    float acc = bi[o];
    #pragma unroll
    for (int j = 0; j < 5; ++j) acc += xi[j]*wi[j*8+o];
    h[o] = fmaxf(acc, 0.f);
  }
  #pragma unroll
  for (int o = 0; o < 16; ++o){
    float a = bl[o], r = br[o];
    #pragma unroll
    for (int j = 0; j < 8; ++j){ a += h[j]*wl[j*16+o]; r += h[j]*wr[j*16+o]; }
    xl[(size_t)i*16+o] = a;
    xr[(size_t)i*16+o] = r;
  }
}

// Layer-1 aggregation, split-K (8 thr/node), 4-edge unroll + fused layer-2
// pre (16->64) epilogue via LDS.
__global__ void __launch_bounds__(256, 4)
k_agg1f(const int* __restrict__ rowstart, const int* __restrict__ csr_src,
        const float2* __restrict__ csr_wc,
        const float* __restrict__ xl, const float* __restrict__ xr,
        const float* __restrict__ we, const float* __restrict__ att,
        const float* __restrict__ bias,
        const float* __restrict__ w2l, const float* __restrict__ b2l,
        const float* __restrict__ w2r, const float* __restrict__ b2r,
        float* __restrict__ xl2, float* __restrict__ xr2, int n){
  constexpr int C = 4, HC = 16;
  __shared__ float s_h[32*17];
  __shared__ float s_wl[512];
  __shared__ float s_wr[512];
  int lt = threadIdx.x;
  for (int k = lt; k < 512; k += 256){ s_wl[k] = w2l[k]; s_wr[k] = w2r[k]; }
  int t = blockIdx.x*blockDim.x + lt;
  int i = t >> 3, l = lt & 7, head = l & 3, half = l >> 2;
  bool valid = i < n;
  int ic = valid ? i : 0;
  float weA[C], weB[C], AT[C], BS[C];
  #pragma unroll
  for (int c = 0; c < C; ++c){
    int o = head*C + c;
    weA[c] = we[o]; weB[c] = we[HC+o]; AT[c] = att[o]; BS[c] = bias[o];
  }
  float XR[C];
  {
    float4 b = *(const float4*)(xr + (size_t)ic*HC + head*C);
    XR[0]=b.x; XR[1]=b.y; XR[2]=b.z; XR[3]=b.w;
  }
  float m = -3.0e38f, den = 0.f, sw = 0.f, sc = 0.f;
  float num[C] = {0.f,0.f,0.f,0.f};
  auto upd = [&](const float4& q, float f0, float f1){
    float XA[C] = {q.x,q.y,q.z,q.w};
    float aa = 0.f;
    #pragma unroll
    for (int c = 0; c < C; ++c) aa += AT[c]*lrelu(XA[c] + XR[c] + f0*weA[c] + f1*weB[c]);
    float nm = fmaxf(m, aa);
    float r = __expf(m - nm), ex = __expf(aa - nm);
    den = den*r + ex;
    #pragma unroll
    for (int c = 0; c < C; ++c) num[c] = num[c]*r + ex*XA[c];
    m = nm;
  };
  int rs = 0, re = 0;
  if (valid){ rs = rowstart[i]; re = rowstart[i+1]; }
  int mid = rs + ((re - rs) >> 1);
  int jb = half ? mid : rs, je = half ? re : mid;
  int j = jb;
  for (; j + 4 <= je; j += 4){
    int s0 = csr_src[j],   s1 = csr_src[j+1], s2 = csr_src[j+2], s3 = csr_src[j+3];
    float2 w0 = csr_wc[j], w1 = csr_wc[j+1], w2 = csr_wc[j+2], w3 = csr_wc[j+3];
    float4 q0 = *(const float4*)(xl + (size_t)s0*HC + head*C);
    float4 q1 = *(const float4*)(xl + (size_t)s1*HC + head*C);
    float4 q2 = *(const float4*)(xl + (size_t)s2*HC + head*C);
    float4 q3 = *(const float4*)(xl + (size_t)s3*HC + head*C);
    sw += w0.x + w1.x + w2.x + w3.x;
    sc += w0.y + w1.y + w2.y + w3.y;
    upd(q0, w0.x, w0.y);
    upd(q1, w1.x, w1.y);
    upd(q2, w2.x, w2.y);
    upd(q3, w3.x, w3.y);
  }
  for (; j < je; ++j){
    int s0 = csr_src[j];
    float2 w0 = csr_wc[j];
    float4 q0 = *(const float4*)(xl + (size_t)s0*HC + head*C);
    sw += w0.x; sc += w0.y;
    upd(q0, w0.x, w0.y);
  }
  {
    float mo  = __shfl_xor(m, 4);
    float dno = __shfl_xor(den, 4);
    float swo = __shfl_xor(sw, 4), sco = __shfl_xor(sc, 4);
    float nm = fmaxf(m, mo);
    float r0 = __expf(m - nm), r1 = __expf(mo - nm);
    den = den*r0 + dno*r1;
    #pragma unroll
    for (int c = 0; c < C; ++c){
      float no = __shfl_xor(num[c], 4);
      num[c] = num[c]*r0 + no*r1;
    }
    m = nm; sw += swo; sc += sco;
  }
  {
    float cf = fmaxf((float)(re - rs), 1.f);
    float la0 = sw/cf, la1 = sc/cf;
    float4 qs = *(const float4*)(xl + (size_t)ic*HC + head*C);
    sw = la0; sc = la1;  // reuse
    upd(qs, la0, la1);
  }
  int ln = lt >> 3;
  if (half == 0){
    float inv = valid ? 1.f/den : 0.f;
    #pragma unroll
    for (int c = 0; c < C; ++c)
      s_h[ln*17 + head*C + c] = valid ? fmaxf(num[c]*inv + BS[c], 0.f) : 0.f;
  }
  __syncthreads();
  float hv[16];
  #pragma unroll
  for (int j2 = 0; j2 < 16; ++j2) hv[j2] = s_h[ln*17 + j2];
  if (valid){
    float ol[4], orr[4];
    #pragma unroll
    for (int k = 0; k < 4; ++k){
      int o = l*4 + k;
      float a = b2l[o], r = b2r[o];
      #pragma unroll
      for (int j2 = 0; j2 < 16; ++j2){ a += hv[j2]*s_wl[j2*32+o]; r += hv[j2]*s_wr[j2*32+o]; }
      ol[k] = a; orr[k] = r;
    }
    *(float4*)(xl2 + (size_t)i*32 + l*4) = make_float4(ol[0],ol[1],ol[2],ol[3]);
    *(float4*)(xr2 + (size_t)i*32 + l*4) = make_float4(orr[0],orr[1],orr[2],orr[3]);
  }
}

// Layer-2 aggregation, split-K (8 thr/node), 4-edge unroll + fused fc/edge-MLP
// epilogue.
__global__ void __launch_bounds__(256, 4)
k_agg2f(const int* __restrict__ rowstart, const int* __restrict__ csr_src,
        const float2* __restrict__ csr_wc,
        const float* __restrict__ xl, const float* __restrict__ xr,
        const float* __restrict__ we, const float* __restrict__ att,
        const float* __restrict__ bias, const float* __restrict__ wfc,
        const float* __restrict__ bfc, const float* __restrict__ wc,
        float* __restrict__ asrc, float* __restrict__ bdst, int n){
  constexpr int C = 8, HC = 32;
  __shared__ float s_h[32*33];
  __shared__ float s_w[1024];
  __shared__ float s_wc[134];
  int lt = threadIdx.x;
  for (int k = lt; k < 1024; k += 256) s_w[k] = wfc[k];
  if (lt < 134) s_wc[lt] = wc[lt];
  int t = blockIdx.x*blockDim.x + lt;
  int i = t >> 3, l = lt & 7, head = l & 3, half = l >> 2;
  bool valid = i < n;
  int ic = valid ? i : 0;
  float weA[C], weB[C], AT[C], BS[C];
  #pragma unroll
  for (int c = 0; c < C; ++c){
    int o = head*C + c;
    weA[c] = we[o]; weB[c] = we[HC+o]; AT[c] = att[o]; BS[c] = bias[o];
  }
  float XR[C];
  {
    const float4* pr = (const float4*)(xr + (size_t)ic*HC + head*C);
    float4 b0 = pr[0], b1 = pr[1];
    XR[0]=b0.x; XR[1]=b0.y; XR[2]=b0.z; XR[3]=b0.w;
    XR[4]=b1.x; XR[5]=b1.y; XR[6]=b1.z; XR[7]=b1.w;
  }
  float m = -3.0e38f, den = 0.f, sw = 0.f, sc = 0.f;
  float num[C] = {0.f,0.f,0.f,0.f,0.f,0.f,0.f,0.f};
  auto upd = [&](const float4& a0, const float4& a1, float f0, float f1){
    float XA[C] = {a0.x,a0.y,a0.z,a0.w,a1.x,a1.y,a1.z,a1.w};
    float aa = 0.f;
    #pragma unroll
    for (int c = 0; c < C; ++c) aa += AT[c]*lrelu(XA[c] + XR[c] + f0*weA[c] + f1*weB[c]);
    float nm = fmaxf(m, aa);
    float r = __expf(m - nm), ex = __expf(aa - nm);
    den = den*r + ex;
    #pragma unroll
    for (int c = 0; c < C; ++c) num[c] = num[c]*r + ex*XA[c];
    m = nm;
  };
  int rs = 0, re = 0;
  if (valid){ rs = rowstart[i]; re = rowstart[i+1]; }
  int mid = rs + ((re - rs) >> 1);
  int jb = half ? mid : rs, je = half ? re : mid;
  int j = jb;
  for (; j + 4 <= je; j += 4){
    int s0 = csr_src[j],   s1 = csr_src[j+1], s2 = csr_src[j+2], s3 = csr_src[j+3];
    float2 w0 = csr_wc[j], w1 = csr_wc[j+1], w2 = csr_wc[j+2], w3 = csr_wc[j+3];
    const float4* q0 = (const float4*)(xl + (size_t)s0*HC + head*C);
    const float4* q1 = (const float4*)(xl + (size_t)s1*HC + head*C);
    const float4* q2 = (const float4*)(xl + (size_t)s2*HC + head*C);
    const float4* q3 = (const float4*)(xl + (size_t)s3*HC + head*C);
    float4 a00 = q0[0], a01 = q0[1];
    float4 a10 = q1[0], a11 = q1[1];
    float4 a20 = q2[0], a21 = q2[1];
    float4 a30 = q3[0], a31 = q3[1];
    sw += w0.x + w1.x + w2.x + w3.x;
    sc += w0.y + w1.y + w2.y + w3.y;
    upd(a00, a01, w0.x, w0.y);
    upd(a10, a11, w1.x, w1.y);
    upd(a20, a21, w2.x, w2.y);
    upd(a30, a31, w3.x, w3.y);
  }
  for (; j < je; ++j){
    int s0 = csr_src[j];
    float2 w0 = csr_wc[j];
    const float4* q0 = (const float4*)(xl + (size_t)s0*HC + head*C);
    float4 a00 = q0[0], a01 = q0[1];
    sw += w0.x; sc += w0.y;
    upd(a00, a01, w0.x, w0.y);
  }
  {
    float mo  = __shfl_xor(m, 4);
    float dno = __shfl_xor(den, 4);
    float swo = __shfl_xor(sw, 4), sco = __shfl_xor(sc, 4);
    float nm = fmaxf(m, mo);
    float r0 = __expf(m - nm), r1 = __expf(mo - nm);
    den = den*r0 + dno*r1;
    #pragma unroll
    for (int c = 0; c < C; ++c){
      float no = __shfl_xor(num[c], 4);
      num[c] = num[c]*r0 + no*r1;
    }
    m = nm; sw += swo; sc += sco;
  }
  if (valid){
    float cf = fmaxf((float)(re - rs), 1.f);
    float la0 = sw/cf, la1 = sc/cf;
    const float4* pl = (const float4*)(xl + (size_t)i*HC + head*C);
    float4 s0 = pl[0], s1 = pl[1];
    upd(s0, s1, la0, la1);
  }
  int ln = lt >> 3;
  if (half == 0){
    float inv = valid ? 1.f/den : 0.f;
    #pragma unroll
    for (int c = 0; c < C; ++c)
      s_h[ln*33 + head*C + c] = valid ? fmaxf(num[c]*inv + BS[c], 0.f) : 0.f;
  }
  __syncthreads();
  float hl[32];
  #pragma unroll
  for (int j2 = 0; j2 < 32; ++j2) hl[j2] = s_h[ln*33 + j2];
  float pa0=0.f, pa1=0.f, pb0=0.f, pb1=0.f;
  #pragma unroll
  for (int k = 0; k < 4; ++k){
    int o = l*4 + k;
    float acc = bfc[o];
    #pragma unroll
    for (int j2 = 0; j2 < 32; ++j2) acc += hl[j2]*s_w[j2*32+o];
    float f = fmaxf(acc, 0.f);
    pa0 += f*s_wc[(2+o)*2];  pa1 += f*s_wc[(2+o)*2+1];
    pb0 += f*s_wc[(34+o)*2]; pb1 += f*s_wc[(34+o)*2+1];
  }
  pa0 += __shfl_xor(pa0,1); pa0 += __shfl_xor(pa0,2); pa0 += __shfl_xor(pa0,4);
  pa1 += __shfl_xor(pa1,1); pa1 += __shfl_xor(pa1,2); pa1 += __shfl_xor(pa1,4);
  pb0 += __shfl_xor(pb0,1); pb0 += __shfl_xor(pb0,2); pb0 += __shfl_xor(pb0,4);
  pb1 += __shfl_xor(pb1,1); pb1 += __shfl_xor(pb1,2); pb1 += __shfl_xor(pb1,4);
  if (valid){
    if (l == 0)      ((float2*)asrc)[i] = make_float2(pa0, pa1);
    else if (l == 1) ((float2*)bdst)[i] = make_float2(pb0, pb1);
  }
}

// out[e] = ef[e]@Wc[0:2] + asrc[src] + bdst[dst] + bc; 2 edges/thread.
__global__ void k_edge_final(const int* __restrict__ ei, const float* __restrict__ ew,
                             const float* __restrict__ ce, const float* __restrict__ asrc,
                             const float* __restrict__ bdst, const float* __restrict__ wc,
                             const float* __restrict__ bc, float2* __restrict__ out, int E){
  int e0 = (blockIdx.x*blockDim.x + threadIdx.x)*2;
  if (e0 >= E) return;
  float W0 = wc[0], W1 = wc[1], W2 = wc[2], W3 = wc[3];
  float B0 = bc[0], B1 = bc[1];
  if (e0 + 2 <= E){
    int2 ss = *(const int2*)(ei + e0);
    int2 dd = *(const int2*)(ei + E + e0);
    float2 ff = *(const float2*)(ew + e0);
    float2 cc = *(const float2*)(ce + e0);
    float2 a0 = ((const float2*)asrc)[ss.x];
    float2 b0 = ((const float2*)bdst)[dd.x];
    float2 a1 = ((const float2*)asrc)[ss.y];
    float2 b1 = ((const float2*)bdst)[dd.y];
    out[e0]   = make_float2(ff.x*W0 + cc.x*W2 + a0.x + b0.x + B0,
                            ff.x*W1 + cc.x*W3 + a0.y + b0.y + B1);
    out[e0+1] = make_float2(ff.y*W0 + cc.y*W2 + a1.x + b1.x + B0,
                            ff.y*W1 + cc.y*W3 + a1.y + b1.y + B1);
  } else {
    int s = ei[e0], d = ei[E+e0];
    float f0 = ew[e0], f1 = ce[e0];
    float2 a = ((const float2*)asrc)[s];
    float2 b = ((const float2*)bdst)[d];
    out[e0] = make_float2(f0*W0 + f1*W2 + a.x + b.x + B0,
                          f0*W1 + f1*W3 + a.y + b.y + B1);
  }
}

extern "C" void kernel_launch(void* const* d_in, const int* in_sizes, int n_in,
                              void* d_out, int out_size, void* d_ws, size_t ws_size,
                              hipStream_t stream){
  const float* x     = (const float*)d_in[0];
  const int*   ei    = (const int*)  d_in[1];
  const float* ew    = (const float*)d_in[2];
  const float* ce    = (const float*)d_in[3];
  const float* w_init= (const float*)d_in[4];
  const float* b_init= (const float*)d_in[5];
  const float* w1l   = (const float*)d_in[6];
  const float* b1l   = (const float*)d_in[7];
  const float* w1r   = (const float*)d_in[8];
  const float* b1r   = (const float*)d_in[9];
  const float* w1e   = (const float*)d_in[10];
  const float* att1  = (const float*)d_in[11];
  const float* bias1 = (const float*)d_in[12];
  const float* w2l   = (const float*)d_in[13];
  const float* b2l   = (const float*)d_in[14];
  const float* w2r   = (const float*)d_in[15];
  const float* b2r   = (const float*)d_in[16];
  const float* w2e   = (const float*)d_in[17];
  const float* att2  = (const float*)d_in[18];
  const float* bias2 = (const float*)d_in[19];
  const float* w_fc  = (const float*)d_in[20];
  const float* b_fc  = (const float*)d_in[21];
  const float* w_e1  = (const float*)d_in[22];
  const float* b_e1  = (const float*)d_in[23];
  const float* w_e2  = (const float*)d_in[24];
  const float* b_e2  = (const float*)d_in[25];

  const int n = in_sizes[0]/5;     // 100000
  const int E = in_sizes[2];       // 3200000
  const int ntiles = (E + TTILE - 1) / TTILE;     // ~782
  const int nbk    = (n + BKN - 1) >> BSH;        // ~782 buckets

  // ---- workspace layout: 128B-aligned (32 x 4B units) ----
  int*   W32 = (int*)d_ws;
  float* Wf  = (float*)d_ws;
  size_t off = 0;
  auto nxt = [&off](size_t cnt){ size_t p = off; off += (cnt + 31) & ~(size_t)31; return p; };
  int*   rowstart = W32 + nxt((size_t)n + 1);
  int*   gcnt     = W32 + nxt(nbk);
  int*   bbase    = W32 + nxt(nbk + 1);
  int*   cursor   = W32 + nxt(nbk);
  float* wc       = Wf  + nxt(160);
  float* bc       = wc + 132;
  int*    csr_src = W32 + nxt((size_t)E);
  float2* csr_wc  = (float2*)(Wf + nxt((size_t)2*E));
  size_t na = ((size_t)n + 31) & ~(size_t)31;
  size_t bigsz = (size_t)4*E > 96*na ? (size_t)4*E : 96*na;
  float* S    = Wf + nxt(bigsz);
  int4*  tmp  = (int4*)S;          // 4E ints, dead after k_bucket
  float* xl1  = S;                 // 16n, dead after agg1f
  float* xr1  = S + 16*na;         // 16n, dead after agg1f
  float* xl2  = S + 32*na;         // 32n
  float* xr2  = S + 64*na;         // 32n
  float* asrc = S;                 // 2n (over dead xl1)
  float* bdst = S + 2*na;          // 2n

  dim3 blk(256);
  dim3 ge2((E/2 + 255)/256), gn((n + 255)/256), gn8(((size_t)8*n + 255)/256);

  hipMemsetAsync(gcnt, 0, nbk*sizeof(int), stream);
  k_wcomb<<<1,192,0,stream>>>(w_e1,b_e1,w_e2,b_e2,wc,bc);

  // ---- CSR build: LDS counting sort + per-bucket atomic cursors ----
  k_bhist<<<ntiles,1024,0,stream>>>(ei + E, gcnt, E, nbk);
  k_bscan<<<1,1024,0,stream>>>(gcnt, bbase, cursor, nbk);
  k_partitionB<<<ntiles,1024,0,stream>>>(ei,ew,ce,cursor,tmp,E,nbk);
  k_bucket<<<nbk,1024,0,stream>>>(tmp,bbase,rowstart,csr_src,csr_wc,n,E,nbk);

  // ---- GATv2 layer 1 (in 8, C=4) + fused layer-2 pre (16->64) ----
  k_pre1<<<gn,blk,0,stream>>>(x,w_init,b_init,w1l,b1l,w1r,b1r,xl1,xr1,n);
  k_agg1f<<<gn8,blk,0,stream>>>(rowstart,csr_src,csr_wc,xl1,xr1,w1e,att1,bias1,
                                w2l,b2l,w2r,b2r,xl2,xr2,n);

  // ---- GATv2 layer 2 (in 16, C=8) + fused fc/edge-MLP node terms ----
  k_agg2f<<<gn8,blk,0,stream>>>(rowstart,csr_src,csr_wc,xl2,xr2,w2e,att2,bias2,
                                w_fc,b_fc,wc,asrc,bdst,n);

  // ---- edge scores ----
  k_edge_final<<<ge2,blk,0,stream>>>(ei,ew,ce,asrc,bdst,wc,bc,(float2*)d_out,E);
}

// Round 5
// 427.154 us; speedup vs baseline: 1.1278x; 1.0128x over previous
//
#include <hip/hip_runtime.h>

// KEPCE_GAT r15: r14 build (per-bucket atomic-cursor CSR, SoA records,
// vectorized edge_final) + r13 agg kernels restored verbatim.
// r14's 4-edge unroll REGRESSED agg2f 88.5->103.5us (VALUBusy 47->39%,
// VGPR stuck at 64): compiler serialized the 8-gather batch instead of
// cross-iteration pipelining. The 2-edge loop is the known-good schedule.

__device__ __forceinline__ float lrelu(float v){ return v > 0.f ? v : 0.2f*v; }

#define BSH   7        // bucket = dst >> 7  (128 dsts/bucket)
#define BKN   (1<<BSH)
#define TTILE 4096     // edges per partition tile (1024 thr x 4)

// Fold edge MLP: Wc[66,2] = w_e1[66,32] @ w_e2[32,2]; bc[2] = b_e1@w_e2 + b_e2.
__global__ void k_wcomb(const float* __restrict__ we1, const float* __restrict__ be1,
                        const float* __restrict__ we2, const float* __restrict__ be2,
                        float* __restrict__ wc, float* __restrict__ bc){
  int t = threadIdx.x;
  if (t < 132){
    int i = t >> 1, k = t & 1;
    float acc = 0.f;
    for (int j = 0; j < 32; ++j) acc += we1[i*32+j]*we2[j*2+k];
    wc[t] = acc;
  } else if (t < 134){
    int k = t - 132;
    float acc = be2[k];
    for (int j = 0; j < 32; ++j) acc += be1[j]*we2[j*2+k];
    bc[k] = acc;
  }
}

// Per-tile LDS bucket histogram -> one global atomicAdd per bin per block.
__global__ void k_bhist(const int* __restrict__ dst, int* __restrict__ gcnt,
                        int E, int nbk){
  __shared__ int cnt[1024];
  int lt = threadIdx.x;
  for (int b = lt; b < nbk; b += 1024) cnt[b] = 0;
  __syncthreads();
  int tb = blockIdx.x*TTILE;
  #pragma unroll
  for (int r = 0; r < TTILE/1024; ++r){
    int e = tb + r*1024 + lt;
    if (e < E) atomicAdd(&cnt[dst[e] >> BSH], 1);
  }
  __syncthreads();
  for (int b = lt; b < nbk; b += 1024)
    if (cnt[b]) atomicAdd(&gcnt[b], cnt[b]);
}

// Exclusive scan of nbk (<=1024) bucket counts -> bbase[0..nbk] and cursor.
__global__ void k_bscan(const int* __restrict__ gcnt, int* __restrict__ bbase,
                        int* __restrict__ cursor, int nb){
  __shared__ int lds[1024];
  int t = threadIdx.x;
  int v = (t < nb) ? gcnt[t] : 0;
  lds[t] = v;
  __syncthreads();
  #pragma unroll
  for (int off = 1; off < 1024; off <<= 1){
    int u = (t >= off) ? lds[t-off] : 0;
    __syncthreads();
    lds[t] += u;
    __syncthreads();
  }
  if (t < nb){
    int ex = lds[t] - v;
    bbase[t] = ex;
    cursor[t] = ex;
    if (t == nb-1) bbase[nb] = lds[t];
  }
}

// Partition: single streaming pass; records in registers; LDS ranks; block's
// per-bucket base claimed via one global atomicAdd per bin.
__global__ void k_partitionB(const int* __restrict__ ei, const float* __restrict__ ew,
                             const float* __restrict__ ce, int* __restrict__ cursor,
                             int4* __restrict__ tmp, int E, int nbk){
  __shared__ int cnt[1024];
  __shared__ int base[1024];
  int lt = threadIdx.x;
  for (int b = lt; b < nbk; b += 1024) cnt[b] = 0;
  __syncthreads();
  int tb = blockIdx.x*TTILE;
  int4 rec[TTILE/1024];
  int bk[TTILE/1024], rk[TTILE/1024];
  #pragma unroll
  for (int r = 0; r < TTILE/1024; ++r){
    int e = tb + r*1024 + lt;
    bk[r] = -1;
    if (e < E){
      int d = ei[E+e];
      int b2 = d >> BSH;
      bk[r] = b2;
      rk[r] = atomicAdd(&cnt[b2], 1);
      rec[r] = make_int4(ei[e], __float_as_int(ew[e]), __float_as_int(ce[e]), d);
    }
  }
  __syncthreads();
  for (int b = lt; b < nbk; b += 1024)
    base[b] = cnt[b] ? atomicAdd(&cursor[b], cnt[b]) : 0;
  __syncthreads();
  #pragma unroll
  for (int r = 0; r < TTILE/1024; ++r)
    if (bk[r] >= 0) tmp[base[bk[r]] + rk[r]] = rec[r];
}

// Per-bucket finalize: LDS dst-histogram -> scan -> rowstart + SoA CSR.
__global__ void k_bucket(const int4* __restrict__ tmp, const int* __restrict__ bbase,
                         int* __restrict__ rowstart, int* __restrict__ csr_src,
                         float2* __restrict__ csr_wc,
                         int n, int E, int nbk){
  __shared__ int cnt[BKN];
  __shared__ int sc[BKN];
  __shared__ int cur[BKN];
  int b = blockIdx.x, lt = threadIdx.x;
  int d0 = b << BSH;
  int segs = bbase[b];
  int sege = bbase[b+1];
  if (lt < BKN) cnt[lt] = 0;
  __syncthreads();
  for (int j = segs + lt; j < sege; j += 1024)
    atomicAdd(&cnt[tmp[j].w & (BKN-1)], 1);
  __syncthreads();
  if (lt < BKN) sc[lt] = cnt[lt];
  __syncthreads();
  #pragma unroll
  for (int off = 1; off < BKN; off <<= 1){
    int u = (lt >= off && lt < BKN) ? sc[lt-off] : 0;
    __syncthreads();
    if (lt < BKN) sc[lt] += u;
    __syncthreads();
  }
  if (lt < BKN){
    int excl = segs + sc[lt] - cnt[lt];
    cur[lt] = excl;
    int d = d0 + lt;
    if (d < n) rowstart[d] = excl;
  }
  if (b == 0 && lt == 0) rowstart[n] = E;
  __syncthreads();
  for (int j = segs + lt; j < sege; j += 1024){
    int4 rec = tmp[j];
    int pos = atomicAdd(&cur[rec.w & (BKN-1)], 1);
    csr_src[pos] = rec.x;
    csr_wc[pos] = make_float2(__int_as_float(rec.y), __int_as_float(rec.z));
  }
}

// Fused init+pre layer1: h0 = relu(x@wi+bi) in regs; xl1/xr1 = h0@Wl/Wr + b.
__global__ void k_pre1(const float* __restrict__ x, const float* __restrict__ wi,
                       const float* __restrict__ bi, const float* __restrict__ wl,
                       const float* __restrict__ bl, const float* __restrict__ wr,
                       const float* __restrict__ br, float* __restrict__ xl,
                       float* __restrict__ xr, int n){
  int i = blockIdx.x*blockDim.x + threadIdx.x;
  if (i >= n) return;
  float xi[5];
  #pragma unroll
  for (int j = 0; j < 5; ++j) xi[j] = x[i*5+j];
  float h[8];
  #pragma unroll
  for (int o = 0; o < 8; ++o){
    float acc = bi[o];
    #pragma unroll
    for (int j = 0; j < 5; ++j) acc += xi[j]*wi[j*8+o];
    h[o] = fmaxf(acc, 0.f);
  }
  #pragma unroll
  for (int o = 0; o < 16; ++o){
    float a = bl[o], r = br[o];
    #pragma unroll
    for (int j = 0; j < 8; ++j){ a += h[j]*wl[j*16+o]; r += h[j]*wr[j*16+o]; }
    xl[(size_t)i*16+o] = a;
    xr[(size_t)i*16+o] = r;
  }
}

// Layer-1 aggregation, split-K (8 thr/node) + FUSED layer-2 pre (fc 16->64)
// epilogue via LDS: h1 never touches HBM. (r13 loop structure.)
__global__ void k_agg1f(const int* __restrict__ rowstart, const int* __restrict__ csr_src,
                        const float2* __restrict__ csr_wc,
                        const float* __restrict__ xl, const float* __restrict__ xr,
                        const float* __restrict__ we, const float* __restrict__ att,
                        const float* __restrict__ bias,
                        const float* __restrict__ w2l, const float* __restrict__ b2l,
                        const float* __restrict__ w2r, const float* __restrict__ b2r,
                        float* __restrict__ xl2, float* __restrict__ xr2, int n){
  constexpr int C = 4, HC = 16;
  __shared__ float s_h[32*17];
  __shared__ float s_wl[512];
  __shared__ float s_wr[512];
  int lt = threadIdx.x;
  for (int k = lt; k < 512; k += 256){ s_wl[k] = w2l[k]; s_wr[k] = w2r[k]; }
  int t = blockIdx.x*blockDim.x + lt;
  int i = t >> 3, l = lt & 7, head = l & 3, half = l >> 2;
  bool valid = i < n;
  int ic = valid ? i : 0;
  float weA[C], weB[C], AT[C], BS[C];
  #pragma unroll
  for (int c = 0; c < C; ++c){
    int o = head*C + c;
    weA[c] = we[o]; weB[c] = we[HC+o]; AT[c] = att[o]; BS[c] = bias[o];
  }
  float XR[C];
  {
    float4 b = *(const float4*)(xr + (size_t)ic*HC + head*C);
    XR[0]=b.x; XR[1]=b.y; XR[2]=b.z; XR[3]=b.w;
  }
  float m = -3.0e38f, den = 0.f, sw = 0.f, sc = 0.f;
  float num[C] = {0.f,0.f,0.f,0.f};
  int rs = 0, re = 0;
  if (valid){ rs = rowstart[i]; re = rowstart[i+1]; }
  int mid = rs + ((re - rs) >> 1);
  int jb = half ? mid : rs, je = half ? re : mid;
  int j = jb;
  for (; j + 2 <= je; j += 2){
    int sa = csr_src[j], sb = csr_src[j+1];
    float2 wa = csr_wc[j], wb = csr_wc[j+1];
    float4 qa = *(const float4*)(xl + (size_t)sa*HC + head*C);
    float4 qb = *(const float4*)(xl + (size_t)sb*HC + head*C);
    float f0a = wa.x, f1a = wa.y;
    float f0b = wb.x, f1b = wb.y;
    sw += f0a + f0b; sc += f1a + f1b;
    float XA[C] = {qa.x,qa.y,qa.z,qa.w};
    float XB[C] = {qb.x,qb.y,qb.z,qb.w};
    float aa = 0.f, ab = 0.f;
    #pragma unroll
    for (int c = 0; c < C; ++c) aa += AT[c]*lrelu(XA[c] + XR[c] + f0a*weA[c] + f1a*weB[c]);
    #pragma unroll
    for (int c = 0; c < C; ++c) ab += AT[c]*lrelu(XB[c] + XR[c] + f0b*weA[c] + f1b*weB[c]);
    float nm = fmaxf(m, aa);
    float r = __expf(m - nm), ex = __expf(aa - nm);
    den = den*r + ex;
    #pragma unroll
    for (int c = 0; c < C; ++c) num[c] = num[c]*r + ex*XA[c];
    m = nm;
    nm = fmaxf(m, ab); r = __expf(m - nm); ex = __expf(ab - nm);
    den = den*r + ex;
    #pragma unroll
    for (int c = 0; c < C; ++c) num[c] = num[c]*r + ex*XB[c];
    m = nm;
  }
  if (j < je){
    int sa = csr_src[j];
    float2 wa = csr_wc[j];
    float4 qa = *(const float4*)(xl + (size_t)sa*HC + head*C);
    float f0a = wa.x, f1a = wa.y;
    sw += f0a; sc += f1a;
    float XA[C] = {qa.x,qa.y,qa.z,qa.w};
    float aa = 0.f;
    #pragma unroll
    for (int c = 0; c < C; ++c) aa += AT[c]*lrelu(XA[c] + XR[c] + f0a*weA[c] + f1a*weB[c]);
    float nm = fmaxf(m, aa);
    float r = __expf(m - nm), ex = __expf(aa - nm);
    den = den*r + ex;
    #pragma unroll
    for (int c = 0; c < C; ++c) num[c] = num[c]*r + ex*XA[c];
    m = nm;
  }
  {
    float mo  = __shfl_xor(m, 4);
    float dno = __shfl_xor(den, 4);
    float swo = __shfl_xor(sw, 4), sco = __shfl_xor(sc, 4);
    float nm = fmaxf(m, mo);
    float r0 = __expf(m - nm), r1 = __expf(mo - nm);
    den = den*r0 + dno*r1;
    #pragma unroll
    for (int c = 0; c < C; ++c){
      float no = __shfl_xor(num[c], 4);
      num[c] = num[c]*r0 + no*r1;
    }
    m = nm; sw += swo; sc += sco;
  }
  {
    float cf = fmaxf((float)(re - rs), 1.f);
    float la0 = sw/cf, la1 = sc/cf;
    float4 qs = *(const float4*)(xl + (size_t)ic*HC + head*C);
    float XS[C] = {qs.x,qs.y,qs.z,qs.w};
    float as = 0.f;
    #pragma unroll
    for (int c = 0; c < C; ++c) as += AT[c]*lrelu(XS[c] + XR[c] + la0*weA[c] + la1*weB[c]);
    float nm = fmaxf(m, as);
    float r = __expf(m - nm), ex = __expf(as - nm);
    den = den*r + ex;
    #pragma unroll
    for (int c = 0; c < C; ++c) num[c] = num[c]*r + ex*XS[c];
  }
  int ln = lt >> 3;
  if (half == 0){
    float inv = valid ? 1.f/den : 0.f;
    #pragma unroll
    for (int c = 0; c < C; ++c)
      s_h[ln*17 + head*C + c] = valid ? fmaxf(num[c]*inv + BS[c], 0.f) : 0.f;
  }
  __syncthreads();
  float hv[16];
  #pragma unroll
  for (int j2 = 0; j2 < 16; ++j2) hv[j2] = s_h[ln*17 + j2];
  if (valid){
    float ol[4], orr[4];
    #pragma unroll
    for (int k = 0; k < 4; ++k){
      int o = l*4 + k;
      float a = b2l[o], r = b2r[o];
      #pragma unroll
      for (int j2 = 0; j2 < 16; ++j2){ a += hv[j2]*s_wl[j2*32+o]; r += hv[j2]*s_wr[j2*32+o]; }
      ol[k] = a; orr[k] = r;
    }
    *(float4*)(xl2 + (size_t)i*32 + l*4) = make_float4(ol[0],ol[1],ol[2],ol[3]);
    *(float4*)(xr2 + (size_t)i*32 + l*4) = make_float4(orr[0],orr[1],orr[2],orr[3]);
  }
}

// Layer-2 aggregation, split-K (8 thr/node) + fused fc/edge-MLP epilogue.
// (r13 loop structure.)
__global__ void k_agg2f(const int* __restrict__ rowstart, const int* __restrict__ csr_src,
                        const float2* __restrict__ csr_wc,
                        const float* __restrict__ xl, const float* __restrict__ xr,
                        const float* __restrict__ we, const float* __restrict__ att,
                        const float* __restrict__ bias, const float* __restrict__ wfc,
                        const float* __restrict__ bfc, const float* __restrict__ wc,
                        float* __restrict__ asrc, float* __restrict__ bdst, int n){
  constexpr int C = 8, HC = 32;
  __shared__ float s_h[32*33];
  __shared__ float s_w[1024];
  __shared__ float s_wc[134];
  int lt = threadIdx.x;
  for (int k = lt; k < 1024; k += 256) s_w[k] = wfc[k];
  if (lt < 134) s_wc[lt] = wc[lt];
  int t = blockIdx.x*blockDim.x + lt;
  int i = t >> 3, l = lt & 7, head = l & 3, half = l >> 2;
  bool valid = i < n;
  int ic = valid ? i : 0;
  float weA[C], weB[C], AT[C], BS[C];
  #pragma unroll
  for (int c = 0; c < C; ++c){
    int o = head*C + c;
    weA[c] = we[o]; weB[c] = we[HC+o]; AT[c] = att[o]; BS[c] = bias[o];
  }
  float XR[C];
  {
    const float4* pr = (const float4*)(xr + (size_t)ic*HC + head*C);
    float4 b0 = pr[0], b1 = pr[1];
    XR[0]=b0.x; XR[1]=b0.y; XR[2]=b0.z; XR[3]=b0.w;
    XR[4]=b1.x; XR[5]=b1.y; XR[6]=b1.z; XR[7]=b1.w;
  }
  float m = -3.0e38f, den = 0.f, sw = 0.f, sc = 0.f;
  float num[C] = {0.f,0.f,0.f,0.f,0.f,0.f,0.f,0.f};
  int rs = 0, re = 0;
  if (valid){ rs = rowstart[i]; re = rowstart[i+1]; }
  int mid = rs + ((re - rs) >> 1);
  int jb = half ? mid : rs, je = half ? re : mid;
  int j = jb;
  for (; j + 2 <= je; j += 2){
    int sa = csr_src[j], sb = csr_src[j+1];
    float2 wa = csr_wc[j], wb = csr_wc[j+1];
    const float4* qa = (const float4*)(xl + (size_t)sa*HC + head*C);
    const float4* qb = (const float4*)(xl + (size_t)sb*HC + head*C);
    float4 a0 = qa[0], a1 = qa[1], b0 = qb[0], b1 = qb[1];
    float f0a = wa.x, f1a = wa.y;
    float f0b = wb.x, f1b = wb.y;
    sw += f0a + f0b; sc += f1a + f1b;
    float XA[C] = {a0.x,a0.y,a0.z,a0.w,a1.x,a1.y,a1.z,a1.w};
    float XB[C] = {b0.x,b0.y,b0.z,b0.w,b1.x,b1.y,b1.z,b1.w};
    float aa = 0.f, ab = 0.f;
    #pragma unroll
    for (int c = 0; c < C; ++c) aa += AT[c]*lrelu(XA[c] + XR[c] + f0a*weA[c] + f1a*weB[c]);
    #pragma unroll
    for (int c = 0; c < C; ++c) ab += AT[c]*lrelu(XB[c] + XR[c] + f0b*weA[c] + f1b*weB[c]);
    float nm = fmaxf(m, aa);
    float r = __expf(m - nm), ex = __expf(aa - nm);
    den = den*r + ex;
    #pragma unroll
    for (int c = 0; c < C; ++c) num[c] = num[c]*r + ex*XA[c];
    m = nm;
    nm = fmaxf(m, ab); r = __expf(m - nm); ex = __expf(ab - nm);
    den = den*r + ex;
    #pragma unroll
    for (int c = 0; c < C; ++c) num[c] = num[c]*r + ex*XB[c];
    m = nm;
  }
  if (j < je){
    int sa = csr_src[j];
    float2 wa = csr_wc[j];
    const float4* qa = (const float4*)(xl + (size_t)sa*HC + head*C);
    float4 a0 = qa[0], a1 = qa[1];
    float f0a = wa.x, f1a = wa.y;
    sw += f0a; sc += f1a;
    float XA[C] = {a0.x,a0.y,a0.z,a0.w,a1.x,a1.y,a1.z,a1.w};
    float aa = 0.f;
    #pragma unroll
    for (int c = 0; c < C; ++c) aa += AT[c]*lrelu(XA[c] + XR[c] + f0a*weA[c] + f1a*weB[c]);
    float nm = fmaxf(m, aa);
    float r = __expf(m - nm), ex = __expf(aa - nm);
    den = den*r + ex;
    #pragma unroll
    for (int c = 0; c < C; ++c) num[c] = num[c]*r + ex*XA[c];
    m = nm;
  }
  {
    float mo  = __shfl_xor(m, 4);
    float dno = __shfl_xor(den, 4);
    float swo = __shfl_xor(sw, 4), sco = __shfl_xor(sc, 4);
    float nm = fmaxf(m, mo);
    float r0 = __expf(m - nm), r1 = __expf(mo - nm);
    den = den*r0 + dno*r1;
    #pragma unroll
    for (int c = 0; c < C; ++c){
      float no = __shfl_xor(num[c], 4);
      num[c] = num[c]*r0 + no*r1;
    }
    m = nm; sw += swo; sc += sco;
  }
  if (valid){
    float cf = fmaxf((float)(re - rs), 1.f);
    float la0 = sw/cf, la1 = sc/cf;
    const float4* pl = (const float4*)(xl + (size_t)i*HC + head*C);
    float4 s0 = pl[0], s1 = pl[1];
    float XS[C] = {s0.x,s0.y,s0.z,s0.w,s1.x,s1.y,s1.z,s1.w};
    float as = 0.f;
    #pragma unroll
    for (int c = 0; c < C; ++c) as += AT[c]*lrelu(XS[c] + XR[c] + la0*weA[c] + la1*weB[c]);
    float nm = fmaxf(m, as);
    float r = __expf(m - nm), ex = __expf(as - nm);
    den = den*r + ex;
    #pragma unroll
    for (int c = 0; c < C; ++c) num[c] = num[c]*r + ex*XS[c];
  }
  int ln = lt >> 3;
  if (half == 0){
    float inv = valid ? 1.f/den : 0.f;
    #pragma unroll
    for (int c = 0; c < C; ++c)
      s_h[ln*33 + head*C + c] = valid ? fmaxf(num[c]*inv + BS[c], 0.f) : 0.f;
  }
  __syncthreads();
  float hl[32];
  #pragma unroll
  for (int j2 = 0; j2 < 32; ++j2) hl[j2] = s_h[ln*33 + j2];
  float pa0=0.f, pa1=0.f, pb0=0.f, pb1=0.f;
  #pragma unroll
  for (int k = 0; k < 4; ++k){
    int o = l*4 + k;
    float acc = bfc[o];
    #pragma unroll
    for (int j2 = 0; j2 < 32; ++j2) acc += hl[j2]*s_w[j2*32+o];
    float f = fmaxf(acc, 0.f);
    pa0 += f*s_wc[(2+o)*2];  pa1 += f*s_wc[(2+o)*2+1];
    pb0 += f*s_wc[(34+o)*2]; pb1 += f*s_wc[(34+o)*2+1];
  }
  pa0 += __shfl_xor(pa0,1); pa0 += __shfl_xor(pa0,2); pa0 += __shfl_xor(pa0,4);
  pa1 += __shfl_xor(pa1,1); pa1 += __shfl_xor(pa1,2); pa1 += __shfl_xor(pa1,4);
  pb0 += __shfl_xor(pb0,1); pb0 += __shfl_xor(pb0,2); pb0 += __shfl_xor(pb0,4);
  pb1 += __shfl_xor(pb1,1); pb1 += __shfl_xor(pb1,2); pb1 += __shfl_xor(pb1,4);
  if (valid){
    if (l == 0)      ((float2*)asrc)[i] = make_float2(pa0, pa1);
    else if (l == 1) ((float2*)bdst)[i] = make_float2(pb0, pb1);
  }
}

// out[e] = ef[e]@Wc[0:2] + asrc[src] + bdst[dst] + bc; 2 edges/thread.
__global__ void k_edge_final(const int* __restrict__ ei, const float* __restrict__ ew,
                             const float* __restrict__ ce, const float* __restrict__ asrc,
                             const float* __restrict__ bdst, const float* __restrict__ wc,
                             const float* __restrict__ bc, float2* __restrict__ out, int E){
  int e0 = (blockIdx.x*blockDim.x + threadIdx.x)*2;
  if (e0 >= E) return;
  float W0 = wc[0], W1 = wc[1], W2 = wc[2], W3 = wc[3];
  float B0 = bc[0], B1 = bc[1];
  if (e0 + 2 <= E){
    int2 ss = *(const int2*)(ei + e0);
    int2 dd = *(const int2*)(ei + E + e0);
    float2 ff = *(const float2*)(ew + e0);
    float2 cc = *(const float2*)(ce + e0);
    float2 a0 = ((const float2*)asrc)[ss.x];
    float2 b0 = ((const float2*)bdst)[dd.x];
    float2 a1 = ((const float2*)asrc)[ss.y];
    float2 b1 = ((const float2*)bdst)[dd.y];
    out[e0]   = make_float2(ff.x*W0 + cc.x*W2 + a0.x + b0.x + B0,
                            ff.x*W1 + cc.x*W3 + a0.y + b0.y + B1);
    out[e0+1] = make_float2(ff.y*W0 + cc.y*W2 + a1.x + b1.x + B0,
                            ff.y*W1 + cc.y*W3 + a1.y + b1.y + B1);
  } else {
    int s = ei[e0], d = ei[E+e0];
    float f0 = ew[e0], f1 = ce[e0];
    float2 a = ((const float2*)asrc)[s];
    float2 b = ((const float2*)bdst)[d];
    out[e0] = make_float2(f0*W0 + f1*W2 + a.x + b.x + B0,
                          f0*W1 + f1*W3 + a.y + b.y + B1);
  }
}

extern "C" void kernel_launch(void* const* d_in, const int* in_sizes, int n_in,
                              void* d_out, int out_size, void* d_ws, size_t ws_size,
                              hipStream_t stream){
  const float* x     = (const float*)d_in[0];
  const int*   ei    = (const int*)  d_in[1];
  const float* ew    = (const float*)d_in[2];
  const float* ce    = (const float*)d_in[3];
  const float* w_init= (const float*)d_in[4];
  const float* b_init= (const float*)d_in[5];
  const float* w1l   = (const float*)d_in[6];
  const float* b1l   = (const float*)d_in[7];
  const float* w1r   = (const float*)d_in[8];
  const float* b1r   = (const float*)d_in[9];
  const float* w1e   = (const float*)d_in[10];
  const float* att1  = (const float*)d_in[11];
  const float* bias1 = (const float*)d_in[12];
  const float* w2l   = (const float*)d_in[13];
  const float* b2l   = (const float*)d_in[14];
  const float* w2r   = (const float*)d_in[15];
  const float* b2r   = (const float*)d_in[16];
  const float* w2e   = (const float*)d_in[17];
  const float* att2  = (const float*)d_in[18];
  const float* bias2 = (const float*)d_in[19];
  const float* w_fc  = (const float*)d_in[20];
  const float* b_fc  = (const float*)d_in[21];
  const float* w_e1  = (const float*)d_in[22];
  const float* b_e1  = (const float*)d_in[23];
  const float* w_e2  = (const float*)d_in[24];
  const float* b_e2  = (const float*)d_in[25];

  const int n = in_sizes[0]/5;     // 100000
  const int E = in_sizes[2];       // 3200000
  const int ntiles = (E + TTILE - 1) / TTILE;     // ~782
  const int nbk    = (n + BKN - 1) >> BSH;        // ~782 buckets

  // ---- workspace layout: 128B-aligned (32 x 4B units) ----
  int*   W32 = (int*)d_ws;
  float* Wf  = (float*)d_ws;
  size_t off = 0;
  auto nxt = [&off](size_t cnt){ size_t p = off; off += (cnt + 31) & ~(size_t)31; return p; };
  int*   rowstart = W32 + nxt((size_t)n + 1);
  int*   gcnt     = W32 + nxt(nbk);
  int*   bbase    = W32 + nxt(nbk + 1);
  int*   cursor   = W32 + nxt(nbk);
  float* wc       = Wf  + nxt(160);
  float* bc       = wc + 132;
  int*    csr_src = W32 + nxt((size_t)E);
  float2* csr_wc  = (float2*)(Wf + nxt((size_t)2*E));
  size_t na = ((size_t)n + 31) & ~(size_t)31;
  size_t bigsz = (size_t)4*E > 96*na ? (size_t)4*E : 96*na;
  float* S    = Wf + nxt(bigsz);
  int4*  tmp  = (int4*)S;          // 4E ints, dead after k_bucket
  float* xl1  = S;                 // 16n, dead after agg1f
  float* xr1  = S + 16*na;         // 16n, dead after agg1f
  float* xl2  = S + 32*na;         // 32n
  float* xr2  = S + 64*na;         // 32n
  float* asrc = S;                 // 2n (over dead xl1)
  float* bdst = S + 2*na;          // 2n

  dim3 blk(256);
  dim3 ge2((E/2 + 255)/256), gn((n + 255)/256), gn8(((size_t)8*n + 255)/256);

  hipMemsetAsync(gcnt, 0, nbk*sizeof(int), stream);
  k_wcomb<<<1,192,0,stream>>>(w_e1,b_e1,w_e2,b_e2,wc,bc);

  // ---- CSR build: LDS counting sort + per-bucket atomic cursors ----
  k_bhist<<<ntiles,1024,0,stream>>>(ei + E, gcnt, E, nbk);
  k_bscan<<<1,1024,0,stream>>>(gcnt, bbase, cursor, nbk);
  k_partitionB<<<ntiles,1024,0,stream>>>(ei,ew,ce,cursor,tmp,E,nbk);
  k_bucket<<<nbk,1024,0,stream>>>(tmp,bbase,rowstart,csr_src,csr_wc,n,E,nbk);

  // ---- GATv2 layer 1 (in 8, C=4) + fused layer-2 pre (16->64) ----
  k_pre1<<<gn,blk,0,stream>>>(x,w_init,b_init,w1l,b1l,w1r,b1r,xl1,xr1,n);
  k_agg1f<<<gn8,blk,0,stream>>>(rowstart,csr_src,csr_wc,xl1,xr1,w1e,att1,bias1,
                                w2l,b2l,w2r,b2r,xl2,xr2,n);

  // ---- GATv2 layer 2 (in 16, C=8) + fused fc/edge-MLP node terms ----
  k_agg2f<<<gn8,blk,0,stream>>>(rowstart,csr_src,csr_wc,xl2,xr2,w2e,att2,bias2,
                                w_fc,b_fc,wc,asrc,bdst,n);

  // ---- edge scores ----
  k_edge_final<<<ge2,blk,0,stream>>>(ei,ew,ce,asrc,bdst,wc,bc,(float2*)d_out,E);
}

// Round 6
// 425.045 us; speedup vs baseline: 1.1334x; 1.0050x over previous
//
#include <hip/hip_runtime.h>
#include <hip/hip_fp16.h>

// KEPCE_GAT r16: r15 + fp16 STORAGE for xl2 (the layer-2 gathered array).
// Evidence r10-r15: agg2f pinned at 2.78-3.0 TB/s L2-fill across 6 structural
// variants -> pattern ceiling for random 128B gathers; must cut bytes.
// xl2 12.8->6.4MB footprint (vs 4MiB/XCD L2), logical gather 410->205MB.
// All math stays fp32; pack in agg1f epilogue, unpack in agg2f. xr2/csr/xl1
// remain fp32 (single-variable change; falsifier = absmax failure).

__device__ __forceinline__ float lrelu(float v){ return v > 0.f ? v : 0.2f*v; }

// Load 8 fp16 (16B) -> 8 floats.
__device__ __forceinline__ void ld_h8(const __half* p, float* X){
  float4 raw = *(const float4*)p;
  float2 a = __half22float2(*(const __half2*)&raw.x);
  float2 b = __half22float2(*(const __half2*)&raw.y);
  float2 c = __half22float2(*(const __half2*)&raw.z);
  float2 d = __half22float2(*(const __half2*)&raw.w);
  X[0]=a.x; X[1]=a.y; X[2]=b.x; X[3]=b.y; X[4]=c.x; X[5]=c.y; X[6]=d.x; X[7]=d.y;
}

#define BSH   7        // bucket = dst >> 7  (128 dsts/bucket)
#define BKN   (1<<BSH)
#define TTILE 4096     // edges per partition tile (1024 thr x 4)

// Fold edge MLP: Wc[66,2] = w_e1[66,32] @ w_e2[32,2]; bc[2] = b_e1@w_e2 + b_e2.
__global__ void k_wcomb(const float* __restrict__ we1, const float* __restrict__ be1,
                        const float* __restrict__ we2, const float* __restrict__ be2,
                        float* __restrict__ wc, float* __restrict__ bc){
  int t = threadIdx.x;
  if (t < 132){
    int i = t >> 1, k = t & 1;
    float acc = 0.f;
    for (int j = 0; j < 32; ++j) acc += we1[i*32+j]*we2[j*2+k];
    wc[t] = acc;
  } else if (t < 134){
    int k = t - 132;
    float acc = be2[k];
    for (int j = 0; j < 32; ++j) acc += be1[j]*we2[j*2+k];
    bc[k] = acc;
  }
}

// Per-tile LDS bucket histogram -> one global atomicAdd per bin per block.
__global__ void k_bhist(const int* __restrict__ dst, int* __restrict__ gcnt,
                        int E, int nbk){
  __shared__ int cnt[1024];
  int lt = threadIdx.x;
  for (int b = lt; b < nbk; b += 1024) cnt[b] = 0;
  __syncthreads();
  int tb = blockIdx.x*TTILE;
  #pragma unroll
  for (int r = 0; r < TTILE/1024; ++r){
    int e = tb + r*1024 + lt;
    if (e < E) atomicAdd(&cnt[dst[e] >> BSH], 1);
  }
  __syncthreads();
  for (int b = lt; b < nbk; b += 1024)
    if (cnt[b]) atomicAdd(&gcnt[b], cnt[b]);
}

// Exclusive scan of nbk (<=1024) bucket counts -> bbase[0..nbk] and cursor.
__global__ void k_bscan(const int* __restrict__ gcnt, int* __restrict__ bbase,
                        int* __restrict__ cursor, int nb){
  __shared__ int lds[1024];
  int t = threadIdx.x;
  int v = (t < nb) ? gcnt[t] : 0;
  lds[t] = v;
  __syncthreads();
  #pragma unroll
  for (int off = 1; off < 1024; off <<= 1){
    int u = (t >= off) ? lds[t-off] : 0;
    __syncthreads();
    lds[t] += u;
    __syncthreads();
  }
  if (t < nb){
    int ex = lds[t] - v;
    bbase[t] = ex;
    cursor[t] = ex;
    if (t == nb-1) bbase[nb] = lds[t];
  }
}

// Partition: single streaming pass; records in registers; LDS ranks; block's
// per-bucket base claimed via one global atomicAdd per bin.
__global__ void k_partitionB(const int* __restrict__ ei, const float* __restrict__ ew,
                             const float* __restrict__ ce, int* __restrict__ cursor,
                             int4* __restrict__ tmp, int E, int nbk){
  __shared__ int cnt[1024];
  __shared__ int base[1024];
  int lt = threadIdx.x;
  for (int b = lt; b < nbk; b += 1024) cnt[b] = 0;
  __syncthreads();
  int tb = blockIdx.x*TTILE;
  int4 rec[TTILE/1024];
  int bk[TTILE/1024], rk[TTILE/1024];
  #pragma unroll
  for (int r = 0; r < TTILE/1024; ++r){
    int e = tb + r*1024 + lt;
    bk[r] = -1;
    if (e < E){
      int d = ei[E+e];
      int b2 = d >> BSH;
      bk[r] = b2;
      rk[r] = atomicAdd(&cnt[b2], 1);
      rec[r] = make_int4(ei[e], __float_as_int(ew[e]), __float_as_int(ce[e]), d);
    }
  }
  __syncthreads();
  for (int b = lt; b < nbk; b += 1024)
    base[b] = cnt[b] ? atomicAdd(&cursor[b], cnt[b]) : 0;
  __syncthreads();
  #pragma unroll
  for (int r = 0; r < TTILE/1024; ++r)
    if (bk[r] >= 0) tmp[base[bk[r]] + rk[r]] = rec[r];
}

// Per-bucket finalize: LDS dst-histogram -> scan -> rowstart + SoA CSR.
__global__ void k_bucket(const int4* __restrict__ tmp, const int* __restrict__ bbase,
                         int* __restrict__ rowstart, int* __restrict__ csr_src,
                         float2* __restrict__ csr_wc,
                         int n, int E, int nbk){
  __shared__ int cnt[BKN];
  __shared__ int sc[BKN];
  __shared__ int cur[BKN];
  int b = blockIdx.x, lt = threadIdx.x;
  int d0 = b << BSH;
  int segs = bbase[b];
  int sege = bbase[b+1];
  if (lt < BKN) cnt[lt] = 0;
  __syncthreads();
  for (int j = segs + lt; j < sege; j += 1024)
    atomicAdd(&cnt[tmp[j].w & (BKN-1)], 1);
  __syncthreads();
  if (lt < BKN) sc[lt] = cnt[lt];
  __syncthreads();
  #pragma unroll
  for (int off = 1; off < BKN; off <<= 1){
    int u = (lt >= off && lt < BKN) ? sc[lt-off] : 0;
    __syncthreads();
    if (lt < BKN) sc[lt] += u;
    __syncthreads();
  }
  if (lt < BKN){
    int excl = segs + sc[lt] - cnt[lt];
    cur[lt] = excl;
    int d = d0 + lt;
    if (d < n) rowstart[d] = excl;
  }
  if (b == 0 && lt == 0) rowstart[n] = E;
  __syncthreads();
  for (int j = segs + lt; j < sege; j += 1024){
    int4 rec = tmp[j];
    int pos = atomicAdd(&cur[rec.w & (BKN-1)], 1);
    csr_src[pos] = rec.x;
    csr_wc[pos] = make_float2(__int_as_float(rec.y), __int_as_float(rec.z));
  }
}

// Fused init+pre layer1: h0 = relu(x@wi+bi) in regs; xl1/xr1 = h0@Wl/Wr + b.
__global__ void k_pre1(const float* __restrict__ x, const float* __restrict__ wi,
                       const float* __restrict__ bi, const float* __restrict__ wl,
                       const float* __restrict__ bl, const float* __restrict__ wr,
                       const float* __restrict__ br, float* __restrict__ xl,
                       float* __restrict__ xr, int n){
  int i = blockIdx.x*blockDim.x + threadIdx.x;
  if (i >= n) return;
  float xi[5];
  #pragma unroll
  for (int j = 0; j < 5; ++j) xi[j] = x[i*5+j];
  float h[8];
  #pragma unroll
  for (int o = 0; o < 8; ++o){
    float acc = bi[o];
    #pragma unroll
    for (int j = 0; j < 5; ++j) acc += xi[j]*wi[j*8+o];
    h[o] = fmaxf(acc, 0.f);
  }
  #pragma unroll
  for (int o = 0; o < 16; ++o){
    float a = bl[o], r = br[o];
    #pragma unroll
    for (int j = 0; j < 8; ++j){ a += h[j]*wl[j*16+o]; r += h[j]*wr[j*16+o]; }
    xl[(size_t)i*16+o] = a;
    xr[(size_t)i*16+o] = r;
  }
}

// Layer-1 aggregation, split-K (8 thr/node) + FUSED layer-2 pre (fc 16->64)
// epilogue via LDS; xl2 written as fp16 (gather-footprint cut for agg2f).
__global__ void k_agg1f(const int* __restrict__ rowstart, const int* __restrict__ csr_src,
                        const float2* __restrict__ csr_wc,
                        const float* __restrict__ xl, const float* __restrict__ xr,
                        const float* __restrict__ we, const float* __restrict__ att,
                        const float* __restrict__ bias,
                        const float* __restrict__ w2l, const float* __restrict__ b2l,
                        const float* __restrict__ w2r, const float* __restrict__ b2r,
                        __half* __restrict__ xl2, float* __restrict__ xr2, int n){
  constexpr int C = 4, HC = 16;
  __shared__ float s_h[32*17];
  __shared__ float s_wl[512];
  __shared__ float s_wr[512];
  int lt = threadIdx.x;
  for (int k = lt; k < 512; k += 256){ s_wl[k] = w2l[k]; s_wr[k] = w2r[k]; }
  int t = blockIdx.x*blockDim.x + lt;
  int i = t >> 3, l = lt & 7, head = l & 3, half = l >> 2;
  bool valid = i < n;
  int ic = valid ? i : 0;
  float weA[C], weB[C], AT[C], BS[C];
  #pragma unroll
  for (int c = 0; c < C; ++c){
    int o = head*C + c;
    weA[c] = we[o]; weB[c] = we[HC+o]; AT[c] = att[o]; BS[c] = bias[o];
  }
  float XR[C];
  {
    float4 b = *(const float4*)(xr + (size_t)ic*HC + head*C);
    XR[0]=b.x; XR[1]=b.y; XR[2]=b.z; XR[3]=b.w;
  }
  float m = -3.0e38f, den = 0.f, sw = 0.f, sc = 0.f;
  float num[C] = {0.f,0.f,0.f,0.f};
  int rs = 0, re = 0;
  if (valid){ rs = rowstart[i]; re = rowstart[i+1]; }
  int mid = rs + ((re - rs) >> 1);
  int jb = half ? mid : rs, je = half ? re : mid;
  int j = jb;
  for (; j + 2 <= je; j += 2){
    int sa = csr_src[j], sb = csr_src[j+1];
    float2 wa = csr_wc[j], wb = csr_wc[j+1];
    float4 qa = *(const float4*)(xl + (size_t)sa*HC + head*C);
    float4 qb = *(const float4*)(xl + (size_t)sb*HC + head*C);
    float f0a = wa.x, f1a = wa.y;
    float f0b = wb.x, f1b = wb.y;
    sw += f0a + f0b; sc += f1a + f1b;
    float XA[C] = {qa.x,qa.y,qa.z,qa.w};
    float XB[C] = {qb.x,qb.y,qb.z,qb.w};
    float aa = 0.f, ab = 0.f;
    #pragma unroll
    for (int c = 0; c < C; ++c) aa += AT[c]*lrelu(XA[c] + XR[c] + f0a*weA[c] + f1a*weB[c]);
    #pragma unroll
    for (int c = 0; c < C; ++c) ab += AT[c]*lrelu(XB[c] + XR[c] + f0b*weA[c] + f1b*weB[c]);
    float nm = fmaxf(m, aa);
    float r = __expf(m - nm), ex = __expf(aa - nm);
    den = den*r + ex;
    #pragma unroll
    for (int c = 0; c < C; ++c) num[c] = num[c]*r + ex*XA[c];
    m = nm;
    nm = fmaxf(m, ab); r = __expf(m - nm); ex = __expf(ab - nm);
    den = den*r + ex;
    #pragma unroll
    for (int c = 0; c < C; ++c) num[c] = num[c]*r + ex*XB[c];
    m = nm;
  }
  if (j < je){
    int sa = csr_src[j];
    float2 wa = csr_wc[j];
    float4 qa = *(const float4*)(xl + (size_t)sa*HC + head*C);
    float f0a = wa.x, f1a = wa.y;
    sw += f0a; sc += f1a;
    float XA[C] = {qa.x,qa.y,qa.z,qa.w};
    float aa = 0.f;
    #pragma unroll
    for (int c = 0; c < C; ++c) aa += AT[c]*lrelu(XA[c] + XR[c] + f0a*weA[c] + f1a*weB[c]);
    float nm = fmaxf(m, aa);
    float r = __expf(m - nm), ex = __expf(aa - nm);
    den = den*r + ex;
    #pragma unroll
    for (int c = 0; c < C; ++c) num[c] = num[c]*r + ex*XA[c];
    m = nm;
  }
  {
    float mo  = __shfl_xor(m, 4);
    float dno = __shfl_xor(den, 4);
    float swo = __shfl_xor(sw, 4), sco = __shfl_xor(sc, 4);
    float nm = fmaxf(m, mo);
    float r0 = __expf(m - nm), r1 = __expf(mo - nm);
    den = den*r0 + dno*r1;
    #pragma unroll
    for (int c = 0; c < C; ++c){
      float no = __shfl_xor(num[c], 4);
      num[c] = num[c]*r0 + no*r1;
    }
    m = nm; sw += swo; sc += sco;
  }
  {
    float cf = fmaxf((float)(re - rs), 1.f);
    float la0 = sw/cf, la1 = sc/cf;
    float4 qs = *(const float4*)(xl + (size_t)ic*HC + head*C);
    float XS[C] = {qs.x,qs.y,qs.z,qs.w};
    float as = 0.f;
    #pragma unroll
    for (int c = 0; c < C; ++c) as += AT[c]*lrelu(XS[c] + XR[c] + la0*weA[c] + la1*weB[c]);
    float nm = fmaxf(m, as);
    float r = __expf(m - nm), ex = __expf(as - nm);
    den = den*r + ex;
    #pragma unroll
    for (int c = 0; c < C; ++c) num[c] = num[c]*r + ex*XS[c];
  }
  int ln = lt >> 3;
  if (half == 0){
    float inv = valid ? 1.f/den : 0.f;
    #pragma unroll
    for (int c = 0; c < C; ++c)
      s_h[ln*17 + head*C + c] = valid ? fmaxf(num[c]*inv + BS[c], 0.f) : 0.f;
  }
  __syncthreads();
  float hv[16];
  #pragma unroll
  for (int j2 = 0; j2 < 16; ++j2) hv[j2] = s_h[ln*17 + j2];
  if (valid){
    float ol[4], orr[4];
    #pragma unroll
    for (int k = 0; k < 4; ++k){
      int o = l*4 + k;
      float a = b2l[o], r = b2r[o];
      #pragma unroll
      for (int j2 = 0; j2 < 16; ++j2){ a += hv[j2]*s_wl[j2*32+o]; r += hv[j2]*s_wr[j2*32+o]; }
      ol[k] = a; orr[k] = r;
    }
    // xl2: fp16 pack (8B store). xr2: fp32 (read once/node, keep exact).
    __half2 p01 = __floats2half2_rn(ol[0], ol[1]);
    __half2 p23 = __floats2half2_rn(ol[2], ol[3]);
    __half2 pk[2] = {p01, p23};
    *(float2*)(xl2 + (size_t)i*32 + l*4) = *(float2*)pk;
    *(float4*)(xr2 + (size_t)i*32 + l*4) = make_float4(orr[0],orr[1],orr[2],orr[3]);
  }
}

// Layer-2 aggregation, split-K (8 thr/node), fp16 xl gather + fused fc/edge-MLP
// epilogue. (r13 loop structure; only loads changed to fp16 decode.)
__global__ void k_agg2f(const int* __restrict__ rowstart, const int* __restrict__ csr_src,
                        const float2* __restrict__ csr_wc,
                        const __half* __restrict__ xl, const float* __restrict__ xr,
                        const float* __restrict__ we, const float* __restrict__ att,
                        const float* __restrict__ bias, const float* __restrict__ wfc,
                        const float* __restrict__ bfc, const float* __restrict__ wc,
                        float* __restrict__ asrc, float* __restrict__ bdst, int n){
  constexpr int C = 8, HC = 32;
  __shared__ float s_h[32*33];
  __shared__ float s_w[1024];
  __shared__ float s_wc[134];
  int lt = threadIdx.x;
  for (int k = lt; k < 1024; k += 256) s_w[k] = wfc[k];
  if (lt < 134) s_wc[lt] = wc[lt];
  int t = blockIdx.x*blockDim.x + lt;
  int i = t >> 3, l = lt & 7, head = l & 3, half = l >> 2;
  bool valid = i < n;
  int ic = valid ? i : 0;
  float weA[C], weB[C], AT[C], BS[C];
  #pragma unroll
  for (int c = 0; c < C; ++c){
    int o = head*C + c;
    weA[c] = we[o]; weB[c] = we[HC+o]; AT[c] = att[o]; BS[c] = bias[o];
  }
  float XR[C];
  {
    const float4* pr = (const float4*)(xr + (size_t)ic*HC + head*C);
    float4 b0 = pr[0], b1 = pr[1];
    XR[0]=b0.x; XR[1]=b0.y; XR[2]=b0.z; XR[3]=b0.w;
    XR[4]=b1.x; XR[5]=b1.y; XR[6]=b1.z; XR[7]=b1.w;
  }
  float m = -3.0e38f, den = 0.f, sw = 0.f, sc = 0.f;
  float num[C] = {0.f,0.f,0.f,0.f,0.f,0.f,0.f,0.f};
  int rs = 0, re = 0;
  if (valid){ rs = rowstart[i]; re = rowstart[i+1]; }
  int mid = rs + ((re - rs) >> 1);
  int jb = half ? mid : rs, je = half ? re : mid;
  int j = jb;
  for (; j + 2 <= je; j += 2){
    int sa = csr_src[j], sb = csr_src[j+1];
    float2 wa = csr_wc[j], wb = csr_wc[j+1];
    float XA[C], XB[C];
    ld_h8(xl + (size_t)sa*HC + head*C, XA);
    ld_h8(xl + (size_t)sb*HC + head*C, XB);
    float f0a = wa.x, f1a = wa.y;
    float f0b = wb.x, f1b = wb.y;
    sw += f0a + f0b; sc += f1a + f1b;
    float aa = 0.f, ab = 0.f;
    #pragma unroll
    for (int c = 0; c < C; ++c) aa += AT[c]*lrelu(XA[c] + XR[c] + f0a*weA[c] + f1a*weB[c]);
    #pragma unroll
    for (int c = 0; c < C; ++c) ab += AT[c]*lrelu(XB[c] + XR[c] + f0b*weA[c] + f1b*weB[c]);
    float nm = fmaxf(m, aa);
    float r = __expf(m - nm), ex = __expf(aa - nm);
    den = den*r + ex;
    #pragma unroll
    for (int c = 0; c < C; ++c) num[c] = num[c]*r + ex*XA[c];
    m = nm;
    nm = fmaxf(m, ab); r = __expf(m - nm); ex = __expf(ab - nm);
    den = den*r + ex;
    #pragma unroll
    for (int c = 0; c < C; ++c) num[c] = num[c]*r + ex*XB[c];
    m = nm;
  }
  if (j < je){
    int sa = csr_src[j];
    float2 wa = csr_wc[j];
    float XA[C];
    ld_h8(xl + (size_t)sa*HC + head*C, XA);
    float f0a = wa.x, f1a = wa.y;
    sw += f0a; sc += f1a;
    float aa = 0.f;
    #pragma unroll
    for (int c = 0; c < C; ++c) aa += AT[c]*lrelu(XA[c] + XR[c] + f0a*weA[c] + f1a*weB[c]);
    float nm = fmaxf(m, aa);
    float r = __expf(m - nm), ex = __expf(aa - nm);
    den = den*r + ex;
    #pragma unroll
    for (int c = 0; c < C; ++c) num[c] = num[c]*r + ex*XA[c];
    m = nm;
  }
  {
    float mo  = __shfl_xor(m, 4);
    float dno = __shfl_xor(den, 4);
    float swo = __shfl_xor(sw, 4), sco = __shfl_xor(sc, 4);
    float nm = fmaxf(m, mo);
    float r0 = __expf(m - nm), r1 = __expf(mo - nm);
    den = den*r0 + dno*r1;
    #pragma unroll
    for (int c = 0; c < C; ++c){
      float no = __shfl_xor(num[c], 4);
      num[c] = num[c]*r0 + no*r1;
    }
    m = nm; sw += swo; sc += sco;
  }
  if (valid){
    float cf = fmaxf((float)(re - rs), 1.f);
    float la0 = sw/cf, la1 = sc/cf;
    float XS[C];
    ld_h8(xl + (size_t)i*HC + head*C, XS);
    float as = 0.f;
    #pragma unroll
    for (int c = 0; c < C; ++c) as += AT[c]*lrelu(XS[c] + XR[c] + la0*weA[c] + la1*weB[c]);
    float nm = fmaxf(m, as);
    float r = __expf(m - nm), ex = __expf(as - nm);
    den = den*r + ex;
    #pragma unroll
    for (int c = 0; c < C; ++c) num[c] = num[c]*r + ex*XS[c];
  }
  int ln = lt >> 3;
  if (half == 0){
    float inv = valid ? 1.f/den : 0.f;
    #pragma unroll
    for (int c = 0; c < C; ++c)
      s_h[ln*33 + head*C + c] = valid ? fmaxf(num[c]*inv + BS[c], 0.f) : 0.f;
  }
  __syncthreads();
  float hl[32];
  #pragma unroll
  for (int j2 = 0; j2 < 32; ++j2) hl[j2] = s_h[ln*33 + j2];
  float pa0=0.f, pa1=0.f, pb0=0.f, pb1=0.f;
  #pragma unroll
  for (int k = 0; k < 4; ++k){
    int o = l*4 + k;
    float acc = bfc[o];
    #pragma unroll
    for (int j2 = 0; j2 < 32; ++j2) acc += hl[j2]*s_w[j2*32+o];
    float f = fmaxf(acc, 0.f);
    pa0 += f*s_wc[(2+o)*2];  pa1 += f*s_wc[(2+o)*2+1];
    pb0 += f*s_wc[(34+o)*2]; pb1 += f*s_wc[(34+o)*2+1];
  }
  pa0 += __shfl_xor(pa0,1); pa0 += __shfl_xor(pa0,2); pa0 += __shfl_xor(pa0,4);
  pa1 += __shfl_xor(pa1,1); pa1 += __shfl_xor(pa1,2); pa1 += __shfl_xor(pa1,4);
  pb0 += __shfl_xor(pb0,1); pb0 += __shfl_xor(pb0,2); pb0 += __shfl_xor(pb0,4);
  pb1 += __shfl_xor(pb1,1); pb1 += __shfl_xor(pb1,2); pb1 += __shfl_xor(pb1,4);
  if (valid){
    if (l == 0)      ((float2*)asrc)[i] = make_float2(pa0, pa1);
    else if (l == 1) ((float2*)bdst)[i] = make_float2(pb0, pb1);
  }
}

// out[e] = ef[e]@Wc[0:2] + asrc[src] + bdst[dst] + bc; 2 edges/thread.
__global__ void k_edge_final(const int* __restrict__ ei, const float* __restrict__ ew,
                             const float* __restrict__ ce, const float* __restrict__ asrc,
                             const float* __restrict__ bdst, const float* __restrict__ wc,
                             const float* __restrict__ bc, float2* __restrict__ out, int E){
  int e0 = (blockIdx.x*blockDim.x + threadIdx.x)*2;
  if (e0 >= E) return;
  float W0 = wc[0], W1 = wc[1], W2 = wc[2], W3 = wc[3];
  float B0 = bc[0], B1 = bc[1];
  if (e0 + 2 <= E){
    int2 ss = *(const int2*)(ei + e0);
    int2 dd = *(const int2*)(ei + E + e0);
    float2 ff = *(const float2*)(ew + e0);
    float2 cc = *(const float2*)(ce + e0);
    float2 a0 = ((const float2*)asrc)[ss.x];
    float2 b0 = ((const float2*)bdst)[dd.x];
    float2 a1 = ((const float2*)asrc)[ss.y];
    float2 b1 = ((const float2*)bdst)[dd.y];
    out[e0]   = make_float2(ff.x*W0 + cc.x*W2 + a0.x + b0.x + B0,
                            ff.x*W1 + cc.x*W3 + a0.y + b0.y + B1);
    out[e0+1] = make_float2(ff.y*W0 + cc.y*W2 + a1.x + b1.x + B0,
                            ff.y*W1 + cc.y*W3 + a1.y + b1.y + B1);
  } else {
    int s = ei[e0], d = ei[E+e0];
    float f0 = ew[e0], f1 = ce[e0];
    float2 a = ((const float2*)asrc)[s];
    float2 b = ((const float2*)bdst)[d];
    out[e0] = make_float2(f0*W0 + f1*W2 + a.x + b.x + B0,
                          f0*W1 + f1*W3 + a.y + b.y + B1);
  }
}

extern "C" void kernel_launch(void* const* d_in, const int* in_sizes, int n_in,
                              void* d_out, int out_size, void* d_ws, size_t ws_size,
                              hipStream_t stream){
  const float* x     = (const float*)d_in[0];
  const int*   ei    = (const int*)  d_in[1];
  const float* ew    = (const float*)d_in[2];
  const float* ce    = (const float*)d_in[3];
  const float* w_init= (const float*)d_in[4];
  const float* b_init= (const float*)d_in[5];
  const float* w1l   = (const float*)d_in[6];
  const float* b1l   = (const float*)d_in[7];
  const float* w1r   = (const float*)d_in[8];
  const float* b1r   = (const float*)d_in[9];
  const float* w1e   = (const float*)d_in[10];
  const float* att1  = (const float*)d_in[11];
  const float* bias1 = (const float*)d_in[12];
  const float* w2l   = (const float*)d_in[13];
  const float* b2l   = (const float*)d_in[14];
  const float* w2r   = (const float*)d_in[15];
  const float* b2r   = (const float*)d_in[16];
  const float* w2e   = (const float*)d_in[17];
  const float* att2  = (const float*)d_in[18];
  const float* bias2 = (const float*)d_in[19];
  const float* w_fc  = (const float*)d_in[20];
  const float* b_fc  = (const float*)d_in[21];
  const float* w_e1  = (const float*)d_in[22];
  const float* b_e1  = (const float*)d_in[23];
  const float* w_e2  = (const float*)d_in[24];
  const float* b_e2  = (const float*)d_in[25];

  const int n = in_sizes[0]/5;     // 100000
  const int E = in_sizes[2];       // 3200000
  const int ntiles = (E + TTILE - 1) / TTILE;     // ~782
  const int nbk    = (n + BKN - 1) >> BSH;        // ~782 buckets

  // ---- workspace layout: 128B-aligned (32 x 4B units) ----
  int*   W32 = (int*)d_ws;
  float* Wf  = (float*)d_ws;
  size_t off = 0;
  auto nxt = [&off](size_t cnt){ size_t p = off; off += (cnt + 31) & ~(size_t)31; return p; };
  int*   rowstart = W32 + nxt((size_t)n + 1);
  int*   gcnt     = W32 + nxt(nbk);
  int*   bbase    = W32 + nxt(nbk + 1);
  int*   cursor   = W32 + nxt(nbk);
  float* wc       = Wf  + nxt(160);
  float* bc       = wc + 132;
  int*    csr_src = W32 + nxt((size_t)E);
  float2* csr_wc  = (float2*)(Wf + nxt((size_t)2*E));
  size_t na = ((size_t)n + 31) & ~(size_t)31;
  size_t bigsz = (size_t)4*E > 96*na ? (size_t)4*E : 96*na;
  float* S    = Wf + nxt(bigsz);
  int4*   tmp  = (int4*)S;          // 4E ints, dead after k_bucket
  float*  xl1  = S;                 // 16n floats, dead after agg1f
  float*  xr1  = S + 16*na;         // 16n floats, dead after agg1f
  __half* xl2  = (__half*)(S + 32*na); // 32n halves = 16n float-slots
  float*  xr2  = S + 48*na;         // 32n floats
  float*  asrc = S;                 // 2n (over dead xl1)
  float*  bdst = S + 2*na;          // 2n

  dim3 blk(256);
  dim3 ge2((E/2 + 255)/256), gn((n + 255)/256), gn8(((size_t)8*n + 255)/256);

  hipMemsetAsync(gcnt, 0, nbk*sizeof(int), stream);
  k_wcomb<<<1,192,0,stream>>>(w_e1,b_e1,w_e2,b_e2,wc,bc);

  // ---- CSR build: LDS counting sort + per-bucket atomic cursors ----
  k_bhist<<<ntiles,1024,0,stream>>>(ei + E, gcnt, E, nbk);
  k_bscan<<<1,1024,0,stream>>>(gcnt, bbase, cursor, nbk);
  k_partitionB<<<ntiles,1024,0,stream>>>(ei,ew,ce,cursor,tmp,E,nbk);
  k_bucket<<<nbk,1024,0,stream>>>(tmp,bbase,rowstart,csr_src,csr_wc,n,E,nbk);

  // ---- GATv2 layer 1 (in 8, C=4) + fused layer-2 pre (16->64, fp16 xl2) ----
  k_pre1<<<gn,blk,0,stream>>>(x,w_init,b_init,w1l,b1l,w1r,b1r,xl1,xr1,n);
  k_agg1f<<<gn8,blk,0,stream>>>(rowstart,csr_src,csr_wc,xl1,xr1,w1e,att1,bias1,
                                w2l,b2l,w2r,b2r,xl2,xr2,n);

  // ---- GATv2 layer 2 (in 16, C=8, fp16 gather) + fused fc/edge-MLP ----
  k_agg2f<<<gn8,blk,0,stream>>>(rowstart,csr_src,csr_wc,xl2,xr2,w2e,att2,bias2,
                                w_fc,b_fc,wc,asrc,bdst,n);

  // ---- edge scores ----
  k_edge_final<<<ge2,blk,0,stream>>>(ei,ew,ce,asrc,bdst,wc,bc,(float2*)d_out,E);
}

// Round 7
// 406.307 us; speedup vs baseline: 1.1857x; 1.0461x over previous
//
#include <hip/hip_runtime.h>
#include <hip/hip_fp16.h>

// KEPCE_GAT r17: r16 + split-K widened 8->16 threads/node (4 heads x 4
// edge-quarters) in both agg kernels. r16 showed agg2f is NOT byte-bound
// (FETCH -18% -> dur -2%); VALUBusy 52% = latency-bound with 2x headroom.
// Halves each lane's serial gather chain (16->8 edges) and doubles wave
// supply (12.5K->25K waves) at identical traffic/math. fp16 xl2 retained
// (absmax unchanged at 1.95e-3).

__device__ __forceinline__ float lrelu(float v){ return v > 0.f ? v : 0.2f*v; }

// Load 8 fp16 (16B) -> 8 floats.
__device__ __forceinline__ void ld_h8(const __half* p, float* X){
  float4 raw = *(const float4*)p;
  float2 a = __half22float2(*(const __half2*)&raw.x);
  float2 b = __half22float2(*(const __half2*)&raw.y);
  float2 c = __half22float2(*(const __half2*)&raw.z);
  float2 d = __half22float2(*(const __half2*)&raw.w);
  X[0]=a.x; X[1]=a.y; X[2]=b.x; X[3]=b.y; X[4]=c.x; X[5]=c.y; X[6]=d.x; X[7]=d.y;
}

#define BSH   7        // bucket = dst >> 7  (128 dsts/bucket)
#define BKN   (1<<BSH)
#define TTILE 4096     // edges per partition tile (1024 thr x 4)

// Fold edge MLP: Wc[66,2] = w_e1[66,32] @ w_e2[32,2]; bc[2] = b_e1@w_e2 + b_e2.
__global__ void k_wcomb(const float* __restrict__ we1, const float* __restrict__ be1,
                        const float* __restrict__ we2, const float* __restrict__ be2,
                        float* __restrict__ wc, float* __restrict__ bc){
  int t = threadIdx.x;
  if (t < 132){
    int i = t >> 1, k = t & 1;
    float acc = 0.f;
    for (int j = 0; j < 32; ++j) acc += we1[i*32+j]*we2[j*2+k];
    wc[t] = acc;
  } else if (t < 134){
    int k = t - 132;
    float acc = be2[k];
    for (int j = 0; j < 32; ++j) acc += be1[j]*we2[j*2+k];
    bc[k] = acc;
  }
}

// Per-tile LDS bucket histogram -> one global atomicAdd per bin per block.
__global__ void k_bhist(const int* __restrict__ dst, int* __restrict__ gcnt,
                        int E, int nbk){
  __shared__ int cnt[1024];
  int lt = threadIdx.x;
  for (int b = lt; b < nbk; b += 1024) cnt[b] = 0;
  __syncthreads();
  int tb = blockIdx.x*TTILE;
  #pragma unroll
  for (int r = 0; r < TTILE/1024; ++r){
    int e = tb + r*1024 + lt;
    if (e < E) atomicAdd(&cnt[dst[e] >> BSH], 1);
  }
  __syncthreads();
  for (int b = lt; b < nbk; b += 1024)
    if (cnt[b]) atomicAdd(&gcnt[b], cnt[b]);
}

// Exclusive scan of nbk (<=1024) bucket counts -> bbase[0..nbk] and cursor.
__global__ void k_bscan(const int* __restrict__ gcnt, int* __restrict__ bbase,
                        int* __restrict__ cursor, int nb){
  __shared__ int lds[1024];
  int t = threadIdx.x;
  int v = (t < nb) ? gcnt[t] : 0;
  lds[t] = v;
  __syncthreads();
  #pragma unroll
  for (int off = 1; off < 1024; off <<= 1){
    int u = (t >= off) ? lds[t-off] : 0;
    __syncthreads();
    lds[t] += u;
    __syncthreads();
  }
  if (t < nb){
    int ex = lds[t] - v;
    bbase[t] = ex;
    cursor[t] = ex;
    if (t == nb-1) bbase[nb] = lds[t];
  }
}

// Partition: single streaming pass; records in registers; LDS ranks; block's
// per-bucket base claimed via one global atomicAdd per bin.
__global__ void k_partitionB(const int* __restrict__ ei, const float* __restrict__ ew,
                             const float* __restrict__ ce, int* __restrict__ cursor,
                             int4* __restrict__ tmp, int E, int nbk){
  __shared__ int cnt[1024];
  __shared__ int base[1024];
  int lt = threadIdx.x;
  for (int b = lt; b < nbk; b += 1024) cnt[b] = 0;
  __syncthreads();
  int tb = blockIdx.x*TTILE;
  int4 rec[TTILE/1024];
  int bk[TTILE/1024], rk[TTILE/1024];
  #pragma unroll
  for (int r = 0; r < TTILE/1024; ++r){
    int e = tb + r*1024 + lt;
    bk[r] = -1;
    if (e < E){
      int d = ei[E+e];
      int b2 = d >> BSH;
      bk[r] = b2;
      rk[r] = atomicAdd(&cnt[b2], 1);
      rec[r] = make_int4(ei[e], __float_as_int(ew[e]), __float_as_int(ce[e]), d);
    }
  }
  __syncthreads();
  for (int b = lt; b < nbk; b += 1024)
    base[b] = cnt[b] ? atomicAdd(&cursor[b], cnt[b]) : 0;
  __syncthreads();
  #pragma unroll
  for (int r = 0; r < TTILE/1024; ++r)
    if (bk[r] >= 0) tmp[base[bk[r]] + rk[r]] = rec[r];
}

// Per-bucket finalize: LDS dst-histogram -> scan -> rowstart + SoA CSR.
__global__ void k_bucket(const int4* __restrict__ tmp, const int* __restrict__ bbase,
                         int* __restrict__ rowstart, int* __restrict__ csr_src,
                         float2* __restrict__ csr_wc,
                         int n, int E, int nbk){
  __shared__ int cnt[BKN];
  __shared__ int sc[BKN];
  __shared__ int cur[BKN];
  int b = blockIdx.x, lt = threadIdx.x;
  int d0 = b << BSH;
  int segs = bbase[b];
  int sege = bbase[b+1];
  if (lt < BKN) cnt[lt] = 0;
  __syncthreads();
  for (int j = segs + lt; j < sege; j += 1024)
    atomicAdd(&cnt[tmp[j].w & (BKN-1)], 1);
  __syncthreads();
  if (lt < BKN) sc[lt] = cnt[lt];
  __syncthreads();
  #pragma unroll
  for (int off = 1; off < BKN; off <<= 1){
    int u = (lt >= off && lt < BKN) ? sc[lt-off] : 0;
    __syncthreads();
    if (lt < BKN) sc[lt] += u;
    __syncthreads();
  }
  if (lt < BKN){
    int excl = segs + sc[lt] - cnt[lt];
    cur[lt] = excl;
    int d = d0 + lt;
    if (d < n) rowstart[d] = excl;
  }
  if (b == 0 && lt == 0) rowstart[n] = E;
  __syncthreads();
  for (int j = segs + lt; j < sege; j += 1024){
    int4 rec = tmp[j];
    int pos = atomicAdd(&cur[rec.w & (BKN-1)], 1);
    csr_src[pos] = rec.x;
    csr_wc[pos] = make_float2(__int_as_float(rec.y), __int_as_float(rec.z));
  }
}

// Fused init+pre layer1: h0 = relu(x@wi+bi) in regs; xl1/xr1 = h0@Wl/Wr + b.
__global__ void k_pre1(const float* __restrict__ x, const float* __restrict__ wi,
                       const float* __restrict__ bi, const float* __restrict__ wl,
                       const float* __restrict__ bl, const float* __restrict__ wr,
                       const float* __restrict__ br, float* __restrict__ xl,
                       float* __restrict__ xr, int n){
  int i = blockIdx.x*blockDim.x + threadIdx.x;
  if (i >= n) return;
  float xi[5];
  #pragma unroll
  for (int j = 0; j < 5; ++j) xi[j] = x[i*5+j];
  float h[8];
  #pragma unroll
  for (int o = 0; o < 8; ++o){
    float acc = bi[o];
    #pragma unroll
    for (int j = 0; j < 5; ++j) acc += xi[j]*wi[j*8+o];
    h[o] = fmaxf(acc, 0.f);
  }
  #pragma unroll
  for (int o = 0; o < 16; ++o){
    float a = bl[o], r = br[o];
    #pragma unroll
    for (int j = 0; j < 8; ++j){ a += h[j]*wl[j*16+o]; r += h[j]*wr[j*16+o]; }
    xl[(size_t)i*16+o] = a;
    xr[(size_t)i*16+o] = r;
  }
}

// Layer-1 aggregation, 16 thr/node (4 heads x 4 quarters) + FUSED layer-2
// pre (fc 16->64) epilogue via LDS; xl2 written fp16.
__global__ void k_agg1f(const int* __restrict__ rowstart, const int* __restrict__ csr_src,
                        const float2* __restrict__ csr_wc,
                        const float* __restrict__ xl, const float* __restrict__ xr,
                        const float* __restrict__ we, const float* __restrict__ att,
                        const float* __restrict__ bias,
                        const float* __restrict__ w2l, const float* __restrict__ b2l,
                        const float* __restrict__ w2r, const float* __restrict__ b2r,
                        __half* __restrict__ xl2, float* __restrict__ xr2, int n){
  constexpr int C = 4, HC = 16;
  __shared__ float s_h[16*17];
  __shared__ float s_wl[512];
  __shared__ float s_wr[512];
  int lt = threadIdx.x;
  for (int k = lt; k < 512; k += 256){ s_wl[k] = w2l[k]; s_wr[k] = w2r[k]; }
  int t = blockIdx.x*blockDim.x + lt;
  int i = t >> 4, l = lt & 15, head = l & 3, qr = l >> 2;
  bool valid = i < n;
  int ic = valid ? i : 0;
  float weA[C], weB[C], AT[C], BS[C];
  #pragma unroll
  for (int c = 0; c < C; ++c){
    int o = head*C + c;
    weA[c] = we[o]; weB[c] = we[HC+o]; AT[c] = att[o]; BS[c] = bias[o];
  }
  float XR[C];
  {
    float4 b = *(const float4*)(xr + (size_t)ic*HC + head*C);
    XR[0]=b.x; XR[1]=b.y; XR[2]=b.z; XR[3]=b.w;
  }
  float m = -3.0e38f, den = 0.f, sw = 0.f, sc = 0.f;
  float num[C] = {0.f,0.f,0.f,0.f};
  int rs = 0, re = 0;
  if (valid){ rs = rowstart[i]; re = rowstart[i+1]; }
  int len = re - rs;
  int jb = rs + ((len*qr) >> 2), je = rs + ((len*(qr+1)) >> 2);
  int j = jb;
  for (; j + 2 <= je; j += 2){
    int sa = csr_src[j], sb = csr_src[j+1];
    float2 wa = csr_wc[j], wb = csr_wc[j+1];
    float4 qa = *(const float4*)(xl + (size_t)sa*HC + head*C);
    float4 qb = *(const float4*)(xl + (size_t)sb*HC + head*C);
    float f0a = wa.x, f1a = wa.y;
    float f0b = wb.x, f1b = wb.y;
    sw += f0a + f0b; sc += f1a + f1b;
    float XA[C] = {qa.x,qa.y,qa.z,qa.w};
    float XB[C] = {qb.x,qb.y,qb.z,qb.w};
    float aa = 0.f, ab = 0.f;
    #pragma unroll
    for (int c = 0; c < C; ++c) aa += AT[c]*lrelu(XA[c] + XR[c] + f0a*weA[c] + f1a*weB[c]);
    #pragma unroll
    for (int c = 0; c < C; ++c) ab += AT[c]*lrelu(XB[c] + XR[c] + f0b*weA[c] + f1b*weB[c]);
    float nm = fmaxf(m, aa);
    float r = __expf(m - nm), ex = __expf(aa - nm);
    den = den*r + ex;
    #pragma unroll
    for (int c = 0; c < C; ++c) num[c] = num[c]*r + ex*XA[c];
    m = nm;
    nm = fmaxf(m, ab); r = __expf(m - nm); ex = __expf(ab - nm);
    den = den*r + ex;
    #pragma unroll
    for (int c = 0; c < C; ++c) num[c] = num[c]*r + ex*XB[c];
    m = nm;
  }
  if (j < je){
    int sa = csr_src[j];
    float2 wa = csr_wc[j];
    float4 qa = *(const float4*)(xl + (size_t)sa*HC + head*C);
    float f0a = wa.x, f1a = wa.y;
    sw += f0a; sc += f1a;
    float XA[C] = {qa.x,qa.y,qa.z,qa.w};
    float aa = 0.f;
    #pragma unroll
    for (int c = 0; c < C; ++c) aa += AT[c]*lrelu(XA[c] + XR[c] + f0a*weA[c] + f1a*weB[c]);
    float nm = fmaxf(m, aa);
    float r = __expf(m - nm), ex = __expf(aa - nm);
    den = den*r + ex;
    #pragma unroll
    for (int c = 0; c < C; ++c) num[c] = num[c]*r + ex*XA[c];
    m = nm;
  }
  // merge the 4 quarters: butterfly over lane bits 2 (xor 4) and 3 (xor 8)
  #pragma unroll
  for (int msk = 4; msk <= 8; msk <<= 1){
    float mo  = __shfl_xor(m, msk);
    float dno = __shfl_xor(den, msk);
    float swo = __shfl_xor(sw, msk), sco = __shfl_xor(sc, msk);
    float nm = fmaxf(m, mo);
    float r0 = __expf(m - nm), r1 = __expf(mo - nm);
    den = den*r0 + dno*r1;
    #pragma unroll
    for (int c = 0; c < C; ++c){
      float no = __shfl_xor(num[c], msk);
      num[c] = num[c]*r0 + no*r1;
    }
    m = nm; sw += swo; sc += sco;
  }
  {
    float cf = fmaxf((float)len, 1.f);
    float la0 = sw/cf, la1 = sc/cf;
    float4 qs = *(const float4*)(xl + (size_t)ic*HC + head*C);
    float XS[C] = {qs.x,qs.y,qs.z,qs.w};
    float as = 0.f;
    #pragma unroll
    for (int c = 0; c < C; ++c) as += AT[c]*lrelu(XS[c] + XR[c] + la0*weA[c] + la1*weB[c]);
    float nm = fmaxf(m, as);
    float r = __expf(m - nm), ex = __expf(as - nm);
    den = den*r + ex;
    #pragma unroll
    for (int c = 0; c < C; ++c) num[c] = num[c]*r + ex*XS[c];
  }
  int ln = lt >> 4;
  if (qr == 0){
    float inv = valid ? 1.f/den : 0.f;
    #pragma unroll
    for (int c = 0; c < C; ++c)
      s_h[ln*17 + head*C + c] = valid ? fmaxf(num[c]*inv + BS[c], 0.f) : 0.f;
  }
  __syncthreads();
  // fc epilogue: node ln; 16 lanes each compute outputs o = l*2, l*2+1 of
  // both xl2 = h@w2l+b2l (fp16 pack) and xr2 = h@w2r+b2r.
  float hv[16];
  #pragma unroll
  for (int j2 = 0; j2 < 16; ++j2) hv[j2] = s_h[ln*17 + j2];
  if (valid){
    float ol[2], orr[2];
    #pragma unroll
    for (int k = 0; k < 2; ++k){
      int o = l*2 + k;
      float a = b2l[o], r = b2r[o];
      #pragma unroll
      for (int j2 = 0; j2 < 16; ++j2){ a += hv[j2]*s_wl[j2*32+o]; r += hv[j2]*s_wr[j2*32+o]; }
      ol[k] = a; orr[k] = r;
    }
    __half2 p01 = __floats2half2_rn(ol[0], ol[1]);
    *(__half2*)(xl2 + (size_t)i*32 + l*2) = p01;
    *(float2*)(xr2 + (size_t)i*32 + l*2) = make_float2(orr[0], orr[1]);
  }
}

// Layer-2 aggregation, 16 thr/node (4 heads x 4 quarters), fp16 xl gather +
// fused fc/edge-MLP epilogue.
__global__ void k_agg2f(const int* __restrict__ rowstart, const int* __restrict__ csr_src,
                        const float2* __restrict__ csr_wc,
                        const __half* __restrict__ xl, const float* __restrict__ xr,
                        const float* __restrict__ we, const float* __restrict__ att,
                        const float* __restrict__ bias, const float* __restrict__ wfc,
                        const float* __restrict__ bfc, const float* __restrict__ wc,
                        float* __restrict__ asrc, float* __restrict__ bdst, int n){
  constexpr int C = 8, HC = 32;
  __shared__ float s_h[16*33];
  __shared__ float s_w[1024];
  __shared__ float s_wc[134];
  int lt = threadIdx.x;
  for (int k = lt; k < 1024; k += 256) s_w[k] = wfc[k];
  if (lt < 134) s_wc[lt] = wc[lt];
  int t = blockIdx.x*blockDim.x + lt;
  int i = t >> 4, l = lt & 15, head = l & 3, qr = l >> 2;
  bool valid = i < n;
  int ic = valid ? i : 0;
  float weA[C], weB[C], AT[C], BS[C];
  #pragma unroll
  for (int c = 0; c < C; ++c){
    int o = head*C + c;
    weA[c] = we[o]; weB[c] = we[HC+o]; AT[c] = att[o]; BS[c] = bias[o];
  }
  float XR[C];
  {
    const float4* pr = (const float4*)(xr + (size_t)ic*HC + head*C);
    float4 b0 = pr[0], b1 = pr[1];
    XR[0]=b0.x; XR[1]=b0.y; XR[2]=b0.z; XR[3]=b0.w;
    XR[4]=b1.x; XR[5]=b1.y; XR[6]=b1.z; XR[7]=b1.w;
  }
  float m = -3.0e38f, den = 0.f, sw = 0.f, sc = 0.f;
  float num[C] = {0.f,0.f,0.f,0.f,0.f,0.f,0.f,0.f};
  int rs = 0, re = 0;
  if (valid){ rs = rowstart[i]; re = rowstart[i+1]; }
  int len = re - rs;
  int jb = rs + ((len*qr) >> 2), je = rs + ((len*(qr+1)) >> 2);
  int j = jb;
  for (; j + 2 <= je; j += 2){
    int sa = csr_src[j], sb = csr_src[j+1];
    float2 wa = csr_wc[j], wb = csr_wc[j+1];
    float XA[C], XB[C];
    ld_h8(xl + (size_t)sa*HC + head*C, XA);
    ld_h8(xl + (size_t)sb*HC + head*C, XB);
    float f0a = wa.x, f1a = wa.y;
    float f0b = wb.x, f1b = wb.y;
    sw += f0a + f0b; sc += f1a + f1b;
    float aa = 0.f, ab = 0.f;
    #pragma unroll
    for (int c = 0; c < C; ++c) aa += AT[c]*lrelu(XA[c] + XR[c] + f0a*weA[c] + f1a*weB[c]);
    #pragma unroll
    for (int c = 0; c < C; ++c) ab += AT[c]*lrelu(XB[c] + XR[c] + f0b*weA[c] + f1b*weB[c]);
    float nm = fmaxf(m, aa);
    float r = __expf(m - nm), ex = __expf(aa - nm);
    den = den*r + ex;
    #pragma unroll
    for (int c = 0; c < C; ++c) num[c] = num[c]*r + ex*XA[c];
    m = nm;
    nm = fmaxf(m, ab); r = __expf(m - nm); ex = __expf(ab - nm);
    den = den*r + ex;
    #pragma unroll
    for (int c = 0; c < C; ++c) num[c] = num[c]*r + ex*XB[c];
    m = nm;
  }
  if (j < je){
    int sa = csr_src[j];
    float2 wa = csr_wc[j];
    float XA[C];
    ld_h8(xl + (size_t)sa*HC + head*C, XA);
    float f0a = wa.x, f1a = wa.y;
    sw += f0a; sc += f1a;
    float aa = 0.f;
    #pragma unroll
    for (int c = 0; c < C; ++c) aa += AT[c]*lrelu(XA[c] + XR[c] + f0a*weA[c] + f1a*weB[c]);
    float nm = fmaxf(m, aa);
    float r = __expf(m - nm), ex = __expf(aa - nm);
    den = den*r + ex;
    #pragma unroll
    for (int c = 0; c < C; ++c) num[c] = num[c]*r + ex*XA[c];
    m = nm;
  }
  // merge the 4 quarters
  #pragma unroll
  for (int msk = 4; msk <= 8; msk <<= 1){
    float mo  = __shfl_xor(m, msk);
    float dno = __shfl_xor(den, msk);
    float swo = __shfl_xor(sw, msk), sco = __shfl_xor(sc, msk);
    float nm = fmaxf(m, mo);
    float r0 = __expf(m - nm), r1 = __expf(mo - nm);
    den = den*r0 + dno*r1;
    #pragma unroll
    for (int c = 0; c < C; ++c){
      float no = __shfl_xor(num[c], msk);
      num[c] = num[c]*r0 + no*r1;
    }
    m = nm; sw += swo; sc += sco;
  }
  if (valid){
    float cf = fmaxf((float)len, 1.f);
    float la0 = sw/cf, la1 = sc/cf;
    float XS[C];
    ld_h8(xl + (size_t)i*HC + head*C, XS);
    float as = 0.f;
    #pragma unroll
    for (int c = 0; c < C; ++c) as += AT[c]*lrelu(XS[c] + XR[c] + la0*weA[c] + la1*weB[c]);
    float nm = fmaxf(m, as);
    float r = __expf(m - nm), ex = __expf(as - nm);
    den = den*r + ex;
    #pragma unroll
    for (int c = 0; c < C; ++c) num[c] = num[c]*r + ex*XS[c];
  }
  int ln = lt >> 4;
  if (qr == 0){
    float inv = valid ? 1.f/den : 0.f;
    #pragma unroll
    for (int c = 0; c < C; ++c)
      s_h[ln*33 + head*C + c] = valid ? fmaxf(num[c]*inv + BS[c], 0.f) : 0.f;
  }
  __syncthreads();
  // fc/edge-MLP epilogue: 16 lanes/node, each computes 2 fc outputs.
  float hl[32];
  #pragma unroll
  for (int j2 = 0; j2 < 32; ++j2) hl[j2] = s_h[ln*33 + j2];
  float pa0=0.f, pa1=0.f, pb0=0.f, pb1=0.f;
  #pragma unroll
  for (int k = 0; k < 2; ++k){
    int o = l*2 + k;
    float acc = bfc[o];
    #pragma unroll
    for (int j2 = 0; j2 < 32; ++j2) acc += hl[j2]*s_w[j2*32+o];
    float f = fmaxf(acc, 0.f);
    pa0 += f*s_wc[(2+o)*2];  pa1 += f*s_wc[(2+o)*2+1];
    pb0 += f*s_wc[(34+o)*2]; pb1 += f*s_wc[(34+o)*2+1];
  }
  pa0 += __shfl_xor(pa0,1); pa0 += __shfl_xor(pa0,2); pa0 += __shfl_xor(pa0,4); pa0 += __shfl_xor(pa0,8);
  pa1 += __shfl_xor(pa1,1); pa1 += __shfl_xor(pa1,2); pa1 += __shfl_xor(pa1,4); pa1 += __shfl_xor(pa1,8);
  pb0 += __shfl_xor(pb0,1); pb0 += __shfl_xor(pb0,2); pb0 += __shfl_xor(pb0,4); pb0 += __shfl_xor(pb0,8);
  pb1 += __shfl_xor(pb1,1); pb1 += __shfl_xor(pb1,2); pb1 += __shfl_xor(pb1,4); pb1 += __shfl_xor(pb1,8);
  if (valid){
    if (l == 0)      ((float2*)asrc)[i] = make_float2(pa0, pa1);
    else if (l == 1) ((float2*)bdst)[i] = make_float2(pb0, pb1);
  }
}

// out[e] = ef[e]@Wc[0:2] + asrc[src] + bdst[dst] + bc; 2 edges/thread.
__global__ void k_edge_final(const int* __restrict__ ei, const float* __restrict__ ew,
                             const float* __restrict__ ce, const float* __restrict__ asrc,
                             const float* __restrict__ bdst, const float* __restrict__ wc,
                             const float* __restrict__ bc, float2* __restrict__ out, int E){
  int e0 = (blockIdx.x*blockDim.x + threadIdx.x)*2;
  if (e0 >= E) return;
  float W0 = wc[0], W1 = wc[1], W2 = wc[2], W3 = wc[3];
  float B0 = bc[0], B1 = bc[1];
  if (e0 + 2 <= E){
    int2 ss = *(const int2*)(ei + e0);
    int2 dd = *(const int2*)(ei + E + e0);
    float2 ff = *(const float2*)(ew + e0);
    float2 cc = *(const float2*)(ce + e0);
    float2 a0 = ((const float2*)asrc)[ss.x];
    float2 b0 = ((const float2*)bdst)[dd.x];
    float2 a1 = ((const float2*)asrc)[ss.y];
    float2 b1 = ((const float2*)bdst)[dd.y];
    out[e0]   = make_float2(ff.x*W0 + cc.x*W2 + a0.x + b0.x + B0,
                            ff.x*W1 + cc.x*W3 + a0.y + b0.y + B1);
    out[e0+1] = make_float2(ff.y*W0 + cc.y*W2 + a1.x + b1.x + B0,
                            ff.y*W1 + cc.y*W3 + a1.y + b1.y + B1);
  } else {
    int s = ei[e0], d = ei[E+e0];
    float f0 = ew[e0], f1 = ce[e0];
    float2 a = ((const float2*)asrc)[s];
    float2 b = ((const float2*)bdst)[d];
    out[e0] = make_float2(f0*W0 + f1*W2 + a.x + b.x + B0,
                          f0*W1 + f1*W3 + a.y + b.y + B1);
  }
}

extern "C" void kernel_launch(void* const* d_in, const int* in_sizes, int n_in,
                              void* d_out, int out_size, void* d_ws, size_t ws_size,
                              hipStream_t stream){
  const float* x     = (const float*)d_in[0];
  const int*   ei    = (const int*)  d_in[1];
  const float* ew    = (const float*)d_in[2];
  const float* ce    = (const float*)d_in[3];
  const float* w_init= (const float*)d_in[4];
  const float* b_init= (const float*)d_in[5];
  const float* w1l   = (const float*)d_in[6];
  const float* b1l   = (const float*)d_in[7];
  const float* w1r   = (const float*)d_in[8];
  const float* b1r   = (const float*)d_in[9];
  const float* w1e   = (const float*)d_in[10];
  const float* att1  = (const float*)d_in[11];
  const float* bias1 = (const float*)d_in[12];
  const float* w2l   = (const float*)d_in[13];
  const float* b2l   = (const float*)d_in[14];
  const float* w2r   = (const float*)d_in[15];
  const float* b2r   = (const float*)d_in[16];
  const float* w2e   = (const float*)d_in[17];
  const float* att2  = (const float*)d_in[18];
  const float* bias2 = (const float*)d_in[19];
  const float* w_fc  = (const float*)d_in[20];
  const float* b_fc  = (const float*)d_in[21];
  const float* w_e1  = (const float*)d_in[22];
  const float* b_e1  = (const float*)d_in[23];
  const float* w_e2  = (const float*)d_in[24];
  const float* b_e2  = (const float*)d_in[25];

  const int n = in_sizes[0]/5;     // 100000
  const int E = in_sizes[2];       // 3200000
  const int ntiles = (E + TTILE - 1) / TTILE;     // ~782
  const int nbk    = (n + BKN - 1) >> BSH;        // ~782 buckets

  // ---- workspace layout: 128B-aligned (32 x 4B units) ----
  int*   W32 = (int*)d_ws;
  float* Wf  = (float*)d_ws;
  size_t off = 0;
  auto nxt = [&off](size_t cnt){ size_t p = off; off += (cnt + 31) & ~(size_t)31; return p; };
  int*   rowstart = W32 + nxt((size_t)n + 1);
  int*   gcnt     = W32 + nxt(nbk);
  int*   bbase    = W32 + nxt(nbk + 1);
  int*   cursor   = W32 + nxt(nbk);
  float* wc       = Wf  + nxt(160);
  float* bc       = wc + 132;
  int*    csr_src = W32 + nxt((size_t)E);
  float2* csr_wc  = (float2*)(Wf + nxt((size_t)2*E));
  size_t na = ((size_t)n + 31) & ~(size_t)31;
  size_t bigsz = (size_t)4*E > 96*na ? (size_t)4*E : 96*na;
  float* S    = Wf + nxt(bigsz);
  int4*   tmp  = (int4*)S;          // 4E ints, dead after k_bucket
  float*  xl1  = S;                 // 16n floats, dead after agg1f
  float*  xr1  = S + 16*na;         // 16n floats, dead after agg1f
  __half* xl2  = (__half*)(S + 32*na); // 32n halves = 16n float-slots
  float*  xr2  = S + 48*na;         // 32n floats
  float*  asrc = S;                 // 2n (over dead xl1)
  float*  bdst = S + 2*na;          // 2n

  dim3 blk(256);
  dim3 ge2((E/2 + 255)/256), gn((n + 255)/256), gn16(((size_t)16*n + 255)/256);

  hipMemsetAsync(gcnt, 0, nbk*sizeof(int), stream);
  k_wcomb<<<1,192,0,stream>>>(w_e1,b_e1,w_e2,b_e2,wc,bc);

  // ---- CSR build: LDS counting sort + per-bucket atomic cursors ----
  k_bhist<<<ntiles,1024,0,stream>>>(ei + E, gcnt, E, nbk);
  k_bscan<<<1,1024,0,stream>>>(gcnt, bbase, cursor, nbk);
  k_partitionB<<<ntiles,1024,0,stream>>>(ei,ew,ce,cursor,tmp,E,nbk);
  k_bucket<<<nbk,1024,0,stream>>>(tmp,bbase,rowstart,csr_src,csr_wc,n,E,nbk);

  // ---- GATv2 layer 1 (in 8, C=4) + fused layer-2 pre (16->64, fp16 xl2) ----
  k_pre1<<<gn,blk,0,stream>>>(x,w_init,b_init,w1l,b1l,w1r,b1r,xl1,xr1,n);
  k_agg1f<<<gn16,blk,0,stream>>>(rowstart,csr_src,csr_wc,xl1,xr1,w1e,att1,bias1,
                                 w2l,b2l,w2r,b2r,xl2,xr2,n);

  // ---- GATv2 layer 2 (in 16, C=8, fp16 gather) + fused fc/edge-MLP ----
  k_agg2f<<<gn16,blk,0,stream>>>(rowstart,csr_src,csr_wc,xl2,xr2,w2e,att2,bias2,
                                 w_fc,b_fc,wc,asrc,bdst,n);

  // ---- edge scores ----
  k_edge_final<<<ge2,blk,0,stream>>>(ei,ew,ce,asrc,bdst,wc,bc,(float2*)d_out,E);
}

// Round 8
// 392.702 us; speedup vs baseline: 1.2268x; 1.0346x over previous
//
#include <hip/hip_runtime.h>
#include <hip/hip_fp16.h>

// KEPCE_GAT r18: r17 + max-free softmax in both agg kernels.
// r17 left agg2f at 84us / VALUBusy 66% / FETCH 132MB -> VALU-stream bound.
// The online-softmax max-tracking (~12 of ~22 softmax VALU ops per edge-head)
// is mathematically redundant: num/den is scale-invariant and glorot logits
// are O(1-10), far below fp32 exp overflow (~85). New inner loop:
// ex = exp2f(alpha') with log2(e) folded into att; den += ex; num += ex*XA.
// Cross-lane merge becomes pure sums. Falsifier: inf/NaN -> revert.

__device__ __forceinline__ float lrelu(float v){ return v > 0.f ? v : 0.2f*v; }
#define LOG2E 1.44269504f

// Load 8 fp16 (16B) -> 8 floats.
__device__ __forceinline__ void ld_h8(const __half* p, float* X){
  float4 raw = *(const float4*)p;
  float2 a = __half22float2(*(const __half2*)&raw.x);
  float2 b = __half22float2(*(const __half2*)&raw.y);
  float2 c = __half22float2(*(const __half2*)&raw.z);
  float2 d = __half22float2(*(const __half2*)&raw.w);
  X[0]=a.x; X[1]=a.y; X[2]=b.x; X[3]=b.y; X[4]=c.x; X[5]=c.y; X[6]=d.x; X[7]=d.y;
}

#define BSH   7        // bucket = dst >> 7  (128 dsts/bucket)
#define BKN   (1<<BSH)
#define TTILE 4096     // edges per partition tile (1024 thr x 4)

// Fold edge MLP: Wc[66,2] = w_e1[66,32] @ w_e2[32,2]; bc[2] = b_e1@w_e2 + b_e2.
__global__ void k_wcomb(const float* __restrict__ we1, const float* __restrict__ be1,
                        const float* __restrict__ we2, const float* __restrict__ be2,
                        float* __restrict__ wc, float* __restrict__ bc){
  int t = threadIdx.x;
  if (t < 132){
    int i = t >> 1, k = t & 1;
    float acc = 0.f;
    for (int j = 0; j < 32; ++j) acc += we1[i*32+j]*we2[j*2+k];
    wc[t] = acc;
  } else if (t < 134){
    int k = t - 132;
    float acc = be2[k];
    for (int j = 0; j < 32; ++j) acc += be1[j]*we2[j*2+k];
    bc[k] = acc;
  }
}

// Per-tile LDS bucket histogram -> one global atomicAdd per bin per block.
__global__ void k_bhist(const int* __restrict__ dst, int* __restrict__ gcnt,
                        int E, int nbk){
  __shared__ int cnt[1024];
  int lt = threadIdx.x;
  for (int b = lt; b < nbk; b += 1024) cnt[b] = 0;
  __syncthreads();
  int tb = blockIdx.x*TTILE;
  #pragma unroll
  for (int r = 0; r < TTILE/1024; ++r){
    int e = tb + r*1024 + lt;
    if (e < E) atomicAdd(&cnt[dst[e] >> BSH], 1);
  }
  __syncthreads();
  for (int b = lt; b < nbk; b += 1024)
    if (cnt[b]) atomicAdd(&gcnt[b], cnt[b]);
}

// Exclusive scan of nbk (<=1024) bucket counts -> bbase[0..nbk] and cursor.
__global__ void k_bscan(const int* __restrict__ gcnt, int* __restrict__ bbase,
                        int* __restrict__ cursor, int nb){
  __shared__ int lds[1024];
  int t = threadIdx.x;
  int v = (t < nb) ? gcnt[t] : 0;
  lds[t] = v;
  __syncthreads();
  #pragma unroll
  for (int off = 1; off < 1024; off <<= 1){
    int u = (t >= off) ? lds[t-off] : 0;
    __syncthreads();
    lds[t] += u;
    __syncthreads();
  }
  if (t < nb){
    int ex = lds[t] - v;
    bbase[t] = ex;
    cursor[t] = ex;
    if (t == nb-1) bbase[nb] = lds[t];
  }
}

// Partition: single streaming pass; records in registers; LDS ranks; block's
// per-bucket base claimed via one global atomicAdd per bin.
__global__ void k_partitionB(const int* __restrict__ ei, const float* __restrict__ ew,
                             const float* __restrict__ ce, int* __restrict__ cursor,
                             int4* __restrict__ tmp, int E, int nbk){
  __shared__ int cnt[1024];
  __shared__ int base[1024];
  int lt = threadIdx.x;
  for (int b = lt; b < nbk; b += 1024) cnt[b] = 0;
  __syncthreads();
  int tb = blockIdx.x*TTILE;
  int4 rec[TTILE/1024];
  int bk[TTILE/1024], rk[TTILE/1024];
  #pragma unroll
  for (int r = 0; r < TTILE/1024; ++r){
    int e = tb + r*1024 + lt;
    bk[r] = -1;
    if (e < E){
      int d = ei[E+e];
      int b2 = d >> BSH;
      bk[r] = b2;
      rk[r] = atomicAdd(&cnt[b2], 1);
      rec[r] = make_int4(ei[e], __float_as_int(ew[e]), __float_as_int(ce[e]), d);
    }
  }
  __syncthreads();
  for (int b = lt; b < nbk; b += 1024)
    base[b] = cnt[b] ? atomicAdd(&cursor[b], cnt[b]) : 0;
  __syncthreads();
  #pragma unroll
  for (int r = 0; r < TTILE/1024; ++r)
    if (bk[r] >= 0) tmp[base[bk[r]] + rk[r]] = rec[r];
}

// Per-bucket finalize: LDS dst-histogram -> scan -> rowstart + SoA CSR.
__global__ void k_bucket(const int4* __restrict__ tmp, const int* __restrict__ bbase,
                         int* __restrict__ rowstart, int* __restrict__ csr_src,
                         float2* __restrict__ csr_wc,
                         int n, int E, int nbk){
  __shared__ int cnt[BKN];
  __shared__ int sc[BKN];
  __shared__ int cur[BKN];
  int b = blockIdx.x, lt = threadIdx.x;
  int d0 = b << BSH;
  int segs = bbase[b];
  int sege = bbase[b+1];
  if (lt < BKN) cnt[lt] = 0;
  __syncthreads();
  for (int j = segs + lt; j < sege; j += 1024)
    atomicAdd(&cnt[tmp[j].w & (BKN-1)], 1);
  __syncthreads();
  if (lt < BKN) sc[lt] = cnt[lt];
  __syncthreads();
  #pragma unroll
  for (int off = 1; off < BKN; off <<= 1){
    int u = (lt >= off && lt < BKN) ? sc[lt-off] : 0;
    __syncthreads();
    if (lt < BKN) sc[lt] += u;
    __syncthreads();
  }
  if (lt < BKN){
    int excl = segs + sc[lt] - cnt[lt];
    cur[lt] = excl;
    int d = d0 + lt;
    if (d < n) rowstart[d] = excl;
  }
  if (b == 0 && lt == 0) rowstart[n] = E;
  __syncthreads();
  for (int j = segs + lt; j < sege; j += 1024){
    int4 rec = tmp[j];
    int pos = atomicAdd(&cur[rec.w & (BKN-1)], 1);
    csr_src[pos] = rec.x;
    csr_wc[pos] = make_float2(__int_as_float(rec.y), __int_as_float(rec.z));
  }
}

// Fused init+pre layer1: h0 = relu(x@wi+bi) in regs; xl1/xr1 = h0@Wl/Wr + b.
__global__ void k_pre1(const float* __restrict__ x, const float* __restrict__ wi,
                       const float* __restrict__ bi, const float* __restrict__ wl,
                       const float* __restrict__ bl, const float* __restrict__ wr,
                       const float* __restrict__ br, float* __restrict__ xl,
                       float* __restrict__ xr, int n){
  int i = blockIdx.x*blockDim.x + threadIdx.x;
  if (i >= n) return;
  float xi[5];
  #pragma unroll
  for (int j = 0; j < 5; ++j) xi[j] = x[i*5+j];
  float h[8];
  #pragma unroll
  for (int o = 0; o < 8; ++o){
    float acc = bi[o];
    #pragma unroll
    for (int j = 0; j < 5; ++j) acc += xi[j]*wi[j*8+o];
    h[o] = fmaxf(acc, 0.f);
  }
  #pragma unroll
  for (int o = 0; o < 16; ++o){
    float a = bl[o], r = br[o];
    #pragma unroll
    for (int j = 0; j < 8; ++j){ a += h[j]*wl[j*16+o]; r += h[j]*wr[j*16+o]; }
    xl[(size_t)i*16+o] = a;
    xr[(size_t)i*16+o] = r;
  }
}

// Layer-1 aggregation, 16 thr/node (4 heads x 4 quarters), max-free softmax
// + FUSED layer-2 pre (fc 16->64) epilogue via LDS; xl2 written fp16.
__global__ void k_agg1f(const int* __restrict__ rowstart, const int* __restrict__ csr_src,
                        const float2* __restrict__ csr_wc,
                        const float* __restrict__ xl, const float* __restrict__ xr,
                        const float* __restrict__ we, const float* __restrict__ att,
                        const float* __restrict__ bias,
                        const float* __restrict__ w2l, const float* __restrict__ b2l,
                        const float* __restrict__ w2r, const float* __restrict__ b2r,
                        __half* __restrict__ xl2, float* __restrict__ xr2, int n){
  constexpr int C = 4, HC = 16;
  __shared__ float s_h[16*17];
  __shared__ float s_wl[512];
  __shared__ float s_wr[512];
  int lt = threadIdx.x;
  for (int k = lt; k < 512; k += 256){ s_wl[k] = w2l[k]; s_wr[k] = w2r[k]; }
  int t = blockIdx.x*blockDim.x + lt;
  int i = t >> 4, l = lt & 15, head = l & 3, qr = l >> 2;
  bool valid = i < n;
  int ic = valid ? i : 0;
  float weA[C], weB[C], AT[C], BS[C];
  #pragma unroll
  for (int c = 0; c < C; ++c){
    int o = head*C + c;
    weA[c] = we[o]; weB[c] = we[HC+o]; AT[c] = att[o]*LOG2E; BS[c] = bias[o];
  }
  float XR[C];
  {
    float4 b = *(const float4*)(xr + (size_t)ic*HC + head*C);
    XR[0]=b.x; XR[1]=b.y; XR[2]=b.z; XR[3]=b.w;
  }
  float den = 0.f, sw = 0.f, sc = 0.f;
  float num[C] = {0.f,0.f,0.f,0.f};
  int rs = 0, re = 0;
  if (valid){ rs = rowstart[i]; re = rowstart[i+1]; }
  int len = re - rs;
  int jb = rs + ((len*qr) >> 2), je = rs + ((len*(qr+1)) >> 2);
  int j = jb;
  for (; j + 2 <= je; j += 2){
    int sa = csr_src[j], sb = csr_src[j+1];
    float2 wa = csr_wc[j], wb = csr_wc[j+1];
    float4 qa = *(const float4*)(xl + (size_t)sa*HC + head*C);
    float4 qb = *(const float4*)(xl + (size_t)sb*HC + head*C);
    float f0a = wa.x, f1a = wa.y;
    float f0b = wb.x, f1b = wb.y;
    sw += f0a + f0b; sc += f1a + f1b;
    float XA[C] = {qa.x,qa.y,qa.z,qa.w};
    float XB[C] = {qb.x,qb.y,qb.z,qb.w};
    float aa = 0.f, ab = 0.f;
    #pragma unroll
    for (int c = 0; c < C; ++c) aa += AT[c]*lrelu(XA[c] + XR[c] + f0a*weA[c] + f1a*weB[c]);
    #pragma unroll
    for (int c = 0; c < C; ++c) ab += AT[c]*lrelu(XB[c] + XR[c] + f0b*weA[c] + f1b*weB[c]);
    float exa = exp2f(aa), exb = exp2f(ab);
    den += exa + exb;
    #pragma unroll
    for (int c = 0; c < C; ++c) num[c] += exa*XA[c] + exb*XB[c];
  }
  if (j < je){
    int sa = csr_src[j];
    float2 wa = csr_wc[j];
    float4 qa = *(const float4*)(xl + (size_t)sa*HC + head*C);
    float f0a = wa.x, f1a = wa.y;
    sw += f0a; sc += f1a;
    float XA[C] = {qa.x,qa.y,qa.z,qa.w};
    float aa = 0.f;
    #pragma unroll
    for (int c = 0; c < C; ++c) aa += AT[c]*lrelu(XA[c] + XR[c] + f0a*weA[c] + f1a*weB[c]);
    float exa = exp2f(aa);
    den += exa;
    #pragma unroll
    for (int c = 0; c < C; ++c) num[c] += exa*XA[c];
  }
  // merge the 4 quarters: pure sums (no max state)
  #pragma unroll
  for (int msk = 4; msk <= 8; msk <<= 1){
    den += __shfl_xor(den, msk);
    sw  += __shfl_xor(sw, msk);
    sc  += __shfl_xor(sc, msk);
    #pragma unroll
    for (int c = 0; c < C; ++c) num[c] += __shfl_xor(num[c], msk);
  }
  {
    float cf = fmaxf((float)len, 1.f);
    float la0 = sw/cf, la1 = sc/cf;
    float4 qs = *(const float4*)(xl + (size_t)ic*HC + head*C);
    float XS[C] = {qs.x,qs.y,qs.z,qs.w};
    float as = 0.f;
    #pragma unroll
    for (int c = 0; c < C; ++c) as += AT[c]*lrelu(XS[c] + XR[c] + la0*weA[c] + la1*weB[c]);
    float exs = exp2f(as);
    den += exs;
    #pragma unroll
    for (int c = 0; c < C; ++c) num[c] += exs*XS[c];
  }
  int ln = lt >> 4;
  if (qr == 0){
    float inv = valid ? 1.f/den : 0.f;
    #pragma unroll
    for (int c = 0; c < C; ++c)
      s_h[ln*17 + head*C + c] = valid ? fmaxf(num[c]*inv + BS[c], 0.f) : 0.f;
  }
  __syncthreads();
  // fc epilogue: node ln; 16 lanes each compute outputs o = l*2, l*2+1 of
  // both xl2 = h@w2l+b2l (fp16 pack) and xr2 = h@w2r+b2r.
  float hv[16];
  #pragma unroll
  for (int j2 = 0; j2 < 16; ++j2) hv[j2] = s_h[ln*17 + j2];
  if (valid){
    float ol[2], orr[2];
    #pragma unroll
    for (int k = 0; k < 2; ++k){
      int o = l*2 + k;
      float a = b2l[o], r = b2r[o];
      #pragma unroll
      for (int j2 = 0; j2 < 16; ++j2){ a += hv[j2]*s_wl[j2*32+o]; r += hv[j2]*s_wr[j2*32+o]; }
      ol[k] = a; orr[k] = r;
    }
    __half2 p01 = __floats2half2_rn(ol[0], ol[1]);
    *(__half2*)(xl2 + (size_t)i*32 + l*2) = p01;
    *(float2*)(xr2 + (size_t)i*32 + l*2) = make_float2(orr[0], orr[1]);
  }
}

// Layer-2 aggregation, 16 thr/node (4 heads x 4 quarters), max-free softmax,
// fp16 xl gather + fused fc/edge-MLP epilogue.
__global__ void k_agg2f(const int* __restrict__ rowstart, const int* __restrict__ csr_src,
                        const float2* __restrict__ csr_wc,
                        const __half* __restrict__ xl, const float* __restrict__ xr,
                        const float* __restrict__ we, const float* __restrict__ att,
                        const float* __restrict__ bias, const float* __restrict__ wfc,
                        const float* __restrict__ bfc, const float* __restrict__ wc,
                        float* __restrict__ asrc, float* __restrict__ bdst, int n){
  constexpr int C = 8, HC = 32;
  __shared__ float s_h[16*33];
  __shared__ float s_w[1024];
  __shared__ float s_wc[134];
  int lt = threadIdx.x;
  for (int k = lt; k < 1024; k += 256) s_w[k] = wfc[k];
  if (lt < 134) s_wc[lt] = wc[lt];
  int t = blockIdx.x*blockDim.x + lt;
  int i = t >> 4, l = lt & 15, head = l & 3, qr = l >> 2;
  bool valid = i < n;
  int ic = valid ? i : 0;
  float weA[C], weB[C], AT[C], BS[C];
  #pragma unroll
  for (int c = 0; c < C; ++c){
    int o = head*C + c;
    weA[c] = we[o]; weB[c] = we[HC+o]; AT[c] = att[o]*LOG2E; BS[c] = bias[o];
  }
  float XR[C];
  {
    const float4* pr = (const float4*)(xr + (size_t)ic*HC + head*C);
    float4 b0 = pr[0], b1 = pr[1];
    XR[0]=b0.x; XR[1]=b0.y; XR[2]=b0.z; XR[3]=b0.w;
    XR[4]=b1.x; XR[5]=b1.y; XR[6]=b1.z; XR[7]=b1.w;
  }
  float den = 0.f, sw = 0.f, sc = 0.f;
  float num[C] = {0.f,0.f,0.f,0.f,0.f,0.f,0.f,0.f};
  int rs = 0, re = 0;
  if (valid){ rs = rowstart[i]; re = rowstart[i+1]; }
  int len = re - rs;
  int jb = rs + ((len*qr) >> 2), je = rs + ((len*(qr+1)) >> 2);
  int j = jb;
  for (; j + 2 <= je; j += 2){
    int sa = csr_src[j], sb = csr_src[j+1];
    float2 wa = csr_wc[j], wb = csr_wc[j+1];
    float XA[C], XB[C];
    ld_h8(xl + (size_t)sa*HC + head*C, XA);
    ld_h8(xl + (size_t)sb*HC + head*C, XB);
    float f0a = wa.x, f1a = wa.y;
    float f0b = wb.x, f1b = wb.y;
    sw += f0a + f0b; sc += f1a + f1b;
    float aa = 0.f, ab = 0.f;
    #pragma unroll
    for (int c = 0; c < C; ++c) aa += AT[c]*lrelu(XA[c] + XR[c] + f0a*weA[c] + f1a*weB[c]);
    #pragma unroll
    for (int c = 0; c < C; ++c) ab += AT[c]*lrelu(XB[c] + XR[c] + f0b*weA[c] + f1b*weB[c]);
    float exa = exp2f(aa), exb = exp2f(ab);
    den += exa + exb;
    #pragma unroll
    for (int c = 0; c < C; ++c) num[c] += exa*XA[c] + exb*XB[c];
  }
  if (j < je){
    int sa = csr_src[j];
    float2 wa = csr_wc[j];
    float XA[C];
    ld_h8(xl + (size_t)sa*HC + head*C, XA);
    float f0a = wa.x, f1a = wa.y;
    sw += f0a; sc += f1a;
    float aa = 0.f;
    #pragma unroll
    for (int c = 0; c < C; ++c) aa += AT[c]*lrelu(XA[c] + XR[c] + f0a*weA[c] + f1a*weB[c]);
    float exa = exp2f(aa);
    den += exa;
    #pragma unroll
    for (int c = 0; c < C; ++c) num[c] += exa*XA[c];
  }
  // merge the 4 quarters: pure sums
  #pragma unroll
  for (int msk = 4; msk <= 8; msk <<= 1){
    den += __shfl_xor(den, msk);
    sw  += __shfl_xor(sw, msk);
    sc  += __shfl_xor(sc, msk);
    #pragma unroll
    for (int c = 0; c < C; ++c) num[c] += __shfl_xor(num[c], msk);
  }
  if (valid){
    float cf = fmaxf((float)len, 1.f);
    float la0 = sw/cf, la1 = sc/cf;
    float XS[C];
    ld_h8(xl + (size_t)i*HC + head*C, XS);
    float as = 0.f;
    #pragma unroll
    for (int c = 0; c < C; ++c) as += AT[c]*lrelu(XS[c] + XR[c] + la0*weA[c] + la1*weB[c]);
    float exs = exp2f(as);
    den += exs;
    #pragma unroll
    for (int c = 0; c < C; ++c) num[c] += exs*XS[c];
  }
  int ln = lt >> 4;
  if (qr == 0){
    float inv = valid ? 1.f/den : 0.f;
    #pragma unroll
    for (int c = 0; c < C; ++c)
      s_h[ln*33 + head*C + c] = valid ? fmaxf(num[c]*inv + BS[c], 0.f) : 0.f;
  }
  __syncthreads();
  // fc/edge-MLP epilogue: 16 lanes/node, each computes 2 fc outputs.
  float hl[32];
  #pragma unroll
  for (int j2 = 0; j2 < 32; ++j2) hl[j2] = s_h[ln*33 + j2];
  float pa0=0.f, pa1=0.f, pb0=0.f, pb1=0.f;
  #pragma unroll
  for (int k = 0; k < 2; ++k){
    int o = l*2 + k;
    float acc = bfc[o];
    #pragma unroll
    for (int j2 = 0; j2 < 32; ++j2) acc += hl[j2]*s_w[j2*32+o];
    float f = fmaxf(acc, 0.f);
    pa0 += f*s_wc[(2+o)*2];  pa1 += f*s_wc[(2+o)*2+1];
    pb0 += f*s_wc[(34+o)*2]; pb1 += f*s_wc[(34+o)*2+1];
  }
  pa0 += __shfl_xor(pa0,1); pa0 += __shfl_xor(pa0,2); pa0 += __shfl_xor(pa0,4); pa0 += __shfl_xor(pa0,8);
  pa1 += __shfl_xor(pa1,1); pa1 += __shfl_xor(pa1,2); pa1 += __shfl_xor(pa1,4); pa1 += __shfl_xor(pa1,8);
  pb0 += __shfl_xor(pb0,1); pb0 += __shfl_xor(pb0,2); pb0 += __shfl_xor(pb0,4); pb0 += __shfl_xor(pb0,8);
  pb1 += __shfl_xor(pb1,1); pb1 += __shfl_xor(pb1,2); pb1 += __shfl_xor(pb1,4); pb1 += __shfl_xor(pb1,8);
  if (valid){
    if (l == 0)      ((float2*)asrc)[i] = make_float2(pa0, pa1);
    else if (l == 1) ((float2*)bdst)[i] = make_float2(pb0, pb1);
  }
}

// out[e] = ef[e]@Wc[0:2] + asrc[src] + bdst[dst] + bc; 2 edges/thread.
__global__ void k_edge_final(const int* __restrict__ ei, const float* __restrict__ ew,
                             const float* __restrict__ ce, const float* __restrict__ asrc,
                             const float* __restrict__ bdst, const float* __restrict__ wc,
                             const float* __restrict__ bc, float2* __restrict__ out, int E){
  int e0 = (blockIdx.x*blockDim.x + threadIdx.x)*2;
  if (e0 >= E) return;
  float W0 = wc[0], W1 = wc[1], W2 = wc[2], W3 = wc[3];
  float B0 = bc[0], B1 = bc[1];
  if (e0 + 2 <= E){
    int2 ss = *(const int2*)(ei + e0);
    int2 dd = *(const int2*)(ei + E + e0);
    float2 ff = *(const float2*)(ew + e0);
    float2 cc = *(const float2*)(ce + e0);
    float2 a0 = ((const float2*)asrc)[ss.x];
    float2 b0 = ((const float2*)bdst)[dd.x];
    float2 a1 = ((const float2*)asrc)[ss.y];
    float2 b1 = ((const float2*)bdst)[dd.y];
    out[e0]   = make_float2(ff.x*W0 + cc.x*W2 + a0.x + b0.x + B0,
                            ff.x*W1 + cc.x*W3 + a0.y + b0.y + B1);
    out[e0+1] = make_float2(ff.y*W0 + cc.y*W2 + a1.x + b1.x + B0,
                            ff.y*W1 + cc.y*W3 + a1.y + b1.y + B1);
  } else {
    int s = ei[e0], d = ei[E+e0];
    float f0 = ew[e0], f1 = ce[e0];
    float2 a = ((const float2*)asrc)[s];
    float2 b = ((const float2*)bdst)[d];
    out[e0] = make_float2(f0*W0 + f1*W2 + a.x + b.x + B0,
                          f0*W1 + f1*W3 + a.y + b.y + B1);
  }
}

extern "C" void kernel_launch(void* const* d_in, const int* in_sizes, int n_in,
                              void* d_out, int out_size, void* d_ws, size_t ws_size,
                              hipStream_t stream){
  const float* x     = (const float*)d_in[0];
  const int*   ei    = (const int*)  d_in[1];
  const float* ew    = (const float*)d_in[2];
  const float* ce    = (const float*)d_in[3];
  const float* w_init= (const float*)d_in[4];
  const float* b_init= (const float*)d_in[5];
  const float* w1l   = (const float*)d_in[6];
  const float* b1l   = (const float*)d_in[7];
  const float* w1r   = (const float*)d_in[8];
  const float* b1r   = (const float*)d_in[9];
  const float* w1e   = (const float*)d_in[10];
  const float* att1  = (const float*)d_in[11];
  const float* bias1 = (const float*)d_in[12];
  const float* w2l   = (const float*)d_in[13];
  const float* b2l   = (const float*)d_in[14];
  const float* w2r   = (const float*)d_in[15];
  const float* b2r   = (const float*)d_in[16];
  const float* w2e   = (const float*)d_in[17];
  const float* att2  = (const float*)d_in[18];
  const float* bias2 = (const float*)d_in[19];
  const float* w_fc  = (const float*)d_in[20];
  const float* b_fc  = (const float*)d_in[21];
  const float* w_e1  = (const float*)d_in[22];
  const float* b_e1  = (const float*)d_in[23];
  const float* w_e2  = (const float*)d_in[24];
  const float* b_e2  = (const float*)d_in[25];

  const int n = in_sizes[0]/5;     // 100000
  const int E = in_sizes[2];       // 3200000
  const int ntiles = (E + TTILE - 1) / TTILE;     // ~782
  const int nbk    = (n + BKN - 1) >> BSH;        // ~782 buckets

  // ---- workspace layout: 128B-aligned (32 x 4B units) ----
  int*   W32 = (int*)d_ws;
  float* Wf  = (float*)d_ws;
  size_t off = 0;
  auto nxt = [&off](size_t cnt){ size_t p = off; off += (cnt + 31) & ~(size_t)31; return p; };
  int*   rowstart = W32 + nxt((size_t)n + 1);
  int*   gcnt     = W32 + nxt(nbk);
  int*   bbase    = W32 + nxt(nbk + 1);
  int*   cursor   = W32 + nxt(nbk);
  float* wc       = Wf  + nxt(160);
  float* bc       = wc + 132;
  int*    csr_src = W32 + nxt((size_t)E);
  float2* csr_wc  = (float2*)(Wf + nxt((size_t)2*E));
  size_t na = ((size_t)n + 31) & ~(size_t)31;
  size_t bigsz = (size_t)4*E > 96*na ? (size_t)4*E : 96*na;
  float* S    = Wf + nxt(bigsz);
  int4*   tmp  = (int4*)S;          // 4E ints, dead after k_bucket
  float*  xl1  = S;                 // 16n floats, dead after agg1f
  float*  xr1  = S + 16*na;         // 16n floats, dead after agg1f
  __half* xl2  = (__half*)(S + 32*na); // 32n halves = 16n float-slots
  float*  xr2  = S + 48*na;         // 32n floats
  float*  asrc = S;                 // 2n (over dead xl1)
  float*  bdst = S + 2*na;          // 2n

  dim3 blk(256);
  dim3 ge2((E/2 + 255)/256), gn((n + 255)/256), gn16(((size_t)16*n + 255)/256);

  hipMemsetAsync(gcnt, 0, nbk*sizeof(int), stream);
  k_wcomb<<<1,192,0,stream>>>(w_e1,b_e1,w_e2,b_e2,wc,bc);

  // ---- CSR build: LDS counting sort + per-bucket atomic cursors ----
  k_bhist<<<ntiles,1024,0,stream>>>(ei + E, gcnt, E, nbk);
  k_bscan<<<1,1024,0,stream>>>(gcnt, bbase, cursor, nbk);
  k_partitionB<<<ntiles,1024,0,stream>>>(ei,ew,ce,cursor,tmp,E,nbk);
  k_bucket<<<nbk,1024,0,stream>>>(tmp,bbase,rowstart,csr_src,csr_wc,n,E,nbk);

  // ---- GATv2 layer 1 (in 8, C=4) + fused layer-2 pre (16->64, fp16 xl2) ----
  k_pre1<<<gn,blk,0,stream>>>(x,w_init,b_init,w1l,b1l,w1r,b1r,xl1,xr1,n);
  k_agg1f<<<gn16,blk,0,stream>>>(rowstart,csr_src,csr_wc,xl1,xr1,w1e,att1,bias1,
                                 w2l,b2l,w2r,b2r,xl2,xr2,n);

  // ---- GATv2 layer 2 (in 16, C=8, fp16 gather) + fused fc/edge-MLP ----
  k_agg2f<<<gn16,blk,0,stream>>>(rowstart,csr_src,csr_wc,xl2,xr2,w2e,att2,bias2,
                                 w_fc,b_fc,wc,asrc,bdst,n);

  // ---- edge scores ----
  k_edge_final<<<ge2,blk,0,stream>>>(ei,ew,ce,asrc,bdst,wc,bc,(float2*)d_out,E);
}